// Round 3
// baseline (1361.569 us; speedup 1.0000x reference)
//
#include <hip/hip_runtime.h>
#include <hip/hip_bf16.h>
#include <math.h>

#define D_MODEL 768
#define T_SEQ   1024
#define BATCH   4
#define NCH     7
#define ROWS    4096            // BATCH*T_SEQ

typedef unsigned short u16;
typedef __attribute__((ext_vector_type(8))) short bh8;   // 8 x bf16
typedef __attribute__((ext_vector_type(4))) float f32x4;

__device__ __forceinline__ u16 f2bf(float f) {
    union { float f; unsigned u; } v; v.f = f;
    return (u16)((v.u + 0x7fffu + ((v.u >> 16) & 1u)) >> 16);  // RNE
}
__device__ __forceinline__ float bf2f(u16 b) {
    union { unsigned u; float f; } v; v.u = ((unsigned)b) << 16;
    return v.f;
}
__device__ __forceinline__ float wred_sum(float v) {
    #pragma unroll
    for (int o = 32; o; o >>= 1) v += __shfl_down(v, o, 64);
    return v;
}
__device__ __forceinline__ float wred_max(float v) {
    #pragma unroll
    for (int o = 32; o; o >>= 1) v = fmaxf(v, __shfl_down(v, o, 64));
    return v;
}
__device__ __forceinline__ float chamber_mask(int i) {
    float slope = 8.0f * 7.0f / 2000.0f;
    return 1.0f / (1.0f + __expf(-slope * (4000.0f - 2000.0f * (i + 0.5f) / 7.0f)));
}

#define GLD16(g, l) __builtin_amdgcn_global_load_lds( \
    (const __attribute__((address_space(1))) void*)(g), \
    (__attribute__((address_space(3))) void*)(l), 16, 0, 0)

// ---------------------------------------------------------------------------
// Grouped NT GEMM: up to 2 descriptors per launch; blocks split by nblk.
// C[M,N] = alpha * A[M,K] * B[N,K]^T   (A,B bf16)
// mode: 0 f32 store, 1 bf16 store, 3 f16 store
// flags: 1 = causal skip (bn>bm), 2 = causal K-limit (K <= (bm+1)*128)
// z decomposition: z = zbase+bz; bz1 = z%zm (offset *s?1), bz2 = z/zm (*s?2)
// ---------------------------------------------------------------------------
struct GDesc {
    const u16* A; const u16* B; void* C;
    int K, lda, ldb, ldc;
    long long sA1, sA2, sB1, sB2, sC1, sC2;
    int zm, zbase, gx, gy, nblk;
    float alpha;
    int mode, flags;
};
struct GPack { GDesc d[2]; int n; };

__global__ __launch_bounds__(256)
void gemm_grouped(GPack p)
{
    GDesc d = p.d[0];
    int flat = blockIdx.x;
    if (p.n > 1 && flat >= p.d[0].nblk) { d = p.d[1]; flat -= p.d[0].nblk; }
    int bn = flat % d.gx;
    int rest = flat / d.gx;
    int bm = rest % d.gy;
    int bz = rest / d.gy;
    if ((d.flags & 1) && bn > bm) return;
    int z = d.zbase + bz;
    int bz1 = z % d.zm, bz2 = z / d.zm;

    const u16* Ab = d.A + bz1 * d.sA1 + bz2 * d.sA2 + (long long)(bm * 128) * d.lda;
    const u16* Bb = d.B + bz1 * d.sB1 + bz2 * d.sB2 + (long long)(bn * 128) * d.ldb;

    __shared__ u16 sm[2 * 128 * 32];
    u16* Al = sm;
    u16* Bl = sm + 128 * 32;

    int tid  = threadIdx.x;
    int lane = tid & 63;
    int wave = tid >> 6;
    int wm = wave >> 1, wn = wave & 1;

    int k_end = d.K;
    if (d.flags & 2) k_end = min(k_end, (bm + 1) * 128);

    f32x4 acc[4][4];
    #pragma unroll
    for (int i = 0; i < 4; i++)
        #pragma unroll
        for (int j = 0; j < 4; j++)
            acc[i][j] = (f32x4){0.f, 0.f, 0.f, 0.f};

    int srow = lane >> 2;
    int skq  = (lane & 3) * 8;
    int fm   = lane & 15;
    int fk   = (lane >> 4) * 8;

    for (int k0 = 0; k0 < k_end; k0 += 32) {
        __syncthreads();
        #pragma unroll
        for (int r = 0; r < 2; r++) {
            int row = r * 64 + wave * 16 + srow;
            GLD16(Ab + (long long)row * d.lda + k0 + skq, Al + row * 32 + skq);
            GLD16(Bb + (long long)row * d.ldb + k0 + skq, Bl + row * 32 + skq);
        }
        __syncthreads();

        bh8 af[4], bf[4];
        #pragma unroll
        for (int i = 0; i < 4; i++)
            af[i] = *(const bh8*)(Al + (wm * 64 + i * 16 + fm) * 32 + fk);
        #pragma unroll
        for (int j = 0; j < 4; j++)
            bf[j] = *(const bh8*)(Bl + (wn * 64 + j * 16 + fm) * 32 + fk);
        #pragma unroll
        for (int i = 0; i < 4; i++)
            #pragma unroll
            for (int j = 0; j < 4; j++)
                acc[i][j] = __builtin_amdgcn_mfma_f32_16x16x32_bf16(af[i], bf[j], acc[i][j], 0, 0, 0);
    }

    int rbase = bm * 128 + wm * 64 + (lane >> 4) * 4;
    int cbase = bn * 128 + wn * 64 + (lane & 15);
    long long zoff = bz1 * d.sC1 + bz2 * d.sC2;
    if (d.mode == 1) {
        u16* C = (u16*)d.C + zoff;
        #pragma unroll
        for (int i = 0; i < 4; i++)
            #pragma unroll
            for (int j = 0; j < 4; j++)
                #pragma unroll
                for (int r = 0; r < 4; r++)
                    C[(long long)(rbase + i * 16 + r) * d.ldc + cbase + j * 16] = f2bf(acc[i][j][r] * d.alpha);
    } else if (d.mode == 3) {
        u16* C = (u16*)d.C + zoff;
        #pragma unroll
        for (int i = 0; i < 4; i++)
            #pragma unroll
            for (int j = 0; j < 4; j++)
                #pragma unroll
                for (int r = 0; r < 4; r++) {
                    union { _Float16 h; u16 u; } cv;
                    cv.h = (_Float16)(acc[i][j][r] * d.alpha);
                    C[(long long)(rbase + i * 16 + r) * d.ldc + cbase + j * 16] = cv.u;
                }
    } else {
        float* C = (float*)d.C + zoff;
        #pragma unroll
        for (int i = 0; i < 4; i++)
            #pragma unroll
            for (int j = 0; j < 4; j++)
                #pragma unroll
                for (int r = 0; r < 4; r++)
                    C[(long long)(rbase + i * 16 + r) * d.ldc + cbase + j * 16] = acc[i][j][r] * d.alpha;
    }
}

// ---------------------------------------------------------------------------
// LN pre: h = LN(x)*g+b; hhf = h; hb_par = hb_seq = bf16(h)
// ---------------------------------------------------------------------------
__global__ __launch_bounds__(256)
void ln_pre_kernel(const float* __restrict__ x, const float* __restrict__ g,
                   const float* __restrict__ b, float* __restrict__ h,
                   float* __restrict__ hhf, u16* __restrict__ hbp, u16* __restrict__ hbs)
{
    int row = blockIdx.x;
    long long base = (long long)row * D_MODEL;
    int tid = threadIdx.x, lane = tid & 63, wave = tid >> 6;
    __shared__ float red[4];
    float v[3]; float s = 0.f;
    #pragma unroll
    for (int k = 0; k < 3; k++) { v[k] = x[base + tid + k * 256]; s += v[k]; }
    s = wred_sum(s);
    if (lane == 0) red[wave] = s;
    __syncthreads();
    float mean = (red[0] + red[1] + red[2] + red[3]) * (1.f / D_MODEL);
    __syncthreads();
    float sq = 0.f;
    #pragma unroll
    for (int k = 0; k < 3; k++) { float dd = v[k] - mean; sq += dd * dd; }
    sq = wred_sum(sq);
    if (lane == 0) red[wave] = sq;
    __syncthreads();
    float var = (red[0] + red[1] + red[2] + red[3]) * (1.f / D_MODEL);
    float rstd = rsqrtf(var + 1e-5f);
    #pragma unroll
    for (int k = 0; k < 3; k++) {
        int c = tid + k * 256;
        float o = (v[k] - mean) * rstd * g[c] + b[c];
        h[base + c] = o; hhf[base + c] = o;
        u16 w = f2bf(o);
        hbp[base + c] = w; hbs[base + c] = w;
    }
}

// ---------------------------------------------------------------------------
// bf16 transpose, dual output: htp/hts[b][d][t] = hb[b][t][d]
// ---------------------------------------------------------------------------
__global__ __launch_bounds__(256)
void transpose2_kernel(const u16* __restrict__ hb, u16* __restrict__ htp,
                       u16* __restrict__ hts)
{
    __shared__ u16 tile[32][33];
    int b = blockIdx.z;
    int d0 = blockIdx.x * 32, t0 = blockIdx.y * 32;
    int tx = threadIdx.x & 31, ty = threadIdx.x >> 5;
    long long bb = (long long)b * T_SEQ * D_MODEL;
    #pragma unroll
    for (int i = 0; i < 32; i += 8)
        tile[ty + i][tx] = hb[bb + (long long)(t0 + ty + i) * D_MODEL + d0 + tx];
    __syncthreads();
    #pragma unroll
    for (int i = 0; i < 32; i += 8) {
        long long o = bb + (long long)(d0 + ty + i) * T_SEQ + t0 + tx;
        u16 w = tile[tx][ty + i];
        htp[o] = w; hts[o] = w;
    }
}

// ---------------------------------------------------------------------------
// causal softmax, f16 in -> bf16 out, in place. grid (T, Z)
// ---------------------------------------------------------------------------
__global__ __launch_bounds__(256)
void softmax_kernel(u16* __restrict__ SP)
{
    int t = blockIdx.x, z = blockIdx.y;
    long long rb = (long long)z * T_SEQ * T_SEQ + (long long)t * T_SEQ;
    u16* row = SP + rb;
    int len = t + 1;
    int tid = threadIdx.x, lane = tid & 63, wave = tid >> 6;
    __shared__ float red[4];

    float ev[4];
    float m = -3.0e38f;
    #pragma unroll
    for (int k = 0; k < 4; k++) {
        int s = tid + k * 256;
        if (s < len) {
            union { u16 u; _Float16 h; } cv; cv.u = row[s];
            ev[k] = (float)cv.h;
        } else ev[k] = -3.0e38f;
        m = fmaxf(m, ev[k]);
    }
    m = wred_max(m);
    if (lane == 0) red[wave] = m;
    __syncthreads();
    m = fmaxf(fmaxf(red[0], red[1]), fmaxf(red[2], red[3]));
    __syncthreads();
    float sum = 0.f;
    #pragma unroll
    for (int k = 0; k < 4; k++) {
        int s = tid + k * 256;
        float e = (s < len) ? __expf(ev[k] - m) : 0.f;
        ev[k] = e; sum += e;
    }
    sum = wred_sum(sum);
    if (lane == 0) red[wave] = sum;
    __syncthreads();
    sum = red[0] + red[1] + red[2] + red[3];
    float inv = 1.f / sum;
    #pragma unroll
    for (int k = 0; k < 4; k++)
        row[tid + k * 256] = f2bf(ev[k] * inv);
}

// ---------------------------------------------------------------------------
// par deltas (all 7 chambers): db[row][i*768+c] = bf16(coef_i * (E_i - h))
// ---------------------------------------------------------------------------
__global__ __launch_bounds__(256)
void delta_par_kernel(const u16* __restrict__ E, const float* __restrict__ h,
                      u16* __restrict__ db,
                      const float* __restrict__ gw, const float* __restrict__ gb,
                      const float* __restrict__ sp)
{
    int row = blockIdx.x;
    long long base = (long long)row * D_MODEL;
    int tid = threadIdx.x, lane = tid & 63, wave = tid >> 6;
    __shared__ float red[NCH][4];
    float hv[3];
    #pragma unroll
    for (int k = 0; k < 3; k++) hv[k] = h[base + tid + k * 256];
    float dot[NCH];
    #pragma unroll
    for (int i = 0; i < NCH; i++) {
        float dd = 0.f;
        #pragma unroll
        for (int k = 0; k < 3; k++) dd += hv[k] * gw[i * D_MODEL + tid + k * 256];
        dot[i] = wred_sum(dd);
    }
    if (lane == 0)
        #pragma unroll
        for (int i = 0; i < NCH; i++) red[i][wave] = dot[i];
    __syncthreads();
    float coef[NCH];
    #pragma unroll
    for (int i = 0; i < NCH; i++) {
        float t = red[i][0] + red[i][1] + red[i][2] + red[i][3];
        float gate = 1.f / (1.f + __expf(-(t + gb[i])));
        coef[i] = log1pf(expf(sp[i])) * chamber_mask(i) * gate;
    }
    #pragma unroll
    for (int i = 0; i < NCH; i++) {
        const u16* Er = E + ((long long)i * ROWS + row) * D_MODEL;
        u16* dr = db + (long long)row * (NCH * D_MODEL) + i * D_MODEL;
        #pragma unroll
        for (int k = 0; k < 3; k++) {
            int c = tid + k * 256;
            dr[c] = f2bf(coef[i] * (bf2f(Er[c]) - hv[k]));
        }
    }
}

// ---------------------------------------------------------------------------
// fused seq delta + transpose: hh' = hh + coef*(E-hh); writes hhf, hb_seq,
// ht_seq. grid (T/32, BATCH), 256 threads, 32 rows x 768 cols per block.
// ---------------------------------------------------------------------------
__global__ __launch_bounds__(256)
void fd_kernel(float* __restrict__ hhf, u16* __restrict__ hb, u16* __restrict__ ht,
               const u16* __restrict__ E,
               const float* __restrict__ gw, const float* __restrict__ gb,
               const float* __restrict__ sp, int ci)
{
    __shared__ u16 tile[32][770];   // stride 770: conflict-free transposed read
    __shared__ float coef[32];
    int tb = blockIdx.x, b = blockIdx.y;
    int t0 = tb * 32;
    long long base = ((long long)b * T_SEQ + t0) * D_MODEL;
    int tid = threadIdx.x;

    // Phase A: per-row gate dot
    int arow = tid >> 3, aj = tid & 7;
    const float* hr = hhf + base + (long long)arow * D_MODEL;
    const float* gr = gw + ci * D_MODEL;
    float dot = 0.f;
    #pragma unroll
    for (int k = 0; k < 96; k++) dot += hr[aj + 8 * k] * gr[aj + 8 * k];
    dot += __shfl_xor(dot, 4);
    dot += __shfl_xor(dot, 2);
    dot += __shfl_xor(dot, 1);
    if (aj == 0) {
        float gate = 1.f / (1.f + __expf(-(dot + gb[ci])));
        coef[arow] = log1pf(expf(sp[ci])) * chamber_mask(ci) * gate;
    }
    __syncthreads();

    // Phase B: update hhf, write hb, stage bf16 into LDS tile
    for (int lr = 0; lr < 32; lr++) {
        float cf = coef[lr];
        long long rb = base + (long long)lr * D_MODEL;
        #pragma unroll
        for (int kk = 0; kk < 3; kk++) {
            int c = tid + kk * 256;
            float v = hhf[rb + c];
            float nh = v + cf * (bf2f(E[rb + c]) - v);
            hhf[rb + c] = nh;
            u16 w = f2bf(nh);
            hb[rb + c] = w;
            tile[lr][c] = w;
        }
    }
    __syncthreads();

    // Phase C: write transposed ht[b][d][t0+tt]
    long long hb2 = (long long)b * T_SEQ * D_MODEL;
    #pragma unroll
    for (int k = 0; k < 96; k++) {
        int u = tid + k * 256;
        int dcol = u >> 5, tt = u & 31;
        ht[hb2 + (long long)dcol * T_SEQ + t0 + tt] = tile[tt][dcol];
    }
}

// ---------------------------------------------------------------------------
__global__ __launch_bounds__(256)
void transw_kernel(const float* __restrict__ W, u16* __restrict__ WT, long long zstride)
{
    __shared__ u16 tile[32][33];
    int z = blockIdx.z;
    int c0 = blockIdx.x * 32, r0 = blockIdx.y * 32;
    int tx = threadIdx.x & 31, ty = threadIdx.x >> 5;
    const float* src = W + (long long)z * D_MODEL * D_MODEL;
    u16* dst = WT + (long long)z * zstride;
    #pragma unroll
    for (int i = 0; i < 32; i += 8)
        tile[ty + i][tx] = f2bf(src[(long long)(r0 + ty + i) * D_MODEL + c0 + tx]);
    __syncthreads();
    #pragma unroll
    for (int i = 0; i < 32; i += 8)
        dst[(long long)(c0 + ty + i) * D_MODEL + r0 + tx] = tile[tx][ty + i];
}

__global__ __launch_bounds__(256)
void cast_kernel(const float* __restrict__ in, u16* __restrict__ outp, int n)
{
    int i = blockIdx.x * 256 + threadIdx.x;
    if (i < n) outp[i] = f2bf(in[i]);
}

// ---------------------------------------------------------------------------
// final: e = (1-mg)*(hhf-h) + mg*par; out = x + rg*(LN(e)*g+b)
// ---------------------------------------------------------------------------
__global__ __launch_bounds__(256)
void final_kernel(const float* __restrict__ x, const float* __restrict__ h,
                  const float* __restrict__ hhf, const float* __restrict__ par,
                  const float* __restrict__ mode_logit, const float* __restrict__ residual_gate,
                  const float* __restrict__ g, const float* __restrict__ b,
                  float* __restrict__ out)
{
    int row = blockIdx.x;
    long long base = (long long)row * D_MODEL;
    int tid = threadIdx.x, lane = tid & 63, wave = tid >> 6;
    __shared__ float red[4];
    float mg = 1.f / (1.f + __expf(-mode_logit[0]));
    float rg = residual_gate[0];
    float e[3]; float s = 0.f;
    #pragma unroll
    for (int k = 0; k < 3; k++) {
        int c = tid + k * 256;
        float v = (1.f - mg) * (hhf[base + c] - h[base + c]) + mg * par[base + c];
        e[k] = v; s += v;
    }
    s = wred_sum(s);
    if (lane == 0) red[wave] = s;
    __syncthreads();
    float mean = (red[0] + red[1] + red[2] + red[3]) * (1.f / D_MODEL);
    __syncthreads();
    float sq = 0.f;
    #pragma unroll
    for (int k = 0; k < 3; k++) { float dd = e[k] - mean; sq += dd * dd; }
    sq = wred_sum(sq);
    if (lane == 0) red[wave] = sq;
    __syncthreads();
    float var = (red[0] + red[1] + red[2] + red[3]) * (1.f / D_MODEL);
    float rstd = rsqrtf(var + 1e-5f);
    #pragma unroll
    for (int k = 0; k < 3; k++) {
        int c = tid + k * 256;
        out[base + c] = x[base + c] + rg * ((e[k] - mean) * rstd * g[c] + b[c]);
    }
}

// ---------------------------------------------------------------------------
extern "C" void kernel_launch(void* const* d_in, const int* in_sizes, int n_in,
                              void* d_out, int out_size, void* d_ws, size_t ws_size,
                              hipStream_t stream)
{
    (void)in_sizes; (void)n_in; (void)out_size; (void)ws_size;
    const float* x             = (const float*)d_in[0];
    const float* Wq            = (const float*)d_in[1];
    const float* Wk            = (const float*)d_in[2];
    const float* gate_w        = (const float*)d_in[3];
    const float* gate_b        = (const float*)d_in[4];
    const float* scale_p       = (const float*)d_in[5];
    const float* merge_W       = (const float*)d_in[6];
    const float* mode_logit    = (const float*)d_in[7];
    const float* residual_gate = (const float*)d_in[8];
    const float* ln_pre_g      = (const float*)d_in[9];
    const float* ln_pre_b      = (const float*)d_in[10];
    const float* ln_post_g     = (const float*)d_in[11];
    const float* ln_post_b     = (const float*)d_in[12];
    float* out = (float*)d_out;

    const long long DD  = (long long)D_MODEL * D_MODEL;   // 589824
    const long long TD  = (long long)T_SEQ * D_MODEL;     // 786432
    const long long TTs = (long long)T_SEQ * T_SEQ;       // 1048576
    const long long RDe = (long long)ROWS * D_MODEL;      // 3145728
    const int KM = NCH * D_MODEL;                         // 5376

    size_t off = 0;
    char* wsb = (char*)d_ws;
    auto alloc = [&](size_t bytes) -> void* {
        void* p = wsb + off; off += (bytes + 255) & ~(size_t)255; return p;
    };
    u16*   Wall  = (u16*)alloc((size_t)NCH * 2 * DD * 2);      // [i][q/k]
    u16*   mgb   = (u16*)alloc((size_t)D_MODEL * KM * 2);
    float* h     = (float*)alloc(RDe * 4);
    float* hhf   = (float*)alloc(RDe * 4);
    float* par   = (float*)alloc(RDe * 4);
    u16*   hb_par= (u16*)alloc(RDe * 2);
    u16*   hb_seq= (u16*)alloc(RDe * 2);
    u16*   ht_par= (u16*)alloc(RDe * 2);
    u16*   ht_seq= (u16*)alloc(RDe * 2);
    u16*   S     = (u16*)alloc((size_t)32 * TTs * 2);          // 4 seq + 28 par slabs
    u16*   qk    = (u16*)alloc((size_t)14 * RDe * 2);          // par q/k; Eall aliases
    u16*   qkb   = (u16*)alloc((size_t)ROWS * 1536 * 2);       // seq q|k
    u16*   Eseq  = (u16*)alloc(RDe * 2);
    u16*   S_par = S + 4 * TTs;
    u16*   Eall  = qk;                                         // alias: qk dead after par scores
    u16*   db    = S_par;                                      // alias: P_par dead after par PV

    const float sc = 1.0f / sqrtf((float)D_MODEL);

    auto mk = [](const u16* A, const u16* B, void* C, int K, int lda, int ldb, int ldc,
                 long long sA1, long long sA2, long long sB1, long long sB2,
                 long long sC1, long long sC2, int zm, int zbase,
                 int gx, int gy, int gz, float alpha, int mode, int flags) -> GDesc {
        GDesc d; d.A=A; d.B=B; d.C=C; d.K=K; d.lda=lda; d.ldb=ldb; d.ldc=ldc;
        d.sA1=sA1; d.sA2=sA2; d.sB1=sB1; d.sB2=sB2; d.sC1=sC1; d.sC2=sC2;
        d.zm=zm; d.zbase=zbase; d.gx=gx; d.gy=gy; d.nblk=gx*gy*gz;
        d.alpha=alpha; d.mode=mode; d.flags=flags; return d;
    };
    auto launch2 = [&](const GDesc& a, const GDesc* f) {
        GPack p; p.d[0] = a; p.n = 1; int total = a.nblk;
        if (f) { p.d[1] = *f; p.n = 2; total += f->nblk; }
        gemm_grouped<<<dim3(total), 256, 0, stream>>>(p);
    };

    // ---- filler descriptors for slots 0..20 (slot = step*3 + {proj,scores,PV})
    GDesc fill[21]; bool have[21] = {};
    {
        // par proj: 14 z, slices gz {3,3,2,2,2,2} -> slots 0..5
        int pgz[6] = {3,3,2,2,2,2}; int zb = 0;
        for (int s = 0; s < 6; s++) {
            fill[s] = mk(hb_par, Wall, qk, D_MODEL, D_MODEL, D_MODEL, D_MODEL,
                         0,0, DD,0, RDe,0, 14, zb, 6, 32, pgz[s], 1.f, 1, 0);
            have[s] = true; zb += pgz[s];
        }
        // par scores: 28 z, slices {5,5,5,5,4,4} -> slots 6..11
        int sgz[6] = {5,5,5,5,4,4}; zb = 0;
        for (int s = 0; s < 6; s++) {
            fill[6+s] = mk(qk, qk + RDe, S_par, D_MODEL, D_MODEL, D_MODEL, T_SEQ,
                           TD, 2*RDe, TD, 2*RDe, TTs, 4*TTs, BATCH, zb,
                           8, 8, sgz[s], sc, 3, 1);
            have[6+s] = true; zb += sgz[s];
        }
        // par PV: 28 z, slices {7,7,7,7} -> slots 14..17
        zb = 0;
        for (int s = 0; s < 4; s++) {
            fill[14+s] = mk(S_par, ht_par, Eall, T_SEQ, T_SEQ, T_SEQ, D_MODEL,
                            TTs, 4*TTs, TD, 0, TD, 4*TD, BATCH, zb,
                            6, 8, 7, 1.f, 1, 2);
            have[14+s] = true; zb += 7;
        }
        // merge: 32 m-tiles, slices gy {11,11,10} -> slots 18..20
        int mgy[3] = {11,11,10}; int yb = 0;
        for (int s = 0; s < 3; s++) {
            fill[18+s] = mk(db + (long long)yb*128*KM, mgb, par + (long long)yb*128*D_MODEL,
                            KM, KM, KM, D_MODEL, 0,0,0,0,0,0, 1, 0,
                            6, mgy[s], 1, 1.f, 0, 0);
            have[18+s] = true; yb += mgy[s];
        }
    }

    // ---- prologue
    ln_pre_kernel<<<ROWS, 256, 0, stream>>>(x, ln_pre_g, ln_pre_b, h, hhf, hb_par, hb_seq);
    transw_kernel<<<dim3(24, 24, NCH), 256, 0, stream>>>(Wq, Wall, 2 * DD);
    transw_kernel<<<dim3(24, 24, NCH), 256, 0, stream>>>(Wk, Wall + DD, 2 * DD);
    cast_kernel<<<((int)(D_MODEL * KM) + 255) / 256, 256, 0, stream>>>(merge_W, mgb, D_MODEL * KM);
    transpose2_kernel<<<dim3(24, 32, BATCH), 256, 0, stream>>>(hb_par, ht_par, ht_seq);

    // ---- seq chain with par filler
    for (int i = 0; i < NCH; i++) {
        GDesc proj = mk(hb_seq, Wall + (long long)i * 2 * DD, qkb,
                        D_MODEL, D_MODEL, D_MODEL, 1536, 0,0, DD,0, 768,0,
                        2, 0, 6, 32, 2, 1.f, 1, 0);
        GDesc scr  = mk(qkb, qkb + 768, S, D_MODEL, 1536, 1536, T_SEQ,
                        (long long)T_SEQ*1536, 0, (long long)T_SEQ*1536, 0, TTs, 0,
                        BATCH, 0, 8, 8, BATCH, sc, 3, 1);
        GDesc pv   = mk(S, ht_seq, Eseq, T_SEQ, T_SEQ, T_SEQ, D_MODEL,
                        TTs, 0, TD, 0, TD, 0, BATCH, 0, 6, 8, BATCH, 1.f, 1, 2);
        int s0 = i * 3;
        launch2(proj, have[s0]     ? &fill[s0]     : nullptr);
        launch2(scr,  have[s0 + 1] ? &fill[s0 + 1] : nullptr);
        softmax_kernel<<<dim3(T_SEQ, i == 4 ? 32 : BATCH), 256, 0, stream>>>(S);
        launch2(pv,   have[s0 + 2] ? &fill[s0 + 2] : nullptr);
        fd_kernel<<<dim3(32, BATCH), 256, 0, stream>>>(hhf, hb_seq, ht_seq, Eseq,
                                                       gate_w, gate_b, scale_p, i);
        if (i == 5)
            delta_par_kernel<<<ROWS, 256, 0, stream>>>(Eall, h, db, gate_w, gate_b, scale_p);
    }

    final_kernel<<<ROWS, 256, 0, stream>>>(x, h, hhf, par, mode_logit, residual_gate,
                                           ln_post_g, ln_post_b, out);
}

// Round 4
// 1227.224 us; speedup vs baseline: 1.1095x; 1.1095x over previous
//
#include <hip/hip_runtime.h>
#include <hip/hip_bf16.h>
#include <math.h>

#define D_MODEL 768
#define T_SEQ   1024
#define BATCH   4
#define NCH     7
#define ROWS    4096            // BATCH*T_SEQ

typedef unsigned short u16;
typedef __attribute__((ext_vector_type(8))) short bh8;   // 8 x bf16
typedef __attribute__((ext_vector_type(4))) float f32x4;

__device__ __forceinline__ u16 f2bf(float f) {
    union { float f; unsigned u; } v; v.f = f;
    return (u16)((v.u + 0x7fffu + ((v.u >> 16) & 1u)) >> 16);  // RNE
}
__device__ __forceinline__ float bf2f(u16 b) {
    union { unsigned u; float f; } v; v.u = ((unsigned)b) << 16;
    return v.f;
}
__device__ __forceinline__ float wred_sum(float v) {
    #pragma unroll
    for (int o = 32; o; o >>= 1) v += __shfl_down(v, o, 64);
    return v;
}
__device__ __forceinline__ float wred_max(float v) {
    #pragma unroll
    for (int o = 32; o; o >>= 1) v = fmaxf(v, __shfl_down(v, o, 64));
    return v;
}
__device__ __forceinline__ float chamber_mask(int i) {
    float slope = 8.0f * 7.0f / 2000.0f;
    return 1.0f / (1.0f + __expf(-slope * (4000.0f - 2000.0f * (i + 0.5f) / 7.0f)));
}

#define GLD16(g, l) __builtin_amdgcn_global_load_lds( \
    (const __attribute__((address_space(1))) void*)(g), \
    (__attribute__((address_space(3))) void*)(l), 16, 0, 0)

// ---------------------------------------------------------------------------
// Generic NT GEMM, BK=64: C[M,N] = alpha * A[M,K] * B[N,K]^T  (bf16 in)
// 128x128 tile, 2x2 waves. BK=64 halves the barrier count vs BK=32 —
// this kernel is grid-starved (1-4 blocks/CU) so per-barrier latency
// exposure dominates; LDS 32KB is free at this occupancy.
// mode: 0 f32 store, 1 bf16 store, 3 f16 store, 4 f32 atomicAdd
// causal_skip: skip bn>bm (QK^T). causal_k: K limited to (bm+1)*128 (PV).
// kss/klen: split-K — k in [bz1*kss, bz1*kss+klen)
// ---------------------------------------------------------------------------
__global__ __launch_bounds__(256)
void gemm_nt_kernel(const u16* __restrict__ A, const u16* __restrict__ B,
                    void* __restrict__ Cv,
                    int K, int lda, int ldb, int ldc,
                    long long sA1, long long sA2, long long sB1, long long sB2,
                    long long sC1, long long sC2, int zm,
                    float alpha, int mode, int causal_skip, int causal_k,
                    int kss, int klen)
{
    int bn = blockIdx.x, bm = blockIdx.y, bz = blockIdx.z;
    if (causal_skip && bn > bm) return;
    int bz1 = bz % zm, bz2 = bz / zm;

    const u16* Ab = A + bz1 * sA1 + bz2 * sA2 + (long long)(bm * 128) * lda;
    const u16* Bb = B + bz1 * sB1 + bz2 * sB2 + (long long)(bn * 128) * ldb;

    __shared__ u16 sm[2 * 128 * 64];       // 32 KB
    u16* Al = sm;
    u16* Bl = sm + 128 * 64;

    int tid  = threadIdx.x;
    int lane = tid & 63;
    int wave = tid >> 6;
    int wm = wave >> 1, wn = wave & 1;

    int k_begin = kss ? bz1 * kss : 0;
    int k_end   = klen ? (k_begin + klen) : K;
    if (causal_k) k_end = min(k_end, (bm + 1) * 128);

    f32x4 acc[4][4];
    #pragma unroll
    for (int i = 0; i < 4; i++)
        #pragma unroll
        for (int j = 0; j < 4; j++)
            acc[i][j] = (f32x4){0.f, 0.f, 0.f, 0.f};

    int srow = lane >> 3;                  // 0..7: row within 8-row group
    int scol = (lane & 7) * 8;             // 16B chunk within 64-elem k-slice
    int fm   = lane & 15;
    int fk   = (lane >> 4) * 8;

    for (int k0 = k_begin; k0 < k_end; k0 += 64) {
        __syncthreads();
        #pragma unroll
        for (int l = 0; l < 4; l++) {
            int row = l * 32 + wave * 8 + srow;
            GLD16(Ab + (long long)row * lda + k0 + scol, Al + row * 64 + scol);
            GLD16(Bb + (long long)row * ldb + k0 + scol, Bl + row * 64 + scol);
        }
        __syncthreads();

        #pragma unroll
        for (int kk = 0; kk < 64; kk += 32) {
            bh8 af[4], bf[4];
            #pragma unroll
            for (int i = 0; i < 4; i++)
                af[i] = *(const bh8*)(Al + (wm * 64 + i * 16 + fm) * 64 + kk + fk);
            #pragma unroll
            for (int j = 0; j < 4; j++)
                bf[j] = *(const bh8*)(Bl + (wn * 64 + j * 16 + fm) * 64 + kk + fk);
            #pragma unroll
            for (int i = 0; i < 4; i++)
                #pragma unroll
                for (int j = 0; j < 4; j++)
                    acc[i][j] = __builtin_amdgcn_mfma_f32_16x16x32_bf16(af[i], bf[j], acc[i][j], 0, 0, 0);
        }
    }

    int rbase = bm * 128 + wm * 64 + (lane >> 4) * 4;
    int cbase = bn * 128 + wn * 64 + (lane & 15);
    long long zoff = bz1 * sC1 + bz2 * sC2;
    if (mode == 1) {
        u16* C = (u16*)Cv + zoff;
        #pragma unroll
        for (int i = 0; i < 4; i++)
            #pragma unroll
            for (int j = 0; j < 4; j++)
                #pragma unroll
                for (int r = 0; r < 4; r++)
                    C[(long long)(rbase + i * 16 + r) * ldc + cbase + j * 16] = f2bf(acc[i][j][r] * alpha);
    } else if (mode == 3) {
        u16* C = (u16*)Cv + zoff;
        #pragma unroll
        for (int i = 0; i < 4; i++)
            #pragma unroll
            for (int j = 0; j < 4; j++)
                #pragma unroll
                for (int r = 0; r < 4; r++) {
                    union { _Float16 h; u16 u; } cv;
                    cv.h = (_Float16)(acc[i][j][r] * alpha);
                    C[(long long)(rbase + i * 16 + r) * ldc + cbase + j * 16] = cv.u;
                }
    } else if (mode == 0) {
        float* C = (float*)Cv + zoff;
        #pragma unroll
        for (int i = 0; i < 4; i++)
            #pragma unroll
            for (int j = 0; j < 4; j++)
                #pragma unroll
                for (int r = 0; r < 4; r++)
                    C[(long long)(rbase + i * 16 + r) * ldc + cbase + j * 16] = acc[i][j][r] * alpha;
    } else {
        float* C = (float*)Cv + zoff;
        #pragma unroll
        for (int i = 0; i < 4; i++)
            #pragma unroll
            for (int j = 0; j < 4; j++)
                #pragma unroll
                for (int r = 0; r < 4; r++)
                    atomicAdd(&C[(long long)(rbase + i * 16 + r) * ldc + cbase + j * 16],
                              acc[i][j][r] * alpha);
    }
}

// ---------------------------------------------------------------------------
// LN pre: h = LN(x)*g+b; hhf = h; hb = bf16(h)
// ---------------------------------------------------------------------------
__global__ __launch_bounds__(256)
void ln_pre_kernel(const float* __restrict__ x, const float* __restrict__ g,
                   const float* __restrict__ b, float* __restrict__ h,
                   float* __restrict__ hhf, u16* __restrict__ hb)
{
    int row = blockIdx.x;
    long long base = (long long)row * D_MODEL;
    int tid = threadIdx.x, lane = tid & 63, wave = tid >> 6;
    __shared__ float red[4];
    float v[3]; float s = 0.f;
    #pragma unroll
    for (int k = 0; k < 3; k++) { v[k] = x[base + tid + k * 256]; s += v[k]; }
    s = wred_sum(s);
    if (lane == 0) red[wave] = s;
    __syncthreads();
    float mean = (red[0] + red[1] + red[2] + red[3]) * (1.f / D_MODEL);
    __syncthreads();
    float sq = 0.f;
    #pragma unroll
    for (int k = 0; k < 3; k++) { float dd = v[k] - mean; sq += dd * dd; }
    sq = wred_sum(sq);
    if (lane == 0) red[wave] = sq;
    __syncthreads();
    float var = (red[0] + red[1] + red[2] + red[3]) * (1.f / D_MODEL);
    float rstd = rsqrtf(var + 1e-5f);
    #pragma unroll
    for (int k = 0; k < 3; k++) {
        int c = tid + k * 256;
        float o = (v[k] - mean) * rstd * g[c] + b[c];
        h[base + c] = o; hhf[base + c] = o; hb[base + c] = f2bf(o);
    }
}

// ---------------------------------------------------------------------------
// bf16 transpose: ht[b][d][t] = hb[b][t][d]
// ---------------------------------------------------------------------------
__global__ __launch_bounds__(256)
void transpose_kernel(const u16* __restrict__ hb, u16* __restrict__ ht)
{
    __shared__ u16 tile[32][33];
    int b = blockIdx.z;
    int d0 = blockIdx.x * 32, t0 = blockIdx.y * 32;
    int tx = threadIdx.x & 31, ty = threadIdx.x >> 5;
    long long bb = (long long)b * T_SEQ * D_MODEL;
    #pragma unroll
    for (int i = 0; i < 32; i += 8)
        tile[ty + i][tx] = hb[bb + (long long)(t0 + ty + i) * D_MODEL + d0 + tx];
    __syncthreads();
    #pragma unroll
    for (int i = 0; i < 32; i += 8)
        ht[bb + (long long)(d0 + ty + i) * T_SEQ + t0 + tx] = tile[tx][ty + i];
}

// ---------------------------------------------------------------------------
// causal softmax, f16 in -> bf16 out, in place. grid (T, Z)
// ---------------------------------------------------------------------------
__global__ __launch_bounds__(256)
void softmax_kernel(u16* __restrict__ SP)
{
    int t = blockIdx.x, z = blockIdx.y;
    long long rb = (long long)z * T_SEQ * T_SEQ + (long long)t * T_SEQ;
    u16* row = SP + rb;
    int len = t + 1;
    int tid = threadIdx.x, lane = tid & 63, wave = tid >> 6;
    __shared__ float red[4];

    float ev[4];
    float m = -3.0e38f;
    #pragma unroll
    for (int k = 0; k < 4; k++) {
        int s = tid + k * 256;
        if (s < len) {
            union { u16 u; _Float16 h; } cv; cv.u = row[s];
            ev[k] = (float)cv.h;
        } else ev[k] = -3.0e38f;
        m = fmaxf(m, ev[k]);
    }
    m = wred_max(m);
    if (lane == 0) red[wave] = m;
    __syncthreads();
    m = fmaxf(fmaxf(red[0], red[1]), fmaxf(red[2], red[3]));
    __syncthreads();
    float sum = 0.f;
    #pragma unroll
    for (int k = 0; k < 4; k++) {
        int s = tid + k * 256;
        float e = (s < len) ? __expf(ev[k] - m) : 0.f;
        ev[k] = e; sum += e;
    }
    sum = wred_sum(sum);
    if (lane == 0) red[wave] = sum;
    __syncthreads();
    sum = red[0] + red[1] + red[2] + red[3];
    float inv = 1.f / sum;
    #pragma unroll
    for (int k = 0; k < 4; k++)
        row[tid + k * 256] = f2bf(ev[k] * inv);
}

// ---------------------------------------------------------------------------
// par deltas (all 7 chambers): db[row][i*768+c] = bf16(coef_i * (E_i - h))
// ---------------------------------------------------------------------------
__global__ __launch_bounds__(256)
void delta_par_kernel(const u16* __restrict__ E, const float* __restrict__ h,
                      u16* __restrict__ db,
                      const float* __restrict__ gw, const float* __restrict__ gb,
                      const float* __restrict__ sp)
{
    int row = blockIdx.x;
    long long base = (long long)row * D_MODEL;
    int tid = threadIdx.x, lane = tid & 63, wave = tid >> 6;
    __shared__ float red[NCH][4];
    float hv[3];
    #pragma unroll
    for (int k = 0; k < 3; k++) hv[k] = h[base + tid + k * 256];
    float dot[NCH];
    #pragma unroll
    for (int i = 0; i < NCH; i++) {
        float dd = 0.f;
        #pragma unroll
        for (int k = 0; k < 3; k++) dd += hv[k] * gw[i * D_MODEL + tid + k * 256];
        dot[i] = wred_sum(dd);
    }
    if (lane == 0)
        #pragma unroll
        for (int i = 0; i < NCH; i++) red[i][wave] = dot[i];
    __syncthreads();
    float coef[NCH];
    #pragma unroll
    for (int i = 0; i < NCH; i++) {
        float t = red[i][0] + red[i][1] + red[i][2] + red[i][3];
        float gate = 1.f / (1.f + __expf(-(t + gb[i])));
        coef[i] = log1pf(expf(sp[i])) * chamber_mask(i) * gate;
    }
    #pragma unroll
    for (int i = 0; i < NCH; i++) {
        const u16* Er = E + ((long long)i * ROWS + row) * D_MODEL;
        u16* dr = db + (long long)row * (NCH * D_MODEL) + i * D_MODEL;
        #pragma unroll
        for (int k = 0; k < 3; k++) {
            int c = tid + k * 256;
            dr[c] = f2bf(coef[i] * (bf2f(Er[c]) - hv[k]));
        }
    }
}

// ---------------------------------------------------------------------------
// fused seq delta + transpose: hh' = hh + coef*(E-hh); writes hhf, hb, ht.
// grid (T/32, BATCH), 256 threads, 32 rows x 768 cols per block.
// ---------------------------------------------------------------------------
__global__ __launch_bounds__(256)
void fd_kernel(float* __restrict__ hhf, u16* __restrict__ hb, u16* __restrict__ ht,
               const u16* __restrict__ E,
               const float* __restrict__ gw, const float* __restrict__ gb,
               const float* __restrict__ sp, int ci)
{
    __shared__ u16 tile[32][770];   // stride 770: conflict-free transposed read
    __shared__ float coef[32];
    int tb = blockIdx.x, b = blockIdx.y;
    int t0 = tb * 32;
    long long base = ((long long)b * T_SEQ + t0) * D_MODEL;
    int tid = threadIdx.x;

    // Phase A: per-row gate dot (8 lanes per row)
    int arow = tid >> 3, aj = tid & 7;
    const float* hr = hhf + base + (long long)arow * D_MODEL;
    const float* gr = gw + ci * D_MODEL;
    float dot = 0.f;
    #pragma unroll
    for (int k = 0; k < 96; k++) dot += hr[aj + 8 * k] * gr[aj + 8 * k];
    dot += __shfl_xor(dot, 4);
    dot += __shfl_xor(dot, 2);
    dot += __shfl_xor(dot, 1);
    if (aj == 0) {
        float gate = 1.f / (1.f + __expf(-(dot + gb[ci])));
        coef[arow] = log1pf(expf(sp[ci])) * chamber_mask(ci) * gate;
    }
    __syncthreads();

    // Phase B: update hhf, write hb, stage bf16 into LDS tile
    for (int lr = 0; lr < 32; lr++) {
        float cf = coef[lr];
        long long rb = base + (long long)lr * D_MODEL;
        #pragma unroll
        for (int kk = 0; kk < 3; kk++) {
            int c = tid + kk * 256;
            float v = hhf[rb + c];
            float nh = v + cf * (bf2f(E[rb + c]) - v);
            hhf[rb + c] = nh;
            u16 w = f2bf(nh);
            hb[rb + c] = w;
            tile[lr][c] = w;
        }
    }
    __syncthreads();

    // Phase C: write transposed ht[b][d][t0+tt]
    long long hb2 = (long long)b * T_SEQ * D_MODEL;
    #pragma unroll
    for (int k = 0; k < 96; k++) {
        int u = tid + k * 256;
        int dcol = u >> 5, tt = u & 31;
        ht[hb2 + (long long)dcol * T_SEQ + t0 + tt] = tile[tt][dcol];
    }
}

// ---------------------------------------------------------------------------
__global__ __launch_bounds__(256)
void transw_kernel(const float* __restrict__ W, u16* __restrict__ WT, long long zstride)
{
    __shared__ u16 tile[32][33];
    int z = blockIdx.z;
    int c0 = blockIdx.x * 32, r0 = blockIdx.y * 32;
    int tx = threadIdx.x & 31, ty = threadIdx.x >> 5;
    const float* src = W + (long long)z * D_MODEL * D_MODEL;
    u16* dst = WT + (long long)z * zstride;
    #pragma unroll
    for (int i = 0; i < 32; i += 8)
        tile[ty + i][tx] = f2bf(src[(long long)(r0 + ty + i) * D_MODEL + c0 + tx]);
    __syncthreads();
    #pragma unroll
    for (int i = 0; i < 32; i += 8)
        dst[(long long)(c0 + ty + i) * D_MODEL + r0 + tx] = tile[tx][ty + i];
}

__global__ __launch_bounds__(256)
void cast_kernel(const float* __restrict__ in, u16* __restrict__ outp, int n)
{
    int i = blockIdx.x * 256 + threadIdx.x;
    if (i < n) outp[i] = f2bf(in[i]);
}

// ---------------------------------------------------------------------------
// final: e = (1-mg)*(hhf-h) + mg*par; out = x + rg*(LN(e)*g+b)
// ---------------------------------------------------------------------------
__global__ __launch_bounds__(256)
void final_kernel(const float* __restrict__ x, const float* __restrict__ h,
                  const float* __restrict__ hhf, const float* __restrict__ par,
                  const float* __restrict__ mode_logit, const float* __restrict__ residual_gate,
                  const float* __restrict__ g, const float* __restrict__ b,
                  float* __restrict__ out)
{
    int row = blockIdx.x;
    long long base = (long long)row * D_MODEL;
    int tid = threadIdx.x, lane = tid & 63, wave = tid >> 6;
    __shared__ float red[4];
    float mg = 1.f / (1.f + __expf(-mode_logit[0]));
    float rg = residual_gate[0];
    float e[3]; float s = 0.f;
    #pragma unroll
    for (int k = 0; k < 3; k++) {
        int c = tid + k * 256;
        float v = (1.f - mg) * (hhf[base + c] - h[base + c]) + mg * par[base + c];
        e[k] = v; s += v;
    }
    s = wred_sum(s);
    if (lane == 0) red[wave] = s;
    __syncthreads();
    float mean = (red[0] + red[1] + red[2] + red[3]) * (1.f / D_MODEL);
    __syncthreads();
    float sq = 0.f;
    #pragma unroll
    for (int k = 0; k < 3; k++) { float dd = e[k] - mean; sq += dd * dd; }
    sq = wred_sum(sq);
    if (lane == 0) red[wave] = sq;
    __syncthreads();
    float var = (red[0] + red[1] + red[2] + red[3]) * (1.f / D_MODEL);
    float rstd = rsqrtf(var + 1e-5f);
    #pragma unroll
    for (int k = 0; k < 3; k++) {
        int c = tid + k * 256;
        out[base + c] = x[base + c] + rg * ((e[k] - mean) * rstd * g[c] + b[c]);
    }
}

// ---------------------------------------------------------------------------
extern "C" void kernel_launch(void* const* d_in, const int* in_sizes, int n_in,
                              void* d_out, int out_size, void* d_ws, size_t ws_size,
                              hipStream_t stream)
{
    (void)in_sizes; (void)n_in; (void)out_size; (void)ws_size;
    const float* x             = (const float*)d_in[0];
    const float* Wq            = (const float*)d_in[1];
    const float* Wk            = (const float*)d_in[2];
    const float* gate_w        = (const float*)d_in[3];
    const float* gate_b        = (const float*)d_in[4];
    const float* scale_p       = (const float*)d_in[5];
    const float* merge_W       = (const float*)d_in[6];
    const float* mode_logit    = (const float*)d_in[7];
    const float* residual_gate = (const float*)d_in[8];
    const float* ln_pre_g      = (const float*)d_in[9];
    const float* ln_pre_b      = (const float*)d_in[10];
    const float* ln_post_g     = (const float*)d_in[11];
    const float* ln_post_b     = (const float*)d_in[12];
    float* out = (float*)d_out;

    const long long DD  = (long long)D_MODEL * D_MODEL;   // 589824
    const long long TD  = (long long)T_SEQ * D_MODEL;     // 786432
    const long long TTs = (long long)T_SEQ * T_SEQ;       // 1048576
    const long long RDe = (long long)ROWS * D_MODEL;      // 3145728
    const int KM = NCH * D_MODEL;                         // 5376

    size_t off = 0;
    char* wsb = (char*)d_ws;
    auto alloc = [&](size_t bytes) -> void* {
        void* p = wsb + off; off += (bytes + 255) & ~(size_t)255; return p;
    };
    u16*  Wall = (u16*)alloc((size_t)NCH * 2 * DD * 2);        // [i][q/k][768][768]
    u16*  mgb  = (u16*)alloc((size_t)D_MODEL * KM * 2);        // merge_W bf16
    float* h   = (float*)alloc(RDe * 4);
    float* hhf = (float*)alloc(RDe * 4);                       // h + seq (running)
    float* par = (float*)alloc(RDe * 4);
    u16*  hb   = (u16*)alloc(RDe * 2);
    u16*  ht   = (u16*)alloc(RDe * 2);
    u16*  S    = (u16*)alloc((size_t)(NCH * BATCH) * TTs * 2); // f16 scores -> bf16 P
    u16*  qk   = (u16*)alloc((size_t)(NCH * 2) * RDe * 2);     // par q/k; Eall aliases
    u16*  qkb  = (u16*)alloc((size_t)ROWS * 1536 * 2);         // seq q|k
    u16*  Eseq = (u16*)alloc(RDe * 2);
    u16*  Eall = qk;                                           // alias: qk dead after par scores
    u16*  db   = S;                                            // alias: P dead after par PV

    const float sc = 1.0f / sqrtf((float)D_MODEL);

    hipMemsetAsync(par, 0, RDe * 4, stream);                   // split-K atomic target

    ln_pre_kernel<<<ROWS, 256, 0, stream>>>(x, ln_pre_g, ln_pre_b, h, hhf, hb);
    transw_kernel<<<dim3(24, 24, NCH), 256, 0, stream>>>(Wq, Wall, 2 * DD);
    transw_kernel<<<dim3(24, 24, NCH), 256, 0, stream>>>(Wk, Wall + DD, 2 * DD);
    cast_kernel<<<((int)(D_MODEL * KM) + 255) / 256, 256, 0, stream>>>(merge_W, mgb, D_MODEL * KM);
    transpose_kernel<<<dim3(24, 32, BATCH), 256, 0, stream>>>(hb, ht);

    // ======================= par branch (batched over chambers) ==============
    gemm_nt_kernel<<<dim3(6, 32, 2 * NCH), 256, 0, stream>>>(
        hb, Wall, qk, D_MODEL, D_MODEL, D_MODEL, D_MODEL,
        0, 0, DD, 0, RDe, 0, 2 * NCH, 1.f, 1, 0, 0, 0, 0);
    gemm_nt_kernel<<<dim3(8, 8, BATCH * NCH), 256, 0, stream>>>(
        qk, qk + RDe, S, D_MODEL, D_MODEL, D_MODEL, T_SEQ,
        TD, 2 * RDe, TD, 2 * RDe, TTs, 4 * TTs, BATCH, sc, 3, 1, 0, 0, 0);
    softmax_kernel<<<dim3(T_SEQ, BATCH * NCH), 256, 0, stream>>>(S);
    gemm_nt_kernel<<<dim3(6, 8, BATCH * NCH), 256, 0, stream>>>(
        S, ht, Eall, T_SEQ, T_SEQ, T_SEQ, D_MODEL,
        TTs, 4 * TTs, TD, 0, TD, 4 * TD, BATCH, 1.f, 1, 0, 1, 0, 0);
    delta_par_kernel<<<ROWS, 256, 0, stream>>>(Eall, h, db, gate_w, gate_b, scale_p);
    // merge: par += db @ mgb^T, split-K x4 with atomic accumulate (1344 % 64 == 0)
    gemm_nt_kernel<<<dim3(6, 32, 4), 256, 0, stream>>>(
        db, mgb, par, KM, KM, KM, D_MODEL,
        0, 0, 0, 0, 0, 0, 4, 1.f, 4, 0, 0, KM / 4, KM / 4);

    // ======================= seq branch (serial chain) =======================
    for (int i = 0; i < NCH; i++) {
        gemm_nt_kernel<<<dim3(6, 32, 2), 256, 0, stream>>>(
            hb, Wall + (long long)i * 2 * DD, qkb, D_MODEL, D_MODEL, D_MODEL, 1536,
            0, 0, DD, 0, 768, 0, 2, 1.f, 1, 0, 0, 0, 0);
        gemm_nt_kernel<<<dim3(8, 8, BATCH), 256, 0, stream>>>(
            qkb, qkb + 768, S, D_MODEL, 1536, 1536, T_SEQ,
            (long long)T_SEQ * 1536, 0, (long long)T_SEQ * 1536, 0, TTs, 0, BATCH,
            sc, 3, 1, 0, 0, 0);
        softmax_kernel<<<dim3(T_SEQ, BATCH), 256, 0, stream>>>(S);
        gemm_nt_kernel<<<dim3(6, 8, BATCH), 256, 0, stream>>>(
            S, ht, Eseq, T_SEQ, T_SEQ, T_SEQ, D_MODEL,
            TTs, 0, TD, 0, TD, 0, BATCH, 1.f, 1, 0, 1, 0, 0);
        fd_kernel<<<dim3(32, BATCH), 256, 0, stream>>>(hhf, hb, ht, Eseq,
                                                       gate_w, gate_b, scale_p, i);
    }

    final_kernel<<<ROWS, 256, 0, stream>>>(x, h, hhf, par, mode_logit, residual_gate,
                                           ln_post_g, ln_post_b, out);
}

// Round 5
// 1141.704 us; speedup vs baseline: 1.1926x; 1.0749x over previous
//
#include <hip/hip_runtime.h>
#include <hip/hip_bf16.h>
#include <math.h>

#define D_MODEL 768
#define T_SEQ   1024
#define BATCH   4
#define NCH     7
#define ROWS    4096            // BATCH*T_SEQ

typedef unsigned short u16;
typedef __attribute__((ext_vector_type(8))) short bh8;   // 8 x bf16
typedef __attribute__((ext_vector_type(4))) float f32x4;

__device__ __forceinline__ u16 f2bf(float f) {
    union { float f; unsigned u; } v; v.f = f;
    return (u16)((v.u + 0x7fffu + ((v.u >> 16) & 1u)) >> 16);  // RNE
}
__device__ __forceinline__ float bf2f(u16 b) {
    union { unsigned u; float f; } v; v.u = ((unsigned)b) << 16;
    return v.f;
}
__device__ __forceinline__ float wred_sum(float v) {
    #pragma unroll
    for (int o = 32; o; o >>= 1) v += __shfl_down(v, o, 64);
    return v;
}
__device__ __forceinline__ float wred_max(float v) {
    #pragma unroll
    for (int o = 32; o; o >>= 1) v = fmaxf(v, __shfl_down(v, o, 64));
    return v;
}
__device__ __forceinline__ float chamber_mask(int i) {
    float slope = 8.0f * 7.0f / 2000.0f;
    return 1.0f / (1.0f + __expf(-slope * (4000.0f - 2000.0f * (i + 0.5f) / 7.0f)));
}

#define GLD16(g, l) __builtin_amdgcn_global_load_lds( \
    (const __attribute__((address_space(1))) void*)(g), \
    (__attribute__((address_space(3))) void*)(l), 16, 0, 0)

// ---------------------------------------------------------------------------
// 128x128-tile NT GEMM, BK=32 (R2-proven): C = alpha * A[M,K] * B[N,K]^T
// Used for the chamber-batched par branch (plenty of z-parallelism).
// mode: 0 f32 store, 1 bf16 store, 3 f16 store, 4 f32 atomicAdd
// ---------------------------------------------------------------------------
__global__ __launch_bounds__(256)
void gemm_nt_kernel(const u16* __restrict__ A, const u16* __restrict__ B,
                    void* __restrict__ Cv,
                    int K, int lda, int ldb, int ldc,
                    long long sA1, long long sA2, long long sB1, long long sB2,
                    long long sC1, long long sC2, int zm,
                    float alpha, int mode, int causal_skip, int causal_k,
                    int kss, int klen)
{
    int bn = blockIdx.x, bm = blockIdx.y, bz = blockIdx.z;
    if (causal_skip && bn > bm) return;
    int bz1 = bz % zm, bz2 = bz / zm;

    const u16* Ab = A + bz1 * sA1 + bz2 * sA2 + (long long)(bm * 128) * lda;
    const u16* Bb = B + bz1 * sB1 + bz2 * sB2 + (long long)(bn * 128) * ldb;

    __shared__ u16 sm[2 * 128 * 32];
    u16* Al = sm;
    u16* Bl = sm + 128 * 32;

    int tid  = threadIdx.x;
    int lane = tid & 63;
    int wave = tid >> 6;
    int wm = wave >> 1, wn = wave & 1;

    int k_begin = kss ? bz1 * kss : 0;
    int k_end   = klen ? (k_begin + klen) : K;
    if (causal_k) k_end = min(k_end, (bm + 1) * 128);

    f32x4 acc[4][4];
    #pragma unroll
    for (int i = 0; i < 4; i++)
        #pragma unroll
        for (int j = 0; j < 4; j++)
            acc[i][j] = (f32x4){0.f, 0.f, 0.f, 0.f};

    int srow = lane >> 2;
    int skq  = (lane & 3) * 8;
    int fm   = lane & 15;
    int fk   = (lane >> 4) * 8;

    for (int k0 = k_begin; k0 < k_end; k0 += 32) {
        __syncthreads();
        #pragma unroll
        for (int r = 0; r < 2; r++) {
            int row = r * 64 + wave * 16 + srow;
            GLD16(Ab + (long long)row * lda + k0 + skq, Al + row * 32 + skq);
            GLD16(Bb + (long long)row * ldb + k0 + skq, Bl + row * 32 + skq);
        }
        __syncthreads();

        bh8 af[4], bf[4];
        #pragma unroll
        for (int i = 0; i < 4; i++)
            af[i] = *(const bh8*)(Al + (wm * 64 + i * 16 + fm) * 32 + fk);
        #pragma unroll
        for (int j = 0; j < 4; j++)
            bf[j] = *(const bh8*)(Bl + (wn * 64 + j * 16 + fm) * 32 + fk);
        #pragma unroll
        for (int i = 0; i < 4; i++)
            #pragma unroll
            for (int j = 0; j < 4; j++)
                acc[i][j] = __builtin_amdgcn_mfma_f32_16x16x32_bf16(af[i], bf[j], acc[i][j], 0, 0, 0);
    }

    int rbase = bm * 128 + wm * 64 + (lane >> 4) * 4;
    int cbase = bn * 128 + wn * 64 + (lane & 15);
    long long zoff = bz1 * sC1 + bz2 * sC2;
    if (mode == 1) {
        u16* C = (u16*)Cv + zoff;
        #pragma unroll
        for (int i = 0; i < 4; i++)
            #pragma unroll
            for (int j = 0; j < 4; j++)
                #pragma unroll
                for (int r = 0; r < 4; r++)
                    C[(long long)(rbase + i * 16 + r) * ldc + cbase + j * 16] = f2bf(acc[i][j][r] * alpha);
    } else if (mode == 3) {
        u16* C = (u16*)Cv + zoff;
        #pragma unroll
        for (int i = 0; i < 4; i++)
            #pragma unroll
            for (int j = 0; j < 4; j++)
                #pragma unroll
                for (int r = 0; r < 4; r++) {
                    union { _Float16 h; u16 u; } cv;
                    cv.h = (_Float16)(acc[i][j][r] * alpha);
                    C[(long long)(rbase + i * 16 + r) * ldc + cbase + j * 16] = cv.u;
                }
    } else if (mode == 0) {
        float* C = (float*)Cv + zoff;
        #pragma unroll
        for (int i = 0; i < 4; i++)
            #pragma unroll
            for (int j = 0; j < 4; j++)
                #pragma unroll
                for (int r = 0; r < 4; r++)
                    C[(long long)(rbase + i * 16 + r) * ldc + cbase + j * 16] = acc[i][j][r] * alpha;
    } else {
        float* C = (float*)Cv + zoff;
        #pragma unroll
        for (int i = 0; i < 4; i++)
            #pragma unroll
            for (int j = 0; j < 4; j++)
                #pragma unroll
                for (int r = 0; r < 4; r++)
                    atomicAdd(&C[(long long)(rbase + i * 16 + r) * ldc + cbase + j * 16],
                              acc[i][j][r] * alpha);
    }
}

// ---------------------------------------------------------------------------
// 64x64-tile NT GEMM, BK=32 — for the grid-starved seq-chain GEMMs.
// 4 waves, each owns a 16x64 slab (1 A-frag, 4 B-frags, 4 acc). 8 KB LDS,
// ~8 blocks/CU schedulable: 4x the block count of the 128-tile kernel.
// causal flags on 64-granularity: skip bn>bm; K <= (bm+1)*64.
// ---------------------------------------------------------------------------
__global__ __launch_bounds__(256)
void gemm64_nt_kernel(const u16* __restrict__ A, const u16* __restrict__ B,
                      void* __restrict__ Cv,
                      int K, int lda, int ldb, int ldc,
                      long long sA, long long sB, long long sC,
                      float alpha, int mode, int causal_skip, int causal_k)
{
    int bn = blockIdx.x, bm = blockIdx.y, bz = blockIdx.z;
    if (causal_skip && bn > bm) return;

    const u16* Ab = A + bz * sA + (long long)(bm * 64) * lda;
    const u16* Bb = B + bz * sB + (long long)(bn * 64) * ldb;

    __shared__ u16 sm[2 * 64 * 32];    // 8 KB
    u16* Al = sm;
    u16* Bl = sm + 64 * 32;

    int tid  = threadIdx.x;
    int lane = tid & 63;
    int wave = tid >> 6;

    int k_end = causal_k ? min(K, (bm + 1) * 64) : K;

    f32x4 acc[4];
    #pragma unroll
    for (int j = 0; j < 4; j++) acc[j] = (f32x4){0.f, 0.f, 0.f, 0.f};

    int srow   = tid >> 2;             // 0..63
    int schunk = (tid & 3) * 8;
    int fm     = lane & 15;
    int fk     = (lane >> 4) * 8;

    for (int k0 = 0; k0 < k_end; k0 += 32) {
        __syncthreads();
        GLD16(Ab + (long long)srow * lda + k0 + schunk, Al + srow * 32 + schunk);
        GLD16(Bb + (long long)srow * ldb + k0 + schunk, Bl + srow * 32 + schunk);
        __syncthreads();

        bh8 af = *(const bh8*)(Al + (wave * 16 + fm) * 32 + fk);
        bh8 bf[4];
        #pragma unroll
        for (int j = 0; j < 4; j++)
            bf[j] = *(const bh8*)(Bl + (j * 16 + fm) * 32 + fk);
        #pragma unroll
        for (int j = 0; j < 4; j++)
            acc[j] = __builtin_amdgcn_mfma_f32_16x16x32_bf16(af, bf[j], acc[j], 0, 0, 0);
    }

    int rbase = bm * 64 + wave * 16 + (lane >> 4) * 4;
    int cbase = bn * 64 + (lane & 15);
    long long zoff = (long long)bz * sC;
    if (mode == 1) {
        u16* C = (u16*)Cv + zoff;
        #pragma unroll
        for (int j = 0; j < 4; j++)
            #pragma unroll
            for (int r = 0; r < 4; r++)
                C[(long long)(rbase + r) * ldc + cbase + j * 16] = f2bf(acc[j][r] * alpha);
    } else if (mode == 3) {
        u16* C = (u16*)Cv + zoff;
        #pragma unroll
        for (int j = 0; j < 4; j++)
            #pragma unroll
            for (int r = 0; r < 4; r++) {
                union { _Float16 h; u16 u; } cv;
                cv.h = (_Float16)(acc[j][r] * alpha);
                C[(long long)(rbase + r) * ldc + cbase + j * 16] = cv.u;
            }
    } else {
        float* C = (float*)Cv + zoff;
        #pragma unroll
        for (int j = 0; j < 4; j++)
            #pragma unroll
            for (int r = 0; r < 4; r++)
                C[(long long)(rbase + r) * ldc + cbase + j * 16] = acc[j][r] * alpha;
    }
}

// ---------------------------------------------------------------------------
// LN pre: h = LN(x)*g+b; hhf = h; hb = bf16(h)
// ---------------------------------------------------------------------------
__global__ __launch_bounds__(256)
void ln_pre_kernel(const float* __restrict__ x, const float* __restrict__ g,
                   const float* __restrict__ b, float* __restrict__ h,
                   float* __restrict__ hhf, u16* __restrict__ hb)
{
    int row = blockIdx.x;
    long long base = (long long)row * D_MODEL;
    int tid = threadIdx.x, lane = tid & 63, wave = tid >> 6;
    __shared__ float red[4];
    float v[3]; float s = 0.f;
    #pragma unroll
    for (int k = 0; k < 3; k++) { v[k] = x[base + tid + k * 256]; s += v[k]; }
    s = wred_sum(s);
    if (lane == 0) red[wave] = s;
    __syncthreads();
    float mean = (red[0] + red[1] + red[2] + red[3]) * (1.f / D_MODEL);
    __syncthreads();
    float sq = 0.f;
    #pragma unroll
    for (int k = 0; k < 3; k++) { float dd = v[k] - mean; sq += dd * dd; }
    sq = wred_sum(sq);
    if (lane == 0) red[wave] = sq;
    __syncthreads();
    float var = (red[0] + red[1] + red[2] + red[3]) * (1.f / D_MODEL);
    float rstd = rsqrtf(var + 1e-5f);
    #pragma unroll
    for (int k = 0; k < 3; k++) {
        int c = tid + k * 256;
        float o = (v[k] - mean) * rstd * g[c] + b[c];
        h[base + c] = o; hhf[base + c] = o; hb[base + c] = f2bf(o);
    }
}

// ---------------------------------------------------------------------------
// bf16 transpose: ht[b][d][t] = hb[b][t][d]
// ---------------------------------------------------------------------------
__global__ __launch_bounds__(256)
void transpose_kernel(const u16* __restrict__ hb, u16* __restrict__ ht)
{
    __shared__ u16 tile[32][33];
    int b = blockIdx.z;
    int d0 = blockIdx.x * 32, t0 = blockIdx.y * 32;
    int tx = threadIdx.x & 31, ty = threadIdx.x >> 5;
    long long bb = (long long)b * T_SEQ * D_MODEL;
    #pragma unroll
    for (int i = 0; i < 32; i += 8)
        tile[ty + i][tx] = hb[bb + (long long)(t0 + ty + i) * D_MODEL + d0 + tx];
    __syncthreads();
    #pragma unroll
    for (int i = 0; i < 32; i += 8)
        ht[bb + (long long)(d0 + ty + i) * T_SEQ + t0 + tx] = tile[tx][ty + i];
}

// ---------------------------------------------------------------------------
// causal softmax, f16 in -> bf16 out, in place. grid (T, Z)
// ---------------------------------------------------------------------------
__global__ __launch_bounds__(256)
void softmax_kernel(u16* __restrict__ SP)
{
    int t = blockIdx.x, z = blockIdx.y;
    long long rb = (long long)z * T_SEQ * T_SEQ + (long long)t * T_SEQ;
    u16* row = SP + rb;
    int len = t + 1;
    int tid = threadIdx.x, lane = tid & 63, wave = tid >> 6;
    __shared__ float red[4];

    float ev[4];
    float m = -3.0e38f;
    #pragma unroll
    for (int k = 0; k < 4; k++) {
        int s = tid + k * 256;
        if (s < len) {
            union { u16 u; _Float16 h; } cv; cv.u = row[s];
            ev[k] = (float)cv.h;
        } else ev[k] = -3.0e38f;
        m = fmaxf(m, ev[k]);
    }
    m = wred_max(m);
    if (lane == 0) red[wave] = m;
    __syncthreads();
    m = fmaxf(fmaxf(red[0], red[1]), fmaxf(red[2], red[3]));
    __syncthreads();
    float sum = 0.f;
    #pragma unroll
    for (int k = 0; k < 4; k++) {
        int s = tid + k * 256;
        float e = (s < len) ? __expf(ev[k] - m) : 0.f;
        ev[k] = e; sum += e;
    }
    sum = wred_sum(sum);
    if (lane == 0) red[wave] = sum;
    __syncthreads();
    sum = red[0] + red[1] + red[2] + red[3];
    float inv = 1.f / sum;
    #pragma unroll
    for (int k = 0; k < 4; k++)
        row[tid + k * 256] = f2bf(ev[k] * inv);
}

// ---------------------------------------------------------------------------
// par deltas (all 7 chambers): db[row][i*768+c] = bf16(coef_i * (E_i - h))
// ---------------------------------------------------------------------------
__global__ __launch_bounds__(256)
void delta_par_kernel(const u16* __restrict__ E, const float* __restrict__ h,
                      u16* __restrict__ db,
                      const float* __restrict__ gw, const float* __restrict__ gb,
                      const float* __restrict__ sp)
{
    int row = blockIdx.x;
    long long base = (long long)row * D_MODEL;
    int tid = threadIdx.x, lane = tid & 63, wave = tid >> 6;
    __shared__ float red[NCH][4];
    float hv[3];
    #pragma unroll
    for (int k = 0; k < 3; k++) hv[k] = h[base + tid + k * 256];
    float dot[NCH];
    #pragma unroll
    for (int i = 0; i < NCH; i++) {
        float dd = 0.f;
        #pragma unroll
        for (int k = 0; k < 3; k++) dd += hv[k] * gw[i * D_MODEL + tid + k * 256];
        dot[i] = wred_sum(dd);
    }
    if (lane == 0)
        #pragma unroll
        for (int i = 0; i < NCH; i++) red[i][wave] = dot[i];
    __syncthreads();
    float coef[NCH];
    #pragma unroll
    for (int i = 0; i < NCH; i++) {
        float t = red[i][0] + red[i][1] + red[i][2] + red[i][3];
        float gate = 1.f / (1.f + __expf(-(t + gb[i])));
        coef[i] = log1pf(expf(sp[i])) * chamber_mask(i) * gate;
    }
    #pragma unroll
    for (int i = 0; i < NCH; i++) {
        const u16* Er = E + ((long long)i * ROWS + row) * D_MODEL;
        u16* dr = db + (long long)row * (NCH * D_MODEL) + i * D_MODEL;
        #pragma unroll
        for (int k = 0; k < 3; k++) {
            int c = tid + k * 256;
            dr[c] = f2bf(coef[i] * (bf2f(Er[c]) - hv[k]));
        }
    }
}

// ---------------------------------------------------------------------------
// fused seq delta + transpose: hh' = hh + coef*(E-hh); writes hhf, hb, ht.
// grid (T/32, BATCH), 256 threads, 32 rows x 768 cols per block.
// ---------------------------------------------------------------------------
__global__ __launch_bounds__(256)
void fd_kernel(float* __restrict__ hhf, u16* __restrict__ hb, u16* __restrict__ ht,
               const u16* __restrict__ E,
               const float* __restrict__ gw, const float* __restrict__ gb,
               const float* __restrict__ sp, int ci)
{
    __shared__ u16 tile[32][770];   // stride 770: conflict-free transposed read
    __shared__ float coef[32];
    int tb = blockIdx.x, b = blockIdx.y;
    int t0 = tb * 32;
    long long base = ((long long)b * T_SEQ + t0) * D_MODEL;
    int tid = threadIdx.x;

    // Phase A: per-row gate dot (8 lanes per row)
    int arow = tid >> 3, aj = tid & 7;
    const float* hr = hhf + base + (long long)arow * D_MODEL;
    const float* gr = gw + ci * D_MODEL;
    float dot = 0.f;
    #pragma unroll
    for (int k = 0; k < 96; k++) dot += hr[aj + 8 * k] * gr[aj + 8 * k];
    dot += __shfl_xor(dot, 4);
    dot += __shfl_xor(dot, 2);
    dot += __shfl_xor(dot, 1);
    if (aj == 0) {
        float gate = 1.f / (1.f + __expf(-(dot + gb[ci])));
        coef[arow] = log1pf(expf(sp[ci])) * chamber_mask(ci) * gate;
    }
    __syncthreads();

    // Phase B: update hhf, write hb, stage bf16 into LDS tile
    for (int lr = 0; lr < 32; lr++) {
        float cf = coef[lr];
        long long rb = base + (long long)lr * D_MODEL;
        #pragma unroll
        for (int kk = 0; kk < 3; kk++) {
            int c = tid + kk * 256;
            float v = hhf[rb + c];
            float nh = v + cf * (bf2f(E[rb + c]) - v);
            hhf[rb + c] = nh;
            u16 w = f2bf(nh);
            hb[rb + c] = w;
            tile[lr][c] = w;
        }
    }
    __syncthreads();

    // Phase C: write transposed ht[b][d][t0+tt]
    long long hb2 = (long long)b * T_SEQ * D_MODEL;
    #pragma unroll
    for (int k = 0; k < 96; k++) {
        int u = tid + k * 256;
        int dcol = u >> 5, tt = u & 31;
        ht[hb2 + (long long)dcol * T_SEQ + t0 + tt] = tile[tt][dcol];
    }
}

// ---------------------------------------------------------------------------
__global__ __launch_bounds__(256)
void transw_kernel(const float* __restrict__ W, u16* __restrict__ WT, long long zstride)
{
    __shared__ u16 tile[32][33];
    int z = blockIdx.z;
    int c0 = blockIdx.x * 32, r0 = blockIdx.y * 32;
    int tx = threadIdx.x & 31, ty = threadIdx.x >> 5;
    const float* src = W + (long long)z * D_MODEL * D_MODEL;
    u16* dst = WT + (long long)z * zstride;
    #pragma unroll
    for (int i = 0; i < 32; i += 8)
        tile[ty + i][tx] = f2bf(src[(long long)(r0 + ty + i) * D_MODEL + c0 + tx]);
    __syncthreads();
    #pragma unroll
    for (int i = 0; i < 32; i += 8)
        dst[(long long)(c0 + ty + i) * D_MODEL + r0 + tx] = tile[tx][ty + i];
}

__global__ __launch_bounds__(256)
void cast_kernel(const float* __restrict__ in, u16* __restrict__ outp, int n)
{
    int i = blockIdx.x * 256 + threadIdx.x;
    if (i < n) outp[i] = f2bf(in[i]);
}

// ---------------------------------------------------------------------------
// final: e = (1-mg)*(hhf-h) + mg*par; out = x + rg*(LN(e)*g+b)
// ---------------------------------------------------------------------------
__global__ __launch_bounds__(256)
void final_kernel(const float* __restrict__ x, const float* __restrict__ h,
                  const float* __restrict__ hhf, const float* __restrict__ par,
                  const float* __restrict__ mode_logit, const float* __restrict__ residual_gate,
                  const float* __restrict__ g, const float* __restrict__ b,
                  float* __restrict__ out)
{
    int row = blockIdx.x;
    long long base = (long long)row * D_MODEL;
    int tid = threadIdx.x, lane = tid & 63, wave = tid >> 6;
    __shared__ float red[4];
    float mg = 1.f / (1.f + __expf(-mode_logit[0]));
    float rg = residual_gate[0];
    float e[3]; float s = 0.f;
    #pragma unroll
    for (int k = 0; k < 3; k++) {
        int c = tid + k * 256;
        float v = (1.f - mg) * (hhf[base + c] - h[base + c]) + mg * par[base + c];
        e[k] = v; s += v;
    }
    s = wred_sum(s);
    if (lane == 0) red[wave] = s;
    __syncthreads();
    float mean = (red[0] + red[1] + red[2] + red[3]) * (1.f / D_MODEL);
    __syncthreads();
    float sq = 0.f;
    #pragma unroll
    for (int k = 0; k < 3; k++) { float dd = e[k] - mean; sq += dd * dd; }
    sq = wred_sum(sq);
    if (lane == 0) red[wave] = sq;
    __syncthreads();
    float var = (red[0] + red[1] + red[2] + red[3]) * (1.f / D_MODEL);
    float rstd = rsqrtf(var + 1e-5f);
    #pragma unroll
    for (int k = 0; k < 3; k++) {
        int c = tid + k * 256;
        out[base + c] = x[base + c] + rg * ((e[k] - mean) * rstd * g[c] + b[c]);
    }
}

// ---------------------------------------------------------------------------
extern "C" void kernel_launch(void* const* d_in, const int* in_sizes, int n_in,
                              void* d_out, int out_size, void* d_ws, size_t ws_size,
                              hipStream_t stream)
{
    (void)in_sizes; (void)n_in; (void)out_size; (void)ws_size;
    const float* x             = (const float*)d_in[0];
    const float* Wq            = (const float*)d_in[1];
    const float* Wk            = (const float*)d_in[2];
    const float* gate_w        = (const float*)d_in[3];
    const float* gate_b        = (const float*)d_in[4];
    const float* scale_p       = (const float*)d_in[5];
    const float* merge_W       = (const float*)d_in[6];
    const float* mode_logit    = (const float*)d_in[7];
    const float* residual_gate = (const float*)d_in[8];
    const float* ln_pre_g      = (const float*)d_in[9];
    const float* ln_pre_b      = (const float*)d_in[10];
    const float* ln_post_g     = (const float*)d_in[11];
    const float* ln_post_b     = (const float*)d_in[12];
    float* out = (float*)d_out;

    const long long DD  = (long long)D_MODEL * D_MODEL;   // 589824
    const long long TD  = (long long)T_SEQ * D_MODEL;     // 786432
    const long long TTs = (long long)T_SEQ * T_SEQ;       // 1048576
    const long long RDe = (long long)ROWS * D_MODEL;      // 3145728
    const int KM = NCH * D_MODEL;                         // 5376

    size_t off = 0;
    char* wsb = (char*)d_ws;
    auto alloc = [&](size_t bytes) -> void* {
        void* p = wsb + off; off += (bytes + 255) & ~(size_t)255; return p;
    };
    u16*  Wall = (u16*)alloc((size_t)NCH * 2 * DD * 2);        // [i][q/k][768][768]
    u16*  mgb  = (u16*)alloc((size_t)D_MODEL * KM * 2);        // merge_W bf16
    float* h   = (float*)alloc(RDe * 4);
    float* hhf = (float*)alloc(RDe * 4);                       // h + seq (running)
    float* par = (float*)alloc(RDe * 4);
    u16*  hb   = (u16*)alloc(RDe * 2);
    u16*  ht   = (u16*)alloc(RDe * 2);
    u16*  S    = (u16*)alloc((size_t)(NCH * BATCH) * TTs * 2); // f16 scores -> bf16 P
    u16*  qk   = (u16*)alloc((size_t)(NCH * 2) * RDe * 2);     // par q/k; Eall aliases
    u16*  qkb  = (u16*)alloc((size_t)ROWS * 1536 * 2);         // seq q|k
    u16*  Eseq = (u16*)alloc(RDe * 2);
    u16*  Eall = qk;                                           // alias: qk dead after par scores
    u16*  db   = S;                                            // alias: P dead after par PV

    const float sc = 1.0f / sqrtf((float)D_MODEL);

    hipMemsetAsync(par, 0, RDe * 4, stream);                   // split-K atomic target

    ln_pre_kernel<<<ROWS, 256, 0, stream>>>(x, ln_pre_g, ln_pre_b, h, hhf, hb);
    transw_kernel<<<dim3(24, 24, NCH), 256, 0, stream>>>(Wq, Wall, 2 * DD);
    transw_kernel<<<dim3(24, 24, NCH), 256, 0, stream>>>(Wk, Wall + DD, 2 * DD);
    cast_kernel<<<((int)(D_MODEL * KM) + 255) / 256, 256, 0, stream>>>(merge_W, mgb, D_MODEL * KM);
    transpose_kernel<<<dim3(24, 32, BATCH), 256, 0, stream>>>(hb, ht);

    // ======================= par branch (batched over chambers, 128-tile) ====
    gemm_nt_kernel<<<dim3(6, 32, 2 * NCH), 256, 0, stream>>>(
        hb, Wall, qk, D_MODEL, D_MODEL, D_MODEL, D_MODEL,
        0, 0, DD, 0, RDe, 0, 2 * NCH, 1.f, 1, 0, 0, 0, 0);
    gemm_nt_kernel<<<dim3(8, 8, BATCH * NCH), 256, 0, stream>>>(
        qk, qk + RDe, S, D_MODEL, D_MODEL, D_MODEL, T_SEQ,
        TD, 2 * RDe, TD, 2 * RDe, TTs, 4 * TTs, BATCH, sc, 3, 1, 0, 0, 0);
    softmax_kernel<<<dim3(T_SEQ, BATCH * NCH), 256, 0, stream>>>(S);
    gemm_nt_kernel<<<dim3(6, 8, BATCH * NCH), 256, 0, stream>>>(
        S, ht, Eall, T_SEQ, T_SEQ, T_SEQ, D_MODEL,
        TTs, 4 * TTs, TD, 0, TD, 4 * TD, BATCH, 1.f, 1, 0, 1, 0, 0);
    delta_par_kernel<<<ROWS, 256, 0, stream>>>(Eall, h, db, gate_w, gate_b, scale_p);
    // merge: par += db @ mgb^T, split-K x4 with atomic accumulate
    gemm_nt_kernel<<<dim3(6, 32, 4), 256, 0, stream>>>(
        db, mgb, par, KM, KM, KM, D_MODEL,
        0, 0, 0, 0, 0, 0, 4, 1.f, 4, 0, 0, KM / 4, KM / 4);

    // ======================= seq branch (serial chain, 64-tile) ==============
    for (int i = 0; i < NCH; i++) {
        // proj: qkb[4096][1536] = hb @ [Wq_i|Wk_i]^T   (1536 blocks)
        gemm64_nt_kernel<<<dim3(24, 64, 1), 256, 0, stream>>>(
            hb, Wall + (long long)i * 2 * DD, qkb,
            D_MODEL, D_MODEL, D_MODEL, 1536, 0, 0, 0, 1.f, 1, 0, 0);
        // scores: S[b] = Q K^T * sc, causal (1024 blocks, ~544 active)
        gemm64_nt_kernel<<<dim3(16, 16, BATCH), 256, 0, stream>>>(
            qkb, qkb + 768, S, D_MODEL, 1536, 1536, T_SEQ,
            (long long)T_SEQ * 1536, (long long)T_SEQ * 1536, TTs, sc, 3, 1, 0);
        softmax_kernel<<<dim3(T_SEQ, BATCH), 256, 0, stream>>>(S);
        // PV: Eseq[b] = P @ ht[b]^T, K-limited (768 blocks)
        gemm64_nt_kernel<<<dim3(12, 16, BATCH), 256, 0, stream>>>(
            S, ht, Eseq, T_SEQ, T_SEQ, T_SEQ, D_MODEL,
            TTs, TD, TD, 1.f, 1, 0, 1);
        fd_kernel<<<dim3(32, BATCH), 256, 0, stream>>>(hhf, hb, ht, Eseq,
                                                       gate_w, gate_b, scale_p, i);
    }

    final_kernel<<<ROWS, 256, 0, stream>>>(x, h, hhf, par, mode_logit, residual_gate,
                                           ln_post_g, ln_post_b, out);
}

// Round 7
// 1050.182 us; speedup vs baseline: 1.2965x; 1.0871x over previous
//
#include <hip/hip_runtime.h>
#include <hip/hip_bf16.h>
#include <math.h>

#define D_MODEL 768
#define T_SEQ   1024
#define BATCH   4
#define NCH     7
#define ROWS    4096            // BATCH*T_SEQ

typedef unsigned short u16;
typedef __attribute__((ext_vector_type(8))) short bh8;   // 8 x bf16
typedef __attribute__((ext_vector_type(4))) float f32x4;

__device__ __forceinline__ u16 f2bf(float f) {
    union { float f; unsigned u; } v; v.f = f;
    return (u16)((v.u + 0x7fffu + ((v.u >> 16) & 1u)) >> 16);  // RNE
}
__device__ __forceinline__ float bf2f(u16 b) {
    union { unsigned u; float f; } v; v.u = ((unsigned)b) << 16;
    return v.f;
}
__device__ __forceinline__ float wred_sum(float v) {
    #pragma unroll
    for (int o = 32; o; o >>= 1) v += __shfl_down(v, o, 64);
    return v;
}
__device__ __forceinline__ float wred_max(float v) {
    #pragma unroll
    for (int o = 32; o; o >>= 1) v = fmaxf(v, __shfl_down(v, o, 64));
    return v;
}
__device__ __forceinline__ float chamber_mask(int i) {
    float slope = 8.0f * 7.0f / 2000.0f;
    return 1.0f / (1.0f + __expf(-slope * (4000.0f - 2000.0f * (i + 0.5f) / 7.0f)));
}

#define GLD16(g, l) __builtin_amdgcn_global_load_lds( \
    (const __attribute__((address_space(1))) void*)(g), \
    (__attribute__((address_space(3))) void*)(l), 16, 0, 0)

// ---------------------------------------------------------------------------
// 128x128-tile NT GEMM, BK=32: C = alpha * A[M,K] * B[N,K]^T  (bf16 in)
// mode: 0 f32 store, 1 bf16 store, 3 f16 store.  Fully deterministic.
// ---------------------------------------------------------------------------
__global__ __launch_bounds__(256)
void gemm_nt_kernel(const u16* __restrict__ A, const u16* __restrict__ B,
                    void* __restrict__ Cv,
                    int K, int lda, int ldb, int ldc,
                    long long sA1, long long sA2, long long sB1, long long sB2,
                    long long sC1, long long sC2, int zm,
                    float alpha, int mode, int causal_skip, int causal_k)
{
    int bn = blockIdx.x, bm = blockIdx.y, bz = blockIdx.z;
    if (causal_skip && bn > bm) return;
    int bz1 = bz % zm, bz2 = bz / zm;

    const u16* Ab = A + bz1 * sA1 + bz2 * sA2 + (long long)(bm * 128) * lda;
    const u16* Bb = B + bz1 * sB1 + bz2 * sB2 + (long long)(bn * 128) * ldb;

    __shared__ u16 sm[2 * 128 * 32];
    u16* Al = sm;
    u16* Bl = sm + 128 * 32;

    int tid  = threadIdx.x;
    int lane = tid & 63;
    int wave = tid >> 6;
    int wm = wave >> 1, wn = wave & 1;

    int k_end = K;
    if (causal_k) k_end = min(k_end, (bm + 1) * 128);

    f32x4 acc[4][4];
    #pragma unroll
    for (int i = 0; i < 4; i++)
        #pragma unroll
        for (int j = 0; j < 4; j++)
            acc[i][j] = (f32x4){0.f, 0.f, 0.f, 0.f};

    int srow = lane >> 2;
    int skq  = (lane & 3) * 8;
    int fm   = lane & 15;
    int fk   = (lane >> 4) * 8;

    for (int k0 = 0; k0 < k_end; k0 += 32) {
        __syncthreads();
        #pragma unroll
        for (int r = 0; r < 2; r++) {
            int row = r * 64 + wave * 16 + srow;
            GLD16(Ab + (long long)row * lda + k0 + skq, Al + row * 32 + skq);
            GLD16(Bb + (long long)row * ldb + k0 + skq, Bl + row * 32 + skq);
        }
        __syncthreads();

        bh8 af[4], bf[4];
        #pragma unroll
        for (int i = 0; i < 4; i++)
            af[i] = *(const bh8*)(Al + (wm * 64 + i * 16 + fm) * 32 + fk);
        #pragma unroll
        for (int j = 0; j < 4; j++)
            bf[j] = *(const bh8*)(Bl + (wn * 64 + j * 16 + fm) * 32 + fk);
        #pragma unroll
        for (int i = 0; i < 4; i++)
            #pragma unroll
            for (int j = 0; j < 4; j++)
                acc[i][j] = __builtin_amdgcn_mfma_f32_16x16x32_bf16(af[i], bf[j], acc[i][j], 0, 0, 0);
    }

    int rbase = bm * 128 + wm * 64 + (lane >> 4) * 4;
    int cbase = bn * 128 + wn * 64 + (lane & 15);
    long long zoff = bz1 * sC1 + bz2 * sC2;
    if (mode == 1) {
        u16* C = (u16*)Cv + zoff;
        #pragma unroll
        for (int i = 0; i < 4; i++)
            #pragma unroll
            for (int j = 0; j < 4; j++)
                #pragma unroll
                for (int r = 0; r < 4; r++)
                    C[(long long)(rbase + i * 16 + r) * ldc + cbase + j * 16] = f2bf(acc[i][j][r] * alpha);
    } else if (mode == 3) {
        u16* C = (u16*)Cv + zoff;
        #pragma unroll
        for (int i = 0; i < 4; i++)
            #pragma unroll
            for (int j = 0; j < 4; j++)
                #pragma unroll
                for (int r = 0; r < 4; r++) {
                    union { _Float16 h; u16 u; } cv;
                    cv.h = (_Float16)(acc[i][j][r] * alpha);
                    C[(long long)(rbase + i * 16 + r) * ldc + cbase + j * 16] = cv.u;
                }
    } else {
        float* C = (float*)Cv + zoff;
        #pragma unroll
        for (int i = 0; i < 4; i++)
            #pragma unroll
            for (int j = 0; j < 4; j++)
                #pragma unroll
                for (int r = 0; r < 4; r++)
                    C[(long long)(rbase + i * 16 + r) * ldc + cbase + j * 16] = acc[i][j][r] * alpha;
    }
}

// ---------------------------------------------------------------------------
// 64x64-tile NT GEMM, BK=32 — grid-starved launches + deterministic merge.
// ---------------------------------------------------------------------------
__global__ __launch_bounds__(256)
void gemm64_nt_kernel(const u16* __restrict__ A, const u16* __restrict__ B,
                      void* __restrict__ Cv,
                      int K, int lda, int ldb, int ldc,
                      long long sA, long long sB, long long sC,
                      float alpha, int mode, int causal_skip, int causal_k)
{
    int bn = blockIdx.x, bm = blockIdx.y, bz = blockIdx.z;
    if (causal_skip && bn > bm) return;

    const u16* Ab = A + bz * sA + (long long)(bm * 64) * lda;
    const u16* Bb = B + bz * sB + (long long)(bn * 64) * ldb;

    __shared__ u16 sm[2 * 64 * 32];    // 8 KB
    u16* Al = sm;
    u16* Bl = sm + 64 * 32;

    int tid  = threadIdx.x;
    int lane = tid & 63;
    int wave = tid >> 6;

    int k_end = causal_k ? min(K, (bm + 1) * 64) : K;

    f32x4 acc[4];
    #pragma unroll
    for (int j = 0; j < 4; j++) acc[j] = (f32x4){0.f, 0.f, 0.f, 0.f};

    int srow   = tid >> 2;             // 0..63
    int schunk = (tid & 3) * 8;
    int fm     = lane & 15;
    int fk     = (lane >> 4) * 8;

    for (int k0 = 0; k0 < k_end; k0 += 32) {
        __syncthreads();
        GLD16(Ab + (long long)srow * lda + k0 + schunk, Al + srow * 32 + schunk);
        GLD16(Bb + (long long)srow * ldb + k0 + schunk, Bl + srow * 32 + schunk);
        __syncthreads();

        bh8 af = *(const bh8*)(Al + (wave * 16 + fm) * 32 + fk);
        bh8 bf[4];
        #pragma unroll
        for (int j = 0; j < 4; j++)
            bf[j] = *(const bh8*)(Bl + (j * 16 + fm) * 32 + fk);
        #pragma unroll
        for (int j = 0; j < 4; j++)
            acc[j] = __builtin_amdgcn_mfma_f32_16x16x32_bf16(af, bf[j], acc[j], 0, 0, 0);
    }

    int rbase = bm * 64 + wave * 16 + (lane >> 4) * 4;
    int cbase = bn * 64 + (lane & 15);
    long long zoff = (long long)bz * sC;
    if (mode == 1) {
        u16* C = (u16*)Cv + zoff;
        #pragma unroll
        for (int j = 0; j < 4; j++)
            #pragma unroll
            for (int r = 0; r < 4; r++)
                C[(long long)(rbase + r) * ldc + cbase + j * 16] = f2bf(acc[j][r] * alpha);
    } else if (mode == 3) {
        u16* C = (u16*)Cv + zoff;
        #pragma unroll
        for (int j = 0; j < 4; j++)
            #pragma unroll
            for (int r = 0; r < 4; r++) {
                union { _Float16 h; u16 u; } cv;
                cv.h = (_Float16)(acc[j][r] * alpha);
                C[(long long)(rbase + r) * ldc + cbase + j * 16] = cv.u;
            }
    } else {
        float* C = (float*)Cv + zoff;
        #pragma unroll
        for (int j = 0; j < 4; j++)
            #pragma unroll
            for (int r = 0; r < 4; r++)
                C[(long long)(rbase + r) * ldc + cbase + j * 16] = acc[j][r] * alpha;
    }
}

// ---------------------------------------------------------------------------
// LN pre: h = LN(x)*g+b; hhf = h; hbp = hbs = bf16(h)
// ---------------------------------------------------------------------------
__global__ __launch_bounds__(256)
void ln_pre_kernel(const float* __restrict__ x, const float* __restrict__ g,
                   const float* __restrict__ b, float* __restrict__ h,
                   float* __restrict__ hhf, u16* __restrict__ hbp,
                   u16* __restrict__ hbs)
{
    int row = blockIdx.x;
    long long base = (long long)row * D_MODEL;
    int tid = threadIdx.x, lane = tid & 63, wave = tid >> 6;
    __shared__ float red[4];
    float v[3]; float s = 0.f;
    #pragma unroll
    for (int k = 0; k < 3; k++) { v[k] = x[base + tid + k * 256]; s += v[k]; }
    s = wred_sum(s);
    if (lane == 0) red[wave] = s;
    __syncthreads();
    float mean = (red[0] + red[1] + red[2] + red[3]) * (1.f / D_MODEL);
    __syncthreads();
    float sq = 0.f;
    #pragma unroll
    for (int k = 0; k < 3; k++) { float dd = v[k] - mean; sq += dd * dd; }
    sq = wred_sum(sq);
    if (lane == 0) red[wave] = sq;
    __syncthreads();
    float var = (red[0] + red[1] + red[2] + red[3]) * (1.f / D_MODEL);
    float rstd = rsqrtf(var + 1e-5f);
    #pragma unroll
    for (int k = 0; k < 3; k++) {
        int c = tid + k * 256;
        float o = (v[k] - mean) * rstd * g[c] + b[c];
        h[base + c] = o; hhf[base + c] = o;
        u16 w = f2bf(o);
        hbp[base + c] = w; hbs[base + c] = w;
    }
}

// ---------------------------------------------------------------------------
// bf16 transpose, dual output: htp/hts[b][d][t] = hb[b][t][d]
// ---------------------------------------------------------------------------
__global__ __launch_bounds__(256)
void transpose2_kernel(const u16* __restrict__ hb, u16* __restrict__ htp,
                       u16* __restrict__ hts)
{
    __shared__ u16 tile[32][33];
    int b = blockIdx.z;
    int d0 = blockIdx.x * 32, t0 = blockIdx.y * 32;
    int tx = threadIdx.x & 31, ty = threadIdx.x >> 5;
    long long bb = (long long)b * T_SEQ * D_MODEL;
    #pragma unroll
    for (int i = 0; i < 32; i += 8)
        tile[ty + i][tx] = hb[bb + (long long)(t0 + ty + i) * D_MODEL + d0 + tx];
    __syncthreads();
    #pragma unroll
    for (int i = 0; i < 32; i += 8) {
        long long o = bb + (long long)(d0 + ty + i) * T_SEQ + t0 + tx;
        u16 w = tile[tx][ty + i];
        htp[o] = w; hts[o] = w;
    }
}

// ---------------------------------------------------------------------------
// causal softmax, f16 in -> bf16 out, in place. grid (T, Z)
// ---------------------------------------------------------------------------
__global__ __launch_bounds__(256)
void softmax_kernel(u16* __restrict__ SP)
{
    int t = blockIdx.x, z = blockIdx.y;
    long long rb = (long long)z * T_SEQ * T_SEQ + (long long)t * T_SEQ;
    u16* row = SP + rb;
    int len = t + 1;
    int tid = threadIdx.x, lane = tid & 63, wave = tid >> 6;
    __shared__ float red[4];

    float ev[4];
    float m = -3.0e38f;
    #pragma unroll
    for (int k = 0; k < 4; k++) {
        int s = tid + k * 256;
        if (s < len) {
            union { u16 u; _Float16 h; } cv; cv.u = row[s];
            ev[k] = (float)cv.h;
        } else ev[k] = -3.0e38f;
        m = fmaxf(m, ev[k]);
    }
    m = wred_max(m);
    if (lane == 0) red[wave] = m;
    __syncthreads();
    m = fmaxf(fmaxf(red[0], red[1]), fmaxf(red[2], red[3]));
    __syncthreads();
    float sum = 0.f;
    #pragma unroll
    for (int k = 0; k < 4; k++) {
        int s = tid + k * 256;
        float e = (s < len) ? __expf(ev[k] - m) : 0.f;
        ev[k] = e; sum += e;
    }
    sum = wred_sum(sum);
    if (lane == 0) red[wave] = sum;
    __syncthreads();
    sum = red[0] + red[1] + red[2] + red[3];
    float inv = 1.f / sum;
    #pragma unroll
    for (int k = 0; k < 4; k++)
        row[tid + k * 256] = f2bf(ev[k] * inv);
}

// ---------------------------------------------------------------------------
// par deltas (all 7 chambers): db[row][i*768+c] = bf16(coef_i * (E_i - h))
// ---------------------------------------------------------------------------
__global__ __launch_bounds__(256)
void delta_par_kernel(const u16* __restrict__ E, const float* __restrict__ h,
                      u16* __restrict__ db,
                      const float* __restrict__ gw, const float* __restrict__ gb,
                      const float* __restrict__ sp)
{
    int row = blockIdx.x;
    long long base = (long long)row * D_MODEL;
    int tid = threadIdx.x, lane = tid & 63, wave = tid >> 6;
    __shared__ float red[NCH][4];
    float hv[3];
    #pragma unroll
    for (int k = 0; k < 3; k++) hv[k] = h[base + tid + k * 256];
    float dot[NCH];
    #pragma unroll
    for (int i = 0; i < NCH; i++) {
        float dd = 0.f;
        #pragma unroll
        for (int k = 0; k < 3; k++) dd += hv[k] * gw[i * D_MODEL + tid + k * 256];
        dot[i] = wred_sum(dd);
    }
    if (lane == 0)
        #pragma unroll
        for (int i = 0; i < NCH; i++) red[i][wave] = dot[i];
    __syncthreads();
    float coef[NCH];
    #pragma unroll
    for (int i = 0; i < NCH; i++) {
        float t = red[i][0] + red[i][1] + red[i][2] + red[i][3];
        float gate = 1.f / (1.f + __expf(-(t + gb[i])));
        coef[i] = log1pf(expf(sp[i])) * chamber_mask(i) * gate;
    }
    #pragma unroll
    for (int i = 0; i < NCH; i++) {
        const u16* Er = E + ((long long)i * ROWS + row) * D_MODEL;
        u16* dr = db + (long long)row * (NCH * D_MODEL) + i * D_MODEL;
        #pragma unroll
        for (int k = 0; k < 3; k++) {
            int c = tid + k * 256;
            dr[c] = f2bf(coef[i] * (bf2f(Er[c]) - hv[k]));
        }
    }
}

// ---------------------------------------------------------------------------
// fused seq delta + transpose: hh' = hh + coef*(E-hh); writes hhf, hb, ht.
// grid (T/32, BATCH), 256 threads, 32 rows x 768 cols per block.
// ---------------------------------------------------------------------------
__global__ __launch_bounds__(256)
void fd_kernel(float* __restrict__ hhf, u16* __restrict__ hb, u16* __restrict__ ht,
               const u16* __restrict__ E,
               const float* __restrict__ gw, const float* __restrict__ gb,
               const float* __restrict__ sp, int ci)
{
    __shared__ u16 tile[32][770];   // stride 770: conflict-free transposed read
    __shared__ float coef[32];
    int tb = blockIdx.x, b = blockIdx.y;
    int t0 = tb * 32;
    long long base = ((long long)b * T_SEQ + t0) * D_MODEL;
    int tid = threadIdx.x;

    // Phase A: per-row gate dot (8 lanes per row)
    int arow = tid >> 3, aj = tid & 7;
    const float* hr = hhf + base + (long long)arow * D_MODEL;
    const float* gr = gw + ci * D_MODEL;
    float dot = 0.f;
    #pragma unroll
    for (int k = 0; k < 96; k++) dot += hr[aj + 8 * k] * gr[aj + 8 * k];
    dot += __shfl_xor(dot, 4);
    dot += __shfl_xor(dot, 2);
    dot += __shfl_xor(dot, 1);
    if (aj == 0) {
        float gate = 1.f / (1.f + __expf(-(dot + gb[ci])));
        coef[arow] = log1pf(expf(sp[ci])) * chamber_mask(ci) * gate;
    }
    __syncthreads();

    // Phase B: update hhf, write hb, stage bf16 into LDS tile
    for (int lr = 0; lr < 32; lr++) {
        float cf = coef[lr];
        long long rb = base + (long long)lr * D_MODEL;
        #pragma unroll
        for (int kk = 0; kk < 3; kk++) {
            int c = tid + kk * 256;
            float v = hhf[rb + c];
            float nh = v + cf * (bf2f(E[rb + c]) - v);
            hhf[rb + c] = nh;
            u16 w = f2bf(nh);
            hb[rb + c] = w;
            tile[lr][c] = w;
        }
    }
    __syncthreads();

    // Phase C: write transposed ht[b][d][t0+tt]
    long long hb2 = (long long)b * T_SEQ * D_MODEL;
    #pragma unroll
    for (int k = 0; k < 96; k++) {
        int u = tid + k * 256;
        int dcol = u >> 5, tt = u & 31;
        ht[hb2 + (long long)dcol * T_SEQ + t0 + tt] = tile[tt][dcol];
    }
}

// ---------------------------------------------------------------------------
// vectorized f32 -> bf16 cast (n divisible by 4)
// ---------------------------------------------------------------------------
__global__ __launch_bounds__(256)
void cast4_kernel(const float4* __restrict__ in, ushort4* __restrict__ outp, int n4)
{
    int i = blockIdx.x * 256 + threadIdx.x;
    if (i < n4) {
        float4 v = in[i];
        ushort4 o;
        o.x = f2bf(v.x); o.y = f2bf(v.y); o.z = f2bf(v.z); o.w = f2bf(v.w);
        outp[i] = o;
    }
}

// ---------------------------------------------------------------------------
// final: e = (1-mg)*(hhf-h) + mg*par; out = x + rg*(LN(e)*g+b)
// ---------------------------------------------------------------------------
__global__ __launch_bounds__(256)
void final_kernel(const float* __restrict__ x, const float* __restrict__ h,
                  const float* __restrict__ hhf, const float* __restrict__ par,
                  const float* __restrict__ mode_logit, const float* __restrict__ residual_gate,
                  const float* __restrict__ g, const float* __restrict__ b,
                  float* __restrict__ out)
{
    int row = blockIdx.x;
    long long base = (long long)row * D_MODEL;
    int tid = threadIdx.x, lane = tid & 63, wave = tid >> 6;
    __shared__ float red[4];
    float mg = 1.f / (1.f + __expf(-mode_logit[0]));
    float rg = residual_gate[0];
    float e[3]; float s = 0.f;
    #pragma unroll
    for (int k = 0; k < 3; k++) {
        int c = tid + k * 256;
        float v = (1.f - mg) * (hhf[base + c] - h[base + c]) + mg * par[base + c];
        e[k] = v; s += v;
    }
    s = wred_sum(s);
    if (lane == 0) red[wave] = s;
    __syncthreads();
    float mean = (red[0] + red[1] + red[2] + red[3]) * (1.f / D_MODEL);
    __syncthreads();
    float sq = 0.f;
    #pragma unroll
    for (int k = 0; k < 3; k++) { float dd = e[k] - mean; sq += dd * dd; }
    sq = wred_sum(sq);
    if (lane == 0) red[wave] = sq;
    __syncthreads();
    float var = (red[0] + red[1] + red[2] + red[3]) * (1.f / D_MODEL);
    float rstd = rsqrtf(var + 1e-5f);
    #pragma unroll
    for (int k = 0; k < 3; k++) {
        int c = tid + k * 256;
        out[base + c] = x[base + c] + rg * ((e[k] - mean) * rstd * g[c] + b[c]);
    }
}

// ---------------------------------------------------------------------------
extern "C" void kernel_launch(void* const* d_in, const int* in_sizes, int n_in,
                              void* d_out, int out_size, void* d_ws, size_t ws_size,
                              hipStream_t stream)
{
    (void)in_sizes; (void)n_in; (void)out_size; (void)ws_size;
    const float* x             = (const float*)d_in[0];
    const float* Wq            = (const float*)d_in[1];
    const float* Wk            = (const float*)d_in[2];
    const float* gate_w        = (const float*)d_in[3];
    const float* gate_b        = (const float*)d_in[4];
    const float* scale_p       = (const float*)d_in[5];
    const float* merge_W       = (const float*)d_in[6];
    const float* mode_logit    = (const float*)d_in[7];
    const float* residual_gate = (const float*)d_in[8];
    const float* ln_pre_g      = (const float*)d_in[9];
    const float* ln_pre_b      = (const float*)d_in[10];
    const float* ln_post_g     = (const float*)d_in[11];
    const float* ln_post_b     = (const float*)d_in[12];
    float* out = (float*)d_out;

    const long long DD  = (long long)D_MODEL * D_MODEL;   // 589824
    const long long TD  = (long long)T_SEQ * D_MODEL;     // 786432
    const long long TTs = (long long)T_SEQ * T_SEQ;       // 1048576
    const long long RDe = (long long)ROWS * D_MODEL;      // 3145728
    const int KM = NCH * D_MODEL;                         // 5376

    size_t off = 0;
    char* wsb = (char*)d_ws;
    auto alloc = [&](size_t bytes) -> void* {
        void* p = wsb + off; off += (bytes + 255) & ~(size_t)255; return p;
    };
    u16*  Wqb  = (u16*)alloc((size_t)NCH * DD * 2);            // 8.26 MB
    u16*  Wkb  = (u16*)alloc((size_t)NCH * DD * 2);            // 8.26 MB
    u16*  Mtb  = (u16*)alloc((size_t)NCH * DD * 2);            // 8.26 MB
    u16*  mgb  = (u16*)alloc((size_t)D_MODEL * KM * 2);        // 8.26 MB
    float* h   = (float*)alloc(RDe * 4);                       // 12.6 MB
    float* hhf = (float*)alloc(RDe * 4);                       // 12.6 MB
    float* par = (float*)alloc(RDe * 4);                       // 12.6 MB
    u16*  hbp  = (u16*)alloc(RDe * 2);                         // frozen h (par)
    u16*  htp  = (u16*)alloc(RDe * 2);
    u16*  hbs  = (u16*)alloc(RDe * 2);                         // running hh (seq)
    u16*  hts  = (u16*)alloc(RDe * 2);
    u16*  Spar = (u16*)alloc((size_t)(NCH * BATCH) * TTs * 2); // 58.7 MB
    u16*  Sseq = (u16*)alloc((size_t)BATCH * TTs * 2);         // 8.4 MB
    u16*  Upar = (u16*)alloc((size_t)NCH * RDe * 2);           // 44.0 MB
    u16*  Useq = (u16*)alloc(RDe * 2);
    u16*  Eseq = (u16*)alloc(RDe * 2);
    u16*  db   = (u16*)alloc((size_t)ROWS * KM * 2);           // 22.0 MB (dedicated)
    u16*  Eall = Upar;   // alias safe within one call: Upar dead after par scores
    // total ~241.7 MB

    const float sc = 1.0f / sqrtf((float)D_MODEL);
    const int N4W = (int)(NCH * DD) / 4;
    const int N4M = (int)(D_MODEL * KM) / 4;

    ln_pre_kernel<<<ROWS, 256, 0, stream>>>(x, ln_pre_g, ln_pre_b, h, hhf, hbp, hbs);
    cast4_kernel<<<(N4W + 255) / 256, 256, 0, stream>>>((const float4*)Wq, (ushort4*)Wqb, N4W);
    cast4_kernel<<<(N4W + 255) / 256, 256, 0, stream>>>((const float4*)Wk, (ushort4*)Wkb, N4W);
    cast4_kernel<<<(N4M + 255) / 256, 256, 0, stream>>>((const float4*)merge_W, (ushort4*)mgb, N4M);
    transpose2_kernel<<<dim3(24, 32, BATCH), 256, 0, stream>>>(hbp, htp, hts);

    // Mt_i[d'][d] = sum_e Wk_i[d'][e] Wq_i[d][e]   (z=7)
    gemm_nt_kernel<<<dim3(6, 6, NCH), 256, 0, stream>>>(
        Wkb, Wqb, Mtb, D_MODEL, D_MODEL, D_MODEL, D_MODEL,
        0, DD, 0, DD, 0, DD, 1, 1.f, 1, 0, 0);

    // ======================= par branch (frozen h, batched over chambers) ====
    // U_i = hbp @ Mt_i^T
    gemm_nt_kernel<<<dim3(6, 32, NCH), 256, 0, stream>>>(
        hbp, Mtb, Upar, D_MODEL, D_MODEL, D_MODEL, D_MODEL,
        0, 0, 0, DD, 0, RDe, 1, 1.f, 1, 0, 0);
    // scores: Spar[i*4+b] = U_i[b] @ hbp[b]^T * sc, causal, f16
    gemm_nt_kernel<<<dim3(8, 8, BATCH * NCH), 256, 0, stream>>>(
        Upar, hbp, Spar, D_MODEL, D_MODEL, D_MODEL, T_SEQ,
        TD, RDe, TD, 0, TTs, 4 * TTs, BATCH, sc, 3, 1, 0);
    softmax_kernel<<<dim3(T_SEQ, BATCH * NCH), 256, 0, stream>>>(Spar);
    // PV: Eall[i*4+b] = P @ htp[b]^T (bf16), causal K-limit
    gemm_nt_kernel<<<dim3(6, 8, BATCH * NCH), 256, 0, stream>>>(
        Spar, htp, Eall, T_SEQ, T_SEQ, T_SEQ, D_MODEL,
        TTs, 4 * TTs, TD, 0, TD, 4 * TD, BATCH, 1.f, 1, 0, 1);
    delta_par_kernel<<<ROWS, 256, 0, stream>>>(Eall, h, db, gate_w, gate_b, scale_p);
    // merge: par = db @ mgb^T — deterministic full-K 64-tile GEMM (no atomics)
    gemm64_nt_kernel<<<dim3(12, 64, 1), 256, 0, stream>>>(
        db, mgb, par, KM, KM, KM, D_MODEL, 0, 0, 0, 1.f, 0, 0, 0);

    // ======================= seq branch (serial chain, 64-tile) ==============
    for (int i = 0; i < NCH; i++) {
        // U = hbs @ Mt_i^T
        gemm64_nt_kernel<<<dim3(12, 64, 1), 256, 0, stream>>>(
            hbs, Mtb + (long long)i * DD, Useq,
            D_MODEL, D_MODEL, D_MODEL, D_MODEL, 0, 0, 0, 1.f, 1, 0, 0);
        // scores: Sseq[b] = U[b] @ hbs[b]^T * sc, causal
        gemm64_nt_kernel<<<dim3(16, 16, BATCH), 256, 0, stream>>>(
            Useq, hbs, Sseq, D_MODEL, D_MODEL, D_MODEL, T_SEQ,
            TD, TD, TTs, sc, 3, 1, 0);
        softmax_kernel<<<dim3(T_SEQ, BATCH), 256, 0, stream>>>(Sseq);
        // PV: Eseq[b] = P @ hts[b]^T, K-limited
        gemm64_nt_kernel<<<dim3(12, 16, BATCH), 256, 0, stream>>>(
            Sseq, hts, Eseq, T_SEQ, T_SEQ, T_SEQ, D_MODEL,
            TTs, TD, TD, 1.f, 1, 0, 1);
        fd_kernel<<<dim3(32, BATCH), 256, 0, stream>>>(hhf, hbs, hts, Eseq,
                                                       gate_w, gate_b, scale_p, i);
    }

    final_kernel<<<ROWS, 256, 0, stream>>>(x, h, hhf, par, mode_logit, residual_gate,
                                           ln_post_g, ln_post_b, out);
}

// Round 8
// 985.600 us; speedup vs baseline: 1.3815x; 1.0655x over previous
//
#include <hip/hip_runtime.h>
#include <hip/hip_bf16.h>
#include <math.h>

#define D_MODEL 768
#define T_SEQ   1024
#define BATCH   4
#define NCH     7
#define ROWS    4096            // BATCH*T_SEQ
#define KM      (NCH * D_MODEL) // 5376

typedef unsigned short u16;
typedef __attribute__((ext_vector_type(8))) short bh8;   // 8 x bf16
typedef __attribute__((ext_vector_type(4))) float f32x4;

__device__ __forceinline__ u16 f2bf(float f) {
    union { float f; unsigned u; } v; v.f = f;
    return (u16)((v.u + 0x7fffu + ((v.u >> 16) & 1u)) >> 16);  // RNE
}
__device__ __forceinline__ float bf2f(u16 b) {
    union { unsigned u; float f; } v; v.u = ((unsigned)b) << 16;
    return v.f;
}
__device__ __forceinline__ float wred_sum(float v) {
    #pragma unroll
    for (int o = 32; o; o >>= 1) v += __shfl_down(v, o, 64);
    return v;
}
__device__ __forceinline__ float wred_max(float v) {
    #pragma unroll
    for (int o = 32; o; o >>= 1) v = fmaxf(v, __shfl_down(v, o, 64));
    return v;
}
__device__ __forceinline__ float chamber_mask(int i) {
    float slope = 8.0f * 7.0f / 2000.0f;
    return 1.0f / (1.0f + __expf(-slope * (4000.0f - 2000.0f * (i + 0.5f) / 7.0f)));
}

#define GLD16(g, l) __builtin_amdgcn_global_load_lds( \
    (const __attribute__((address_space(1))) void*)(g), \
    (__attribute__((address_space(3))) void*)(l), 16, 0, 0)

// ---------------------------------------------------------------------------
// 128x128-tile NT GEMM, BK=32: C = alpha * A[M,K] * B[N,K]^T  (bf16 in)
// mode: 0 f32 store, 1 bf16 store, 3 f16 store,
//       5 par-delta epilogue: db[(b,t)][ch*768+d] = bf16(coef*(acc - h))
// kss/klen: K slice per bz1 (merge partials). Deterministic throughout.
// ---------------------------------------------------------------------------
__global__ __launch_bounds__(256)
void gemm_nt_kernel(const u16* __restrict__ A, const u16* __restrict__ B,
                    void* __restrict__ Cv,
                    int K, int lda, int ldb, int ldc,
                    long long sA1, long long sA2, long long sB1, long long sB2,
                    long long sC1, long long sC2, int zm,
                    float alpha, int mode, int causal_skip, int causal_k,
                    int kss, int klen,
                    const float* __restrict__ coefp, const float* __restrict__ hp,
                    u16* __restrict__ dbp)
{
    int bn = blockIdx.x, bm = blockIdx.y, bz = blockIdx.z;
    if (causal_skip && bn > bm) return;
    int bz1 = bz % zm, bz2 = bz / zm;

    const u16* Ab = A + bz1 * sA1 + bz2 * sA2 + (long long)(bm * 128) * lda;
    const u16* Bb = B + bz1 * sB1 + bz2 * sB2 + (long long)(bn * 128) * ldb;

    __shared__ u16 sm[2 * 128 * 32];
    u16* Al = sm;
    u16* Bl = sm + 128 * 32;

    int tid  = threadIdx.x;
    int lane = tid & 63;
    int wave = tid >> 6;
    int wm = wave >> 1, wn = wave & 1;

    int k_begin = kss ? bz1 * kss : 0;
    int k_end   = klen ? (k_begin + klen) : K;
    if (causal_k) k_end = min(k_end, (bm + 1) * 128);

    f32x4 acc[4][4];
    #pragma unroll
    for (int i = 0; i < 4; i++)
        #pragma unroll
        for (int j = 0; j < 4; j++)
            acc[i][j] = (f32x4){0.f, 0.f, 0.f, 0.f};

    int srow = lane >> 2;
    int skq  = (lane & 3) * 8;
    int fm   = lane & 15;
    int fk   = (lane >> 4) * 8;

    for (int k0 = k_begin; k0 < k_end; k0 += 32) {
        __syncthreads();
        #pragma unroll
        for (int r = 0; r < 2; r++) {
            int row = r * 64 + wave * 16 + srow;
            GLD16(Ab + (long long)row * lda + k0 + skq, Al + row * 32 + skq);
            GLD16(Bb + (long long)row * ldb + k0 + skq, Bl + row * 32 + skq);
        }
        __syncthreads();

        bh8 af[4], bf[4];
        #pragma unroll
        for (int i = 0; i < 4; i++)
            af[i] = *(const bh8*)(Al + (wm * 64 + i * 16 + fm) * 32 + fk);
        #pragma unroll
        for (int j = 0; j < 4; j++)
            bf[j] = *(const bh8*)(Bl + (wn * 64 + j * 16 + fm) * 32 + fk);
        #pragma unroll
        for (int i = 0; i < 4; i++)
            #pragma unroll
            for (int j = 0; j < 4; j++)
                acc[i][j] = __builtin_amdgcn_mfma_f32_16x16x32_bf16(af[i], bf[j], acc[i][j], 0, 0, 0);
    }

    int rbase = bm * 128 + wm * 64 + (lane >> 4) * 4;
    int cbase = bn * 128 + wn * 64 + (lane & 15);
    long long zoff = bz1 * sC1 + bz2 * sC2;
    if (mode == 1) {
        u16* C = (u16*)Cv + zoff;
        #pragma unroll
        for (int i = 0; i < 4; i++)
            #pragma unroll
            for (int j = 0; j < 4; j++)
                #pragma unroll
                for (int r = 0; r < 4; r++)
                    C[(long long)(rbase + i * 16 + r) * ldc + cbase + j * 16] = f2bf(acc[i][j][r] * alpha);
    } else if (mode == 3) {
        u16* C = (u16*)Cv + zoff;
        #pragma unroll
        for (int i = 0; i < 4; i++)
            #pragma unroll
            for (int j = 0; j < 4; j++)
                #pragma unroll
                for (int r = 0; r < 4; r++) {
                    union { _Float16 h; u16 u; } cv;
                    cv.h = (_Float16)(acc[i][j][r] * alpha);
                    C[(long long)(rbase + i * 16 + r) * ldc + cbase + j * 16] = cv.u;
                }
    } else if (mode == 5) {
        // par PV + delta: b = bz1 (batch), ch = bz2
        int b = bz1, ch = bz2;
        #pragma unroll
        for (int i = 0; i < 4; i++)
            #pragma unroll
            for (int r = 0; r < 4; r++) {
                int t = rbase + i * 16 + r;                 // 0..1023
                long long rowg = (long long)b * T_SEQ + t;  // 0..4095
                float cf = coefp[(long long)ch * ROWS + rowg];
                #pragma unroll
                for (int j = 0; j < 4; j++) {
                    int d = cbase + j * 16;                 // 0..767
                    float hv = hp[rowg * D_MODEL + d];
                    dbp[rowg * KM + ch * D_MODEL + d] = f2bf(cf * (acc[i][j][r] - hv));
                }
            }
    } else {
        float* C = (float*)Cv + zoff;
        #pragma unroll
        for (int i = 0; i < 4; i++)
            #pragma unroll
            for (int j = 0; j < 4; j++)
                #pragma unroll
                for (int r = 0; r < 4; r++)
                    C[(long long)(rbase + i * 16 + r) * ldc + cbase + j * 16] = acc[i][j][r] * alpha;
    }
}

// ---------------------------------------------------------------------------
// 64x64-tile NT GEMM, BK=32 — grid-starved seq-chain launches.
// mode: 0 f32, 1 bf16, 3 f16,
//       6 seq PV + delta: hh' = hh + coef*(acc - hh); writes hhf, hbs,
//         htsNew (transposed via LDS). bz = batch.
// ---------------------------------------------------------------------------
__global__ __launch_bounds__(256)
void gemm64_nt_kernel(const u16* __restrict__ A, const u16* __restrict__ B,
                      void* __restrict__ Cv,
                      int K, int lda, int ldb, int ldc,
                      long long sA, long long sB, long long sC,
                      float alpha, int mode, int causal_skip, int causal_k,
                      float* __restrict__ hhfp, const float* __restrict__ coefp,
                      u16* __restrict__ hbsp, u16* __restrict__ htsp)
{
    int bn = blockIdx.x, bm = blockIdx.y, bz = blockIdx.z;
    if (causal_skip && bn > bm) return;

    const u16* Ab = A + bz * sA + (long long)(bm * 64) * lda;
    const u16* Bb = B + bz * sB + (long long)(bn * 64) * ldb;

    __shared__ u16 sm[64 * 68];        // staging (2*64*32=4096) and mode-6 tile (64*66)
    u16* Al = sm;
    u16* Bl = sm + 64 * 32;

    int tid  = threadIdx.x;
    int lane = tid & 63;
    int wave = tid >> 6;

    int k_end = causal_k ? min(K, (bm + 1) * 64) : K;

    f32x4 acc[4];
    #pragma unroll
    for (int j = 0; j < 4; j++) acc[j] = (f32x4){0.f, 0.f, 0.f, 0.f};

    int srow   = tid >> 2;             // 0..63
    int schunk = (tid & 3) * 8;
    int fm     = lane & 15;
    int fk     = (lane >> 4) * 8;

    for (int k0 = 0; k0 < k_end; k0 += 32) {
        __syncthreads();
        GLD16(Ab + (long long)srow * lda + k0 + schunk, Al + srow * 32 + schunk);
        GLD16(Bb + (long long)srow * ldb + k0 + schunk, Bl + srow * 32 + schunk);
        __syncthreads();

        bh8 af = *(const bh8*)(Al + (wave * 16 + fm) * 32 + fk);
        bh8 bf[4];
        #pragma unroll
        for (int j = 0; j < 4; j++)
            bf[j] = *(const bh8*)(Bl + (j * 16 + fm) * 32 + fk);
        #pragma unroll
        for (int j = 0; j < 4; j++)
            acc[j] = __builtin_amdgcn_mfma_f32_16x16x32_bf16(af, bf[j], acc[j], 0, 0, 0);
    }

    int rbase = bm * 64 + wave * 16 + (lane >> 4) * 4;
    int cbase = bn * 64 + (lane & 15);
    long long zoff = (long long)bz * sC;
    if (mode == 1) {
        u16* C = (u16*)Cv + zoff;
        #pragma unroll
        for (int j = 0; j < 4; j++)
            #pragma unroll
            for (int r = 0; r < 4; r++)
                C[(long long)(rbase + r) * ldc + cbase + j * 16] = f2bf(acc[j][r] * alpha);
    } else if (mode == 3) {
        u16* C = (u16*)Cv + zoff;
        #pragma unroll
        for (int j = 0; j < 4; j++)
            #pragma unroll
            for (int r = 0; r < 4; r++) {
                union { _Float16 h; u16 u; } cv;
                cv.h = (_Float16)(acc[j][r] * alpha);
                C[(long long)(rbase + r) * ldc + cbase + j * 16] = cv.u;
            }
    } else if (mode == 6) {
        __syncthreads();               // staging LDS dead; reuse as transpose tile
        u16* tile = sm;                // [64][66]
        #pragma unroll
        for (int r = 0; r < 4; r++) {
            int t = rbase + r;                              // 0..1023
            long long rowg = (long long)bz * T_SEQ + t;
            float cf = coefp[rowg];
            int tl = t - bm * 64;
            #pragma unroll
            for (int j = 0; j < 4; j++) {
                int d = cbase + j * 16;
                long long idx = rowg * D_MODEL + d;
                float v = hhfp[idx];
                float nh = v + cf * (acc[j][r] - v);
                hhfp[idx] = nh;
                u16 w = f2bf(nh);
                hbsp[idx] = w;
                tile[((lane & 15) + j * 16) * 66 + tl] = w;
            }
        }
        __syncthreads();
        // coalesced transposed write: htsNew[b][bn*64+dl][bm*64 + t]
        int dl = tid >> 2, tch = (tid & 3) * 16;
        long long ob = (long long)bz * T_SEQ * D_MODEL +
                       (long long)(bn * 64 + dl) * T_SEQ + bm * 64 + tch;
        #pragma unroll
        for (int kk = 0; kk < 16; kk++)
            htsp[ob + kk] = tile[dl * 66 + tch + kk];
    } else {
        float* C = (float*)Cv + zoff;
        #pragma unroll
        for (int j = 0; j < 4; j++)
            #pragma unroll
            for (int r = 0; r < 4; r++)
                C[(long long)(rbase + r) * ldc + cbase + j * 16] = acc[j][r] * alpha;
    }
}

// ---------------------------------------------------------------------------
// LN pre: h = LN(x)*g+b; hhf = h; hbp = hbs = bf16(h)
// ---------------------------------------------------------------------------
__global__ __launch_bounds__(256)
void ln_pre_kernel(const float* __restrict__ x, const float* __restrict__ g,
                   const float* __restrict__ b, float* __restrict__ h,
                   float* __restrict__ hhf, u16* __restrict__ hbp,
                   u16* __restrict__ hbs)
{
    int row = blockIdx.x;
    long long base = (long long)row * D_MODEL;
    int tid = threadIdx.x, lane = tid & 63, wave = tid >> 6;
    __shared__ float red[4];
    float v[3]; float s = 0.f;
    #pragma unroll
    for (int k = 0; k < 3; k++) { v[k] = x[base + tid + k * 256]; s += v[k]; }
    s = wred_sum(s);
    if (lane == 0) red[wave] = s;
    __syncthreads();
    float mean = (red[0] + red[1] + red[2] + red[3]) * (1.f / D_MODEL);
    __syncthreads();
    float sq = 0.f;
    #pragma unroll
    for (int k = 0; k < 3; k++) { float dd = v[k] - mean; sq += dd * dd; }
    sq = wred_sum(sq);
    if (lane == 0) red[wave] = sq;
    __syncthreads();
    float var = (red[0] + red[1] + red[2] + red[3]) * (1.f / D_MODEL);
    float rstd = rsqrtf(var + 1e-5f);
    #pragma unroll
    for (int k = 0; k < 3; k++) {
        int c = tid + k * 256;
        float o = (v[k] - mean) * rstd * g[c] + b[c];
        h[base + c] = o; hhf[base + c] = o;
        u16 w = f2bf(o);
        hbp[base + c] = w; hbs[base + c] = w;
    }
}

// ---------------------------------------------------------------------------
// bf16 transpose, dual output: htp/hts0[b][d][t] = hb[b][t][d]
// ---------------------------------------------------------------------------
__global__ __launch_bounds__(256)
void transpose2_kernel(const u16* __restrict__ hb, u16* __restrict__ htp,
                       u16* __restrict__ hts)
{
    __shared__ u16 tile[32][33];
    int b = blockIdx.z;
    int d0 = blockIdx.x * 32, t0 = blockIdx.y * 32;
    int tx = threadIdx.x & 31, ty = threadIdx.x >> 5;
    long long bb = (long long)b * T_SEQ * D_MODEL;
    #pragma unroll
    for (int i = 0; i < 32; i += 8)
        tile[ty + i][tx] = hb[bb + (long long)(t0 + ty + i) * D_MODEL + d0 + tx];
    __syncthreads();
    #pragma unroll
    for (int i = 0; i < 32; i += 8) {
        long long o = bb + (long long)(d0 + ty + i) * T_SEQ + t0 + tx;
        u16 w = tile[tx][ty + i];
        htp[o] = w; hts[o] = w;
    }
}

// ---------------------------------------------------------------------------
// causal softmax, f16 in -> bf16 out, in place. grid (T, Z)
// ---------------------------------------------------------------------------
__global__ __launch_bounds__(256)
void softmax_kernel(u16* __restrict__ SP)
{
    int t = blockIdx.x, z = blockIdx.y;
    long long rb = (long long)z * T_SEQ * T_SEQ + (long long)t * T_SEQ;
    u16* row = SP + rb;
    int len = t + 1;
    int tid = threadIdx.x, lane = tid & 63, wave = tid >> 6;
    __shared__ float red[4];

    float ev[4];
    float m = -3.0e38f;
    #pragma unroll
    for (int k = 0; k < 4; k++) {
        int s = tid + k * 256;
        if (s < len) {
            union { u16 u; _Float16 h; } cv; cv.u = row[s];
            ev[k] = (float)cv.h;
        } else ev[k] = -3.0e38f;
        m = fmaxf(m, ev[k]);
    }
    m = wred_max(m);
    if (lane == 0) red[wave] = m;
    __syncthreads();
    m = fmaxf(fmaxf(red[0], red[1]), fmaxf(red[2], red[3]));
    __syncthreads();
    float sum = 0.f;
    #pragma unroll
    for (int k = 0; k < 4; k++) {
        int s = tid + k * 256;
        float e = (s < len) ? __expf(ev[k] - m) : 0.f;
        ev[k] = e; sum += e;
    }
    sum = wred_sum(sum);
    if (lane == 0) red[wave] = sum;
    __syncthreads();
    sum = red[0] + red[1] + red[2] + red[3];
    float inv = 1.f / sum;
    #pragma unroll
    for (int k = 0; k < 4; k++)
        row[tid + k * 256] = f2bf(ev[k] * inv);
}

// ---------------------------------------------------------------------------
// coef kernels: gate coefficient per row (hoisted out of PV epilogues)
// ---------------------------------------------------------------------------
__global__ __launch_bounds__(256)
void coef_seq_kernel(const float* __restrict__ hhf, const float* __restrict__ gw,
                     const float* __restrict__ gb, const float* __restrict__ sp,
                     int ci, float* __restrict__ coefS)
{
    int row = blockIdx.x * 4 + (threadIdx.x >> 6);
    int lane = threadIdx.x & 63;
    long long base = (long long)row * D_MODEL;
    const float* g = gw + ci * D_MODEL;
    float dot = 0.f;
    #pragma unroll
    for (int k = 0; k < 12; k++) dot += hhf[base + lane + 64 * k] * g[lane + 64 * k];
    dot = wred_sum(dot);
    if (lane == 0) {
        float gate = 1.f / (1.f + __expf(-(dot + gb[ci])));
        coefS[row] = log1pf(expf(sp[ci])) * chamber_mask(ci) * gate;
    }
}

__global__ __launch_bounds__(256)
void coef_par_kernel(const float* __restrict__ h, const float* __restrict__ gw,
                     const float* __restrict__ gb, const float* __restrict__ sp,
                     float* __restrict__ coefP)
{
    int row = blockIdx.x * 4 + (threadIdx.x >> 6);
    int lane = threadIdx.x & 63;
    long long base = (long long)row * D_MODEL;
    float hv[12];
    #pragma unroll
    for (int k = 0; k < 12; k++) hv[k] = h[base + lane + 64 * k];
    for (int ci = 0; ci < NCH; ci++) {
        const float* g = gw + ci * D_MODEL;
        float dot = 0.f;
        #pragma unroll
        for (int k = 0; k < 12; k++) dot += hv[k] * g[lane + 64 * k];
        dot = wred_sum(dot);
        if (lane == 0) {
            float gate = 1.f / (1.f + __expf(-(dot + gb[ci])));
            coefP[ci * ROWS + row] = log1pf(expf(sp[ci])) * chamber_mask(ci) * gate;
        }
    }
}

// ---------------------------------------------------------------------------
// vectorized f32 -> bf16 cast (n divisible by 4)
// ---------------------------------------------------------------------------
__global__ __launch_bounds__(256)
void cast4_kernel(const float4* __restrict__ in, ushort4* __restrict__ outp, int n4)
{
    int i = blockIdx.x * 256 + threadIdx.x;
    if (i < n4) {
        float4 v = in[i];
        ushort4 o;
        o.x = f2bf(v.x); o.y = f2bf(v.y); o.z = f2bf(v.z); o.w = f2bf(v.w);
        outp[i] = o;
    }
}

// ---------------------------------------------------------------------------
// final: par = sum of 7 bf16 partial slabs; e = (1-mg)*(hhf-h) + mg*par;
// out = x + rg*(LN(e)*g+b)
// ---------------------------------------------------------------------------
__global__ __launch_bounds__(256)
void final_kernel(const float* __restrict__ x, const float* __restrict__ h,
                  const float* __restrict__ hhf, const u16* __restrict__ Pp,
                  const float* __restrict__ mode_logit, const float* __restrict__ residual_gate,
                  const float* __restrict__ g, const float* __restrict__ b,
                  float* __restrict__ out)
{
    const long long RDe = (long long)ROWS * D_MODEL;
    int row = blockIdx.x;
    long long base = (long long)row * D_MODEL;
    int tid = threadIdx.x, lane = tid & 63, wave = tid >> 6;
    __shared__ float red[4];
    float mg = 1.f / (1.f + __expf(-mode_logit[0]));
    float rg = residual_gate[0];
    float e[3]; float s = 0.f;
    #pragma unroll
    for (int k = 0; k < 3; k++) {
        int c = tid + k * 256;
        float p = 0.f;
        #pragma unroll
        for (int z = 0; z < NCH; z++) p += bf2f(Pp[z * RDe + base + c]);
        float v = (1.f - mg) * (hhf[base + c] - h[base + c]) + mg * p;
        e[k] = v; s += v;
    }
    s = wred_sum(s);
    if (lane == 0) red[wave] = s;
    __syncthreads();
    float mean = (red[0] + red[1] + red[2] + red[3]) * (1.f / D_MODEL);
    __syncthreads();
    float sq = 0.f;
    #pragma unroll
    for (int k = 0; k < 3; k++) { float dd = e[k] - mean; sq += dd * dd; }
    sq = wred_sum(sq);
    if (lane == 0) red[wave] = sq;
    __syncthreads();
    float var = (red[0] + red[1] + red[2] + red[3]) * (1.f / D_MODEL);
    float rstd = rsqrtf(var + 1e-5f);
    #pragma unroll
    for (int k = 0; k < 3; k++) {
        int c = tid + k * 256;
        out[base + c] = x[base + c] + rg * ((e[k] - mean) * rstd * g[c] + b[c]);
    }
}

// ---------------------------------------------------------------------------
extern "C" void kernel_launch(void* const* d_in, const int* in_sizes, int n_in,
                              void* d_out, int out_size, void* d_ws, size_t ws_size,
                              hipStream_t stream)
{
    (void)in_sizes; (void)n_in; (void)out_size; (void)ws_size;
    const float* x             = (const float*)d_in[0];
    const float* Wq            = (const float*)d_in[1];
    const float* Wk            = (const float*)d_in[2];
    const float* gate_w        = (const float*)d_in[3];
    const float* gate_b        = (const float*)d_in[4];
    const float* scale_p       = (const float*)d_in[5];
    const float* merge_W       = (const float*)d_in[6];
    const float* mode_logit    = (const float*)d_in[7];
    const float* residual_gate = (const float*)d_in[8];
    const float* ln_pre_g      = (const float*)d_in[9];
    const float* ln_pre_b      = (const float*)d_in[10];
    const float* ln_post_g     = (const float*)d_in[11];
    const float* ln_post_b     = (const float*)d_in[12];
    float* out = (float*)d_out;

    const long long DD  = (long long)D_MODEL * D_MODEL;   // 589824
    const long long TD  = (long long)T_SEQ * D_MODEL;     // 786432
    const long long TTs = (long long)T_SEQ * T_SEQ;       // 1048576
    const long long RDe = (long long)ROWS * D_MODEL;      // 3145728

    size_t off = 0;
    char* wsb = (char*)d_ws;
    auto alloc = [&](size_t bytes) -> void* {
        void* p = wsb + off; off += (bytes + 255) & ~(size_t)255; return p;
    };
    u16*   Mtb  = (u16*)alloc((size_t)NCH * DD * 2);           // 8.26 MB
    u16*   mgb  = (u16*)alloc((size_t)D_MODEL * KM * 2);       // 8.26 MB
    float* h    = (float*)alloc(RDe * 4);                      // 12.6 MB
    float* hhf  = (float*)alloc(RDe * 4);                      // 12.6 MB
    u16*   hbp  = (u16*)alloc(RDe * 2);                        // frozen h (par)
    u16*   htp  = (u16*)alloc(RDe * 2);
    u16*   hbs  = (u16*)alloc(RDe * 2);                        // running hh (seq)
    u16*   hts0 = (u16*)alloc(RDe * 2);                        // hts ping-pong
    u16*   hts1 = (u16*)alloc(RDe * 2);
    u16*   Spar = (u16*)alloc((size_t)(NCH * BATCH) * TTs * 2);// 58.7 MB
    u16*   Sseq = (u16*)alloc((size_t)BATCH * TTs * 2);        // 8.4 MB
    u16*   Upar = (u16*)alloc((size_t)NCH * RDe * 2);          // 44.0 MB
    u16*   Useq = (u16*)alloc(RDe * 2);
    u16*   db   = (u16*)alloc((size_t)ROWS * KM * 2);          // 44.0 MB
    float* coefP= (float*)alloc((size_t)NCH * ROWS * 4);
    float* coefS= (float*)alloc((size_t)ROWS * 4);
    // transient aliases (stream-ordered lifetimes):
    u16*   Wqb  = Spar;                 // dead after Mtb GEMM, before Spar written
    u16*   Wkb  = Spar + (size_t)NCH * DD;
    u16*   Pp   = Upar;                 // merge partials: Upar dead after par scores
    // total ~235 MB

    const float sc = 1.0f / sqrtf((float)D_MODEL);
    const int N4W = (int)((size_t)NCH * DD) / 4;
    const int N4M = (int)((size_t)D_MODEL * KM) / 4;

    ln_pre_kernel<<<ROWS, 256, 0, stream>>>(x, ln_pre_g, ln_pre_b, h, hhf, hbp, hbs);
    cast4_kernel<<<(N4W + 255) / 256, 256, 0, stream>>>((const float4*)Wq, (ushort4*)Wqb, N4W);
    cast4_kernel<<<(N4W + 255) / 256, 256, 0, stream>>>((const float4*)Wk, (ushort4*)Wkb, N4W);
    cast4_kernel<<<(N4M + 255) / 256, 256, 0, stream>>>((const float4*)merge_W, (ushort4*)mgb, N4M);
    transpose2_kernel<<<dim3(24, 32, BATCH), 256, 0, stream>>>(hbp, htp, hts0);
    coef_par_kernel<<<ROWS / 4, 256, 0, stream>>>(h, gate_w, gate_b, scale_p, coefP);

    // Mt_i[d'][d] = sum_e Wk_i[d'][e] Wq_i[d][e]   (z=7)
    gemm_nt_kernel<<<dim3(6, 6, NCH), 256, 0, stream>>>(
        Wkb, Wqb, Mtb, D_MODEL, D_MODEL, D_MODEL, D_MODEL,
        DD, 0, DD, 0, DD, 0, NCH, 1.f, 1, 0, 0, 0, 0, nullptr, nullptr, nullptr);

    // ======================= par branch (frozen h, batched over chambers) ====
    // U_i = hbp @ Mt_i^T
    gemm_nt_kernel<<<dim3(6, 32, NCH), 256, 0, stream>>>(
        hbp, Mtb, Upar, D_MODEL, D_MODEL, D_MODEL, D_MODEL,
        0, 0, DD, 0, RDe, 0, NCH, 1.f, 1, 0, 0, 0, 0, nullptr, nullptr, nullptr);
    // scores: Spar[ch*4+b] = U_ch[b] @ hbp[b]^T * sc, causal, f16
    gemm_nt_kernel<<<dim3(8, 8, BATCH * NCH), 256, 0, stream>>>(
        Upar, hbp, Spar, D_MODEL, D_MODEL, D_MODEL, T_SEQ,
        TD, RDe, TD, 0, TTs, 4 * TTs, BATCH, sc, 3, 1, 0, 0, 0,
        nullptr, nullptr, nullptr);
    softmax_kernel<<<dim3(T_SEQ, BATCH * NCH), 256, 0, stream>>>(Spar);
    // PV + delta (mode 5): db[(b,t)][ch*768+d] = bf16(coef*(E - h)), causal K-limit
    gemm_nt_kernel<<<dim3(6, 8, BATCH * NCH), 256, 0, stream>>>(
        Spar, htp, nullptr, T_SEQ, T_SEQ, T_SEQ, D_MODEL,
        TTs, 4 * TTs, TD, 0, 0, 0, BATCH, 1.f, 5, 0, 1, 0, 0,
        coefP, h, db);
    // merge partials: Pp[ch] = d_ch @ Wm_ch^T  (K-slice per z; Pp aliases Upar)
    gemm_nt_kernel<<<dim3(6, 32, NCH), 256, 0, stream>>>(
        db, mgb, Pp, KM, KM, KM, D_MODEL,
        0, 0, 0, 0, RDe, 0, NCH, 1.f, 1, 0, 0, D_MODEL, D_MODEL,
        nullptr, nullptr, nullptr);

    // ======================= seq branch (serial chain, 64-tile) ==============
    u16* htsCur = hts0;
    u16* htsNxt = hts1;
    for (int i = 0; i < NCH; i++) {
        coef_seq_kernel<<<ROWS / 4, 256, 0, stream>>>(hhf, gate_w, gate_b, scale_p, i, coefS);
        // U = hbs @ Mt_i^T
        gemm64_nt_kernel<<<dim3(12, 64, 1), 256, 0, stream>>>(
            hbs, Mtb + (long long)i * DD, Useq,
            D_MODEL, D_MODEL, D_MODEL, D_MODEL, 0, 0, 0, 1.f, 1, 0, 0,
            nullptr, nullptr, nullptr, nullptr);
        // scores: Sseq[b] = U[b] @ hbs[b]^T * sc, causal
        gemm64_nt_kernel<<<dim3(16, 16, BATCH), 256, 0, stream>>>(
            Useq, hbs, Sseq, D_MODEL, D_MODEL, D_MODEL, T_SEQ,
            TD, TD, TTs, sc, 3, 1, 0, nullptr, nullptr, nullptr, nullptr);
        softmax_kernel<<<dim3(T_SEQ, BATCH), 256, 0, stream>>>(Sseq);
        // PV + delta (mode 6): hh' = hh + coef*(E-hh) -> hhf, hbs, htsNxt
        gemm64_nt_kernel<<<dim3(12, 16, BATCH), 256, 0, stream>>>(
            Sseq, htsCur, nullptr, T_SEQ, T_SEQ, T_SEQ, D_MODEL,
            TTs, TD, 0, 1.f, 6, 0, 1, hhf, coefS, hbs, htsNxt);
        u16* tmp = htsCur; htsCur = htsNxt; htsNxt = tmp;
    }

    final_kernel<<<ROWS, 256, 0, stream>>>(x, h, hhf, Pp, mode_logit, residual_gate,
                                           ln_post_g, ln_post_b, out);
}

// Round 9
// 952.610 us; speedup vs baseline: 1.4293x; 1.0346x over previous
//
#include <hip/hip_runtime.h>
#include <hip/hip_bf16.h>
#include <math.h>

#define D_MODEL 768
#define T_SEQ   1024
#define BATCH   4
#define NCH     7
#define ROWS    4096            // BATCH*T_SEQ
#define KM      (NCH * D_MODEL) // 5376

typedef unsigned short u16;
typedef __attribute__((ext_vector_type(8))) short bh8;   // 8 x bf16
typedef __attribute__((ext_vector_type(4))) float f32x4;

__device__ __forceinline__ u16 f2bf(float f) {
    union { float f; unsigned u; } v; v.f = f;
    return (u16)((v.u + 0x7fffu + ((v.u >> 16) & 1u)) >> 16);  // RNE
}
__device__ __forceinline__ float bf2f(u16 b) {
    union { unsigned u; float f; } v; v.u = ((unsigned)b) << 16;
    return v.f;
}
__device__ __forceinline__ float wred_sum(float v) {
    #pragma unroll
    for (int o = 32; o; o >>= 1) v += __shfl_down(v, o, 64);
    return v;
}
__device__ __forceinline__ float wred_max(float v) {
    #pragma unroll
    for (int o = 32; o; o >>= 1) v = fmaxf(v, __shfl_down(v, o, 64));
    return v;
}
__device__ __forceinline__ float chamber_mask(int i) {
    float slope = 8.0f * 7.0f / 2000.0f;
    return 1.0f / (1.0f + __expf(-slope * (4000.0f - 2000.0f * (i + 0.5f) / 7.0f)));
}

#define GLD16(g, l) __builtin_amdgcn_global_load_lds( \
    (const __attribute__((address_space(1))) void*)(g), \
    (__attribute__((address_space(3))) void*)(l), 16, 0, 0)

// ---------------------------------------------------------------------------
// 128x128-tile NT GEMM, BK=32: C = alpha * A[M,K] * B[N,K]^T  (bf16 in)
// mode: 0 f32 store, 1 bf16 store, 3 f16 store
// kss/klen: K slice per bz1 (merge partials). Deterministic throughout.
// ---------------------------------------------------------------------------
__global__ __launch_bounds__(256)
void gemm_nt_kernel(const u16* __restrict__ A, const u16* __restrict__ B,
                    void* __restrict__ Cv,
                    int K, int lda, int ldb, int ldc,
                    long long sA1, long long sA2, long long sB1, long long sB2,
                    long long sC1, long long sC2, int zm,
                    float alpha, int mode, int causal_skip, int causal_k,
                    int kss, int klen)
{
    int bn = blockIdx.x, bm = blockIdx.y, bz = blockIdx.z;
    if (causal_skip && bn > bm) return;
    int bz1 = bz % zm, bz2 = bz / zm;

    const u16* Ab = A + bz1 * sA1 + bz2 * sA2 + (long long)(bm * 128) * lda;
    const u16* Bb = B + bz1 * sB1 + bz2 * sB2 + (long long)(bn * 128) * ldb;

    __shared__ u16 sm[2 * 128 * 32];
    u16* Al = sm;
    u16* Bl = sm + 128 * 32;

    int tid  = threadIdx.x;
    int lane = tid & 63;
    int wave = tid >> 6;
    int wm = wave >> 1, wn = wave & 1;

    int k_begin = kss ? bz1 * kss : 0;
    int k_end   = klen ? (k_begin + klen) : K;
    if (causal_k) k_end = min(k_end, (bm + 1) * 128);

    f32x4 acc[4][4];
    #pragma unroll
    for (int i = 0; i < 4; i++)
        #pragma unroll
        for (int j = 0; j < 4; j++)
            acc[i][j] = (f32x4){0.f, 0.f, 0.f, 0.f};

    int srow = lane >> 2;
    int skq  = (lane & 3) * 8;
    int fm   = lane & 15;
    int fk   = (lane >> 4) * 8;

    for (int k0 = k_begin; k0 < k_end; k0 += 32) {
        __syncthreads();
        #pragma unroll
        for (int r = 0; r < 2; r++) {
            int row = r * 64 + wave * 16 + srow;
            GLD16(Ab + (long long)row * lda + k0 + skq, Al + row * 32 + skq);
            GLD16(Bb + (long long)row * ldb + k0 + skq, Bl + row * 32 + skq);
        }
        __syncthreads();

        bh8 af[4], bf[4];
        #pragma unroll
        for (int i = 0; i < 4; i++)
            af[i] = *(const bh8*)(Al + (wm * 64 + i * 16 + fm) * 32 + fk);
        #pragma unroll
        for (int j = 0; j < 4; j++)
            bf[j] = *(const bh8*)(Bl + (wn * 64 + j * 16 + fm) * 32 + fk);
        #pragma unroll
        for (int i = 0; i < 4; i++)
            #pragma unroll
            for (int j = 0; j < 4; j++)
                acc[i][j] = __builtin_amdgcn_mfma_f32_16x16x32_bf16(af[i], bf[j], acc[i][j], 0, 0, 0);
    }

    int rbase = bm * 128 + wm * 64 + (lane >> 4) * 4;
    int cbase = bn * 128 + wn * 64 + (lane & 15);
    long long zoff = bz1 * sC1 + bz2 * sC2;
    if (mode == 1) {
        u16* C = (u16*)Cv + zoff;
        #pragma unroll
        for (int i = 0; i < 4; i++)
            #pragma unroll
            for (int j = 0; j < 4; j++)
                #pragma unroll
                for (int r = 0; r < 4; r++)
                    C[(long long)(rbase + i * 16 + r) * ldc + cbase + j * 16] = f2bf(acc[i][j][r] * alpha);
    } else if (mode == 3) {
        u16* C = (u16*)Cv + zoff;
        #pragma unroll
        for (int i = 0; i < 4; i++)
            #pragma unroll
            for (int j = 0; j < 4; j++)
                #pragma unroll
                for (int r = 0; r < 4; r++) {
                    union { _Float16 h; u16 u; } cv;
                    cv.h = (_Float16)(acc[i][j][r] * alpha);
                    C[(long long)(rbase + i * 16 + r) * ldc + cbase + j * 16] = cv.u;
                }
    } else {
        float* C = (float*)Cv + zoff;
        #pragma unroll
        for (int i = 0; i < 4; i++)
            #pragma unroll
            for (int j = 0; j < 4; j++)
                #pragma unroll
                for (int r = 0; r < 4; r++)
                    C[(long long)(rbase + i * 16 + r) * ldc + cbase + j * 16] = acc[i][j][r] * alpha;
    }
}

// ---------------------------------------------------------------------------
// 64x64-tile NT GEMM, BK=32 — high-block-count launches (latency hiding).
// z decode: bz1 = bz % zm (stride s?1), bz2 = bz / zm (stride s?2).
// mode: 0 f32, 1 bf16, 3 f16,
//       5 par PV+delta: db[(bz1,t)][bz2*768+d] = bf16(coef*(acc - h))
//       6 seq PV+delta: hh' = hh + coef*(acc - hh) -> hhf, hbs, hts (transposed)
// ---------------------------------------------------------------------------
__global__ __launch_bounds__(256)
void gemm64_nt_kernel(const u16* __restrict__ A, const u16* __restrict__ B,
                      void* __restrict__ Cv,
                      int K, int lda, int ldb, int ldc,
                      long long sA1, long long sA2, long long sB1, long long sB2,
                      long long sC1, long long sC2, int zm,
                      float alpha, int mode, int causal_skip, int causal_k,
                      float* __restrict__ hhfp, const float* __restrict__ coefp,
                      u16* __restrict__ hbsp, u16* __restrict__ htsp,
                      const float* __restrict__ hp, u16* __restrict__ dbp)
{
    int bn = blockIdx.x, bm = blockIdx.y, bz = blockIdx.z;
    if (causal_skip && bn > bm) return;
    int bz1 = bz % zm, bz2 = bz / zm;

    const u16* Ab = A + bz1 * sA1 + bz2 * sA2 + (long long)(bm * 64) * lda;
    const u16* Bb = B + bz1 * sB1 + bz2 * sB2 + (long long)(bn * 64) * ldb;

    __shared__ u16 sm[64 * 68];        // staging (2*64*32) / mode-6 tile (64*66)
    u16* Al = sm;
    u16* Bl = sm + 64 * 32;

    int tid  = threadIdx.x;
    int lane = tid & 63;
    int wave = tid >> 6;

    int k_end = causal_k ? min(K, (bm + 1) * 64) : K;

    f32x4 acc[4];
    #pragma unroll
    for (int j = 0; j < 4; j++) acc[j] = (f32x4){0.f, 0.f, 0.f, 0.f};

    int srow   = tid >> 2;             // 0..63
    int schunk = (tid & 3) * 8;
    int fm     = lane & 15;
    int fk     = (lane >> 4) * 8;

    for (int k0 = 0; k0 < k_end; k0 += 32) {
        __syncthreads();
        GLD16(Ab + (long long)srow * lda + k0 + schunk, Al + srow * 32 + schunk);
        GLD16(Bb + (long long)srow * ldb + k0 + schunk, Bl + srow * 32 + schunk);
        __syncthreads();

        bh8 af = *(const bh8*)(Al + (wave * 16 + fm) * 32 + fk);
        bh8 bf[4];
        #pragma unroll
        for (int j = 0; j < 4; j++)
            bf[j] = *(const bh8*)(Bl + (j * 16 + fm) * 32 + fk);
        #pragma unroll
        for (int j = 0; j < 4; j++)
            acc[j] = __builtin_amdgcn_mfma_f32_16x16x32_bf16(af, bf[j], acc[j], 0, 0, 0);
    }

    int rbase = bm * 64 + wave * 16 + (lane >> 4) * 4;
    int cbase = bn * 64 + (lane & 15);
    long long zoff = bz1 * sC1 + bz2 * sC2;
    if (mode == 1) {
        u16* C = (u16*)Cv + zoff;
        #pragma unroll
        for (int j = 0; j < 4; j++)
            #pragma unroll
            for (int r = 0; r < 4; r++)
                C[(long long)(rbase + r) * ldc + cbase + j * 16] = f2bf(acc[j][r] * alpha);
    } else if (mode == 3) {
        u16* C = (u16*)Cv + zoff;
        #pragma unroll
        for (int j = 0; j < 4; j++)
            #pragma unroll
            for (int r = 0; r < 4; r++) {
                union { _Float16 h; u16 u; } cv;
                cv.h = (_Float16)(acc[j][r] * alpha);
                C[(long long)(rbase + r) * ldc + cbase + j * 16] = cv.u;
            }
    } else if (mode == 5) {
        // par PV + delta: bz1 = batch b, bz2 = chamber ch
        int b = bz1, ch = bz2;
        #pragma unroll
        for (int r = 0; r < 4; r++) {
            int t = rbase + r;
            long long rowg = (long long)b * T_SEQ + t;
            float cf = coefp[(long long)ch * ROWS + rowg];
            #pragma unroll
            for (int j = 0; j < 4; j++) {
                int d = cbase + j * 16;
                float hv = hp[rowg * D_MODEL + d];
                dbp[rowg * KM + ch * D_MODEL + d] = f2bf(cf * (acc[j][r] - hv));
            }
        }
    } else if (mode == 6) {
        __syncthreads();               // staging LDS dead; reuse as transpose tile
        u16* tile = sm;                // [64][66]
        #pragma unroll
        for (int r = 0; r < 4; r++) {
            int t = rbase + r;
            long long rowg = (long long)bz1 * T_SEQ + t;
            float cf = coefp[rowg];
            int tl = t - bm * 64;
            #pragma unroll
            for (int j = 0; j < 4; j++) {
                int d = cbase + j * 16;
                long long idx = rowg * D_MODEL + d;
                float v = hhfp[idx];
                float nh = v + cf * (acc[j][r] - v);
                hhfp[idx] = nh;
                u16 w = f2bf(nh);
                hbsp[idx] = w;
                tile[((lane & 15) + j * 16) * 66 + tl] = w;
            }
        }
        __syncthreads();
        int dl = tid >> 2, tch = (tid & 3) * 16;
        long long ob = (long long)bz1 * T_SEQ * D_MODEL +
                       (long long)(bn * 64 + dl) * T_SEQ + bm * 64 + tch;
        #pragma unroll
        for (int kk = 0; kk < 16; kk++)
            htsp[ob + kk] = tile[dl * 66 + tch + kk];
    } else {
        float* C = (float*)Cv + zoff;
        #pragma unroll
        for (int j = 0; j < 4; j++)
            #pragma unroll
            for (int r = 0; r < 4; r++)
                C[(long long)(rbase + r) * ldc + cbase + j * 16] = acc[j][r] * alpha;
    }
}

// ---------------------------------------------------------------------------
// LN pre: h = LN(x)*g+b; hhf = h; hbp = hbs = bf16(h)
// ---------------------------------------------------------------------------
__global__ __launch_bounds__(256)
void ln_pre_kernel(const float* __restrict__ x, const float* __restrict__ g,
                   const float* __restrict__ b, float* __restrict__ h,
                   float* __restrict__ hhf, u16* __restrict__ hbp,
                   u16* __restrict__ hbs)
{
    int row = blockIdx.x;
    long long base = (long long)row * D_MODEL;
    int tid = threadIdx.x, lane = tid & 63, wave = tid >> 6;
    __shared__ float red[4];
    float v[3]; float s = 0.f;
    #pragma unroll
    for (int k = 0; k < 3; k++) { v[k] = x[base + tid + k * 256]; s += v[k]; }
    s = wred_sum(s);
    if (lane == 0) red[wave] = s;
    __syncthreads();
    float mean = (red[0] + red[1] + red[2] + red[3]) * (1.f / D_MODEL);
    __syncthreads();
    float sq = 0.f;
    #pragma unroll
    for (int k = 0; k < 3; k++) { float dd = v[k] - mean; sq += dd * dd; }
    sq = wred_sum(sq);
    if (lane == 0) red[wave] = sq;
    __syncthreads();
    float var = (red[0] + red[1] + red[2] + red[3]) * (1.f / D_MODEL);
    float rstd = rsqrtf(var + 1e-5f);
    #pragma unroll
    for (int k = 0; k < 3; k++) {
        int c = tid + k * 256;
        float o = (v[k] - mean) * rstd * g[c] + b[c];
        h[base + c] = o; hhf[base + c] = o;
        u16 w = f2bf(o);
        hbp[base + c] = w; hbs[base + c] = w;
    }
}

// ---------------------------------------------------------------------------
// bf16 transpose, dual output
// ---------------------------------------------------------------------------
__global__ __launch_bounds__(256)
void transpose2_kernel(const u16* __restrict__ hb, u16* __restrict__ htp,
                       u16* __restrict__ hts)
{
    __shared__ u16 tile[32][33];
    int b = blockIdx.z;
    int d0 = blockIdx.x * 32, t0 = blockIdx.y * 32;
    int tx = threadIdx.x & 31, ty = threadIdx.x >> 5;
    long long bb = (long long)b * T_SEQ * D_MODEL;
    #pragma unroll
    for (int i = 0; i < 32; i += 8)
        tile[ty + i][tx] = hb[bb + (long long)(t0 + ty + i) * D_MODEL + d0 + tx];
    __syncthreads();
    #pragma unroll
    for (int i = 0; i < 32; i += 8) {
        long long o = bb + (long long)(d0 + ty + i) * T_SEQ + t0 + tx;
        u16 w = tile[tx][ty + i];
        htp[o] = w; hts[o] = w;
    }
}

// ---------------------------------------------------------------------------
// causal softmax, f16 in -> bf16 out, in place. grid (T, Z)  [par branch]
// ---------------------------------------------------------------------------
__device__ __forceinline__ void softmax_row(u16* row, int len, int tid, int lane, int wave,
                                            float* red)
{
    float ev[4];
    float m = -3.0e38f;
    #pragma unroll
    for (int k = 0; k < 4; k++) {
        int s = tid + k * 256;
        if (s < len) {
            union { u16 u; _Float16 h; } cv; cv.u = row[s];
            ev[k] = (float)cv.h;
        } else ev[k] = -3.0e38f;
        m = fmaxf(m, ev[k]);
    }
    m = wred_max(m);
    if (lane == 0) red[wave] = m;
    __syncthreads();
    m = fmaxf(fmaxf(red[0], red[1]), fmaxf(red[2], red[3]));
    __syncthreads();
    float sum = 0.f;
    #pragma unroll
    for (int k = 0; k < 4; k++) {
        int s = tid + k * 256;
        float e = (s < len) ? __expf(ev[k] - m) : 0.f;
        ev[k] = e; sum += e;
    }
    sum = wred_sum(sum);
    if (lane == 0) red[wave] = sum;
    __syncthreads();
    sum = red[0] + red[1] + red[2] + red[3];
    float inv = 1.f / sum;
    #pragma unroll
    for (int k = 0; k < 4; k++)
        row[tid + k * 256] = f2bf(ev[k] * inv);
}

__global__ __launch_bounds__(256)
void softmax_kernel(u16* __restrict__ SP)
{
    int t = blockIdx.x, z = blockIdx.y;
    __shared__ float red[4];
    int tid = threadIdx.x, lane = tid & 63, wave = tid >> 6;
    softmax_row(SP + (long long)z * T_SEQ * T_SEQ + (long long)t * T_SEQ,
                t + 1, tid, lane, wave, red);
}

// seq softmax + fused coef slice (z == BATCH computes gate coefs for 4 rows)
__global__ __launch_bounds__(256)
void softmax_coef_kernel(u16* __restrict__ SP, const float* __restrict__ hhf,
                         const float* __restrict__ gw, const float* __restrict__ gb,
                         const float* __restrict__ sp, int ci,
                         float* __restrict__ coefS)
{
    int t = blockIdx.x, z = blockIdx.y;
    int tid = threadIdx.x, lane = tid & 63, wave = tid >> 6;
    if (z == BATCH) {
        int row = t * 4 + wave;
        long long base = (long long)row * D_MODEL;
        const float* g = gw + ci * D_MODEL;
        float dot = 0.f;
        #pragma unroll
        for (int k = 0; k < 12; k++) dot += hhf[base + lane + 64 * k] * g[lane + 64 * k];
        dot = wred_sum(dot);
        if (lane == 0) {
            float gate = 1.f / (1.f + __expf(-(dot + gb[ci])));
            coefS[row] = log1pf(expf(sp[ci])) * chamber_mask(ci) * gate;
        }
        return;
    }
    __shared__ float red[4];
    softmax_row(SP + (long long)z * T_SEQ * T_SEQ + (long long)t * T_SEQ,
                t + 1, tid, lane, wave, red);
}

// ---------------------------------------------------------------------------
// par coef: gate coefficient per row for all 7 chambers (frozen h)
// ---------------------------------------------------------------------------
__global__ __launch_bounds__(256)
void coef_par_kernel(const float* __restrict__ h, const float* __restrict__ gw,
                     const float* __restrict__ gb, const float* __restrict__ sp,
                     float* __restrict__ coefP)
{
    int row = blockIdx.x * 4 + (threadIdx.x >> 6);
    int lane = threadIdx.x & 63;
    long long base = (long long)row * D_MODEL;
    float hv[12];
    #pragma unroll
    for (int k = 0; k < 12; k++) hv[k] = h[base + lane + 64 * k];
    for (int ci = 0; ci < NCH; ci++) {
        const float* g = gw + ci * D_MODEL;
        float dot = 0.f;
        #pragma unroll
        for (int k = 0; k < 12; k++) dot += hv[k] * g[lane + 64 * k];
        dot = wred_sum(dot);
        if (lane == 0) {
            float gate = 1.f / (1.f + __expf(-(dot + gb[ci])));
            coefP[ci * ROWS + row] = log1pf(expf(sp[ci])) * chamber_mask(ci) * gate;
        }
    }
}

// ---------------------------------------------------------------------------
__global__ __launch_bounds__(256)
void cast4_kernel(const float4* __restrict__ in, ushort4* __restrict__ outp, int n4)
{
    int i = blockIdx.x * 256 + threadIdx.x;
    if (i < n4) {
        float4 v = in[i];
        ushort4 o;
        o.x = f2bf(v.x); o.y = f2bf(v.y); o.z = f2bf(v.z); o.w = f2bf(v.w);
        outp[i] = o;
    }
}

// ---------------------------------------------------------------------------
// final: par = sum of 7 bf16 partial slabs; e = (1-mg)*(hhf-h) + mg*par;
// out = x + rg*(LN(e)*g+b)
// ---------------------------------------------------------------------------
__global__ __launch_bounds__(256)
void final_kernel(const float* __restrict__ x, const float* __restrict__ h,
                  const float* __restrict__ hhf, const u16* __restrict__ Pp,
                  const float* __restrict__ mode_logit, const float* __restrict__ residual_gate,
                  const float* __restrict__ g, const float* __restrict__ b,
                  float* __restrict__ out)
{
    const long long RDe = (long long)ROWS * D_MODEL;
    int row = blockIdx.x;
    long long base = (long long)row * D_MODEL;
    int tid = threadIdx.x, lane = tid & 63, wave = tid >> 6;
    __shared__ float red[4];
    float mg = 1.f / (1.f + __expf(-mode_logit[0]));
    float rg = residual_gate[0];
    float e[3]; float s = 0.f;
    #pragma unroll
    for (int k = 0; k < 3; k++) {
        int c = tid + k * 256;
        float p = 0.f;
        #pragma unroll
        for (int z = 0; z < NCH; z++) p += bf2f(Pp[z * RDe + base + c]);
        float v = (1.f - mg) * (hhf[base + c] - h[base + c]) + mg * p;
        e[k] = v; s += v;
    }
    s = wred_sum(s);
    if (lane == 0) red[wave] = s;
    __syncthreads();
    float mean = (red[0] + red[1] + red[2] + red[3]) * (1.f / D_MODEL);
    __syncthreads();
    float sq = 0.f;
    #pragma unroll
    for (int k = 0; k < 3; k++) { float dd = e[k] - mean; sq += dd * dd; }
    sq = wred_sum(sq);
    if (lane == 0) red[wave] = sq;
    __syncthreads();
    float var = (red[0] + red[1] + red[2] + red[3]) * (1.f / D_MODEL);
    float rstd = rsqrtf(var + 1e-5f);
    #pragma unroll
    for (int k = 0; k < 3; k++) {
        int c = tid + k * 256;
        out[base + c] = x[base + c] + rg * ((e[k] - mean) * rstd * g[c] + b[c]);
    }
}

// ---------------------------------------------------------------------------
extern "C" void kernel_launch(void* const* d_in, const int* in_sizes, int n_in,
                              void* d_out, int out_size, void* d_ws, size_t ws_size,
                              hipStream_t stream)
{
    (void)in_sizes; (void)n_in; (void)out_size; (void)ws_size;
    const float* x             = (const float*)d_in[0];
    const float* Wq            = (const float*)d_in[1];
    const float* Wk            = (const float*)d_in[2];
    const float* gate_w        = (const float*)d_in[3];
    const float* gate_b        = (const float*)d_in[4];
    const float* scale_p       = (const float*)d_in[5];
    const float* merge_W       = (const float*)d_in[6];
    const float* mode_logit    = (const float*)d_in[7];
    const float* residual_gate = (const float*)d_in[8];
    const float* ln_pre_g      = (const float*)d_in[9];
    const float* ln_pre_b      = (const float*)d_in[10];
    const float* ln_post_g     = (const float*)d_in[11];
    const float* ln_post_b     = (const float*)d_in[12];
    float* out = (float*)d_out;

    const long long DD  = (long long)D_MODEL * D_MODEL;   // 589824
    const long long TD  = (long long)T_SEQ * D_MODEL;     // 786432
    const long long TTs = (long long)T_SEQ * T_SEQ;       // 1048576
    const long long RDe = (long long)ROWS * D_MODEL;      // 3145728

    size_t off = 0;
    char* wsb = (char*)d_ws;
    auto alloc = [&](size_t bytes) -> void* {
        void* p = wsb + off; off += (bytes + 255) & ~(size_t)255; return p;
    };
    u16*   Mtb  = (u16*)alloc((size_t)NCH * DD * 2);
    u16*   mgb  = (u16*)alloc((size_t)D_MODEL * KM * 2);
    float* h    = (float*)alloc(RDe * 4);
    float* hhf  = (float*)alloc(RDe * 4);
    u16*   hbp  = (u16*)alloc(RDe * 2);
    u16*   htp  = (u16*)alloc(RDe * 2);
    u16*   hbs  = (u16*)alloc(RDe * 2);
    u16*   hts0 = (u16*)alloc(RDe * 2);
    u16*   hts1 = (u16*)alloc(RDe * 2);
    u16*   Spar = (u16*)alloc((size_t)(NCH * BATCH) * TTs * 2);
    u16*   Sseq = (u16*)alloc((size_t)BATCH * TTs * 2);
    u16*   Upar = (u16*)alloc((size_t)NCH * RDe * 2);
    u16*   Useq = (u16*)alloc(RDe * 2);
    u16*   db   = (u16*)alloc((size_t)ROWS * KM * 2);
    float* coefP= (float*)alloc((size_t)NCH * ROWS * 4);
    float* coefS= (float*)alloc((size_t)ROWS * 4);
    // transient aliases (stream-ordered lifetimes):
    u16*   Wqb  = Spar;                 // dead before Spar written
    u16*   Wkb  = Spar + (size_t)NCH * DD;
    u16*   Pp   = Upar;                 // merge partials: Upar dead after par scores

    const float sc = 1.0f / sqrtf((float)D_MODEL);
    const int N4W = (int)((size_t)NCH * DD) / 4;
    const int N4M = (int)((size_t)D_MODEL * KM) / 4;

    ln_pre_kernel<<<ROWS, 256, 0, stream>>>(x, ln_pre_g, ln_pre_b, h, hhf, hbp, hbs);
    cast4_kernel<<<(N4W + 255) / 256, 256, 0, stream>>>((const float4*)Wq, (ushort4*)Wqb, N4W);
    cast4_kernel<<<(N4W + 255) / 256, 256, 0, stream>>>((const float4*)Wk, (ushort4*)Wkb, N4W);
    cast4_kernel<<<(N4M + 255) / 256, 256, 0, stream>>>((const float4*)merge_W, (ushort4*)mgb, N4M);
    transpose2_kernel<<<dim3(24, 32, BATCH), 256, 0, stream>>>(hbp, htp, hts0);
    coef_par_kernel<<<ROWS / 4, 256, 0, stream>>>(h, gate_w, gate_b, scale_p, coefP);

    // Mt_i[d'][d] = sum_e Wk_i[d'][e] Wq_i[d][e]   (z=7)
    gemm_nt_kernel<<<dim3(6, 6, NCH), 256, 0, stream>>>(
        Wkb, Wqb, Mtb, D_MODEL, D_MODEL, D_MODEL, D_MODEL,
        DD, 0, DD, 0, DD, 0, NCH, 1.f, 1, 0, 0, 0, 0);

    // ======================= par branch (frozen h, batched over chambers) ====
    // U_i = hbp @ Mt_i^T  (128-tile; inputs fully L2-resident)
    gemm_nt_kernel<<<dim3(6, 32, NCH), 256, 0, stream>>>(
        hbp, Mtb, Upar, D_MODEL, D_MODEL, D_MODEL, D_MODEL,
        0, 0, DD, 0, RDe, 0, NCH, 1.f, 1, 0, 0, 0, 0);
    // scores (64-tile, ~3.8k blocks): Spar[ch*4+b] = U_ch[b] @ hbp[b]^T * sc
    gemm64_nt_kernel<<<dim3(16, 16, BATCH * NCH), 256, 0, stream>>>(
        Upar, hbp, Spar, D_MODEL, D_MODEL, D_MODEL, T_SEQ,
        TD, RDe, TD, 0, TTs, 4 * TTs, BATCH, sc, 3, 1, 0,
        nullptr, nullptr, nullptr, nullptr, nullptr, nullptr);
    softmax_kernel<<<dim3(T_SEQ, BATCH * NCH), 256, 0, stream>>>(Spar);
    // PV + delta (64-tile mode 5): db[(b,t)][ch*768+d] = bf16(coef*(E - h))
    gemm64_nt_kernel<<<dim3(12, 16, BATCH * NCH), 256, 0, stream>>>(
        Spar, htp, nullptr, T_SEQ, T_SEQ, T_SEQ, D_MODEL,
        TTs, 4 * TTs, TD, 0, 0, 0, BATCH, 1.f, 5, 0, 1,
        nullptr, coefP, nullptr, nullptr, h, db);
    // merge partials: Pp[ch] = d_ch @ Wm_ch^T  (K-slice per z; Pp aliases Upar)
    gemm_nt_kernel<<<dim3(6, 32, NCH), 256, 0, stream>>>(
        db, mgb, Pp, KM, KM, KM, D_MODEL,
        0, 0, 0, 0, RDe, 0, NCH, 1.f, 1, 0, 0, D_MODEL, D_MODEL);

    // ======================= seq branch (serial chain, 64-tile) ==============
    u16* htsCur = hts0;
    u16* htsNxt = hts1;
    for (int i = 0; i < NCH; i++) {
        // U = hbs @ Mt_i^T
        gemm64_nt_kernel<<<dim3(12, 64, 1), 256, 0, stream>>>(
            hbs, Mtb + (long long)i * DD, Useq,
            D_MODEL, D_MODEL, D_MODEL, D_MODEL, 0, 0, 0, 0, 0, 0, 1,
            1.f, 1, 0, 0, nullptr, nullptr, nullptr, nullptr, nullptr, nullptr);
        // scores: Sseq[b] = U[b] @ hbs[b]^T * sc, causal
        gemm64_nt_kernel<<<dim3(16, 16, BATCH), 256, 0, stream>>>(
            Useq, hbs, Sseq, D_MODEL, D_MODEL, D_MODEL, T_SEQ,
            TD, 0, TD, 0, TTs, 0, BATCH, sc, 3, 1, 0,
            nullptr, nullptr, nullptr, nullptr, nullptr, nullptr);
        // softmax + fused gate-coef slice (z == BATCH)
        softmax_coef_kernel<<<dim3(T_SEQ, BATCH + 1), 256, 0, stream>>>(
            Sseq, hhf, gate_w, gate_b, scale_p, i, coefS);
        // PV + delta (mode 6): hh' = hh + coef*(E-hh) -> hhf, hbs, htsNxt
        gemm64_nt_kernel<<<dim3(12, 16, BATCH), 256, 0, stream>>>(
            Sseq, htsCur, nullptr, T_SEQ, T_SEQ, T_SEQ, D_MODEL,
            TTs, 0, TD, 0, 0, 0, BATCH, 1.f, 6, 0, 1,
            hhf, coefS, hbs, htsNxt, nullptr, nullptr);
        u16* tmp = htsCur; htsCur = htsNxt; htsNxt = tmp;
    }

    final_kernel<<<ROWS, 256, 0, stream>>>(x, h, hhf, Pp, mode_logit, residual_gate,
                                           ln_post_g, ln_post_b, out);
}

// Round 10
// 907.865 us; speedup vs baseline: 1.4997x; 1.0493x over previous
//
#include <hip/hip_runtime.h>
#include <hip/hip_bf16.h>
#include <math.h>

#define D_MODEL 768
#define T_SEQ   1024
#define BATCH   4
#define NCH     7
#define ROWS    4096            // BATCH*T_SEQ
#define KM      (NCH * D_MODEL) // 5376

typedef unsigned short u16;
typedef __attribute__((ext_vector_type(8))) short bh8;   // 8 x bf16
typedef __attribute__((ext_vector_type(4))) float f32x4;

__device__ __forceinline__ u16 f2bf(float f) {
    union { float f; unsigned u; } v; v.f = f;
    return (u16)((v.u + 0x7fffu + ((v.u >> 16) & 1u)) >> 16);  // RNE
}
__device__ __forceinline__ float bf2f(u16 b) {
    union { unsigned u; float f; } v; v.u = ((unsigned)b) << 16;
    return v.f;
}
__device__ __forceinline__ float wred_sum(float v) {
    #pragma unroll
    for (int o = 32; o; o >>= 1) v += __shfl_down(v, o, 64);
    return v;
}
__device__ __forceinline__ float wred_max(float v) {
    #pragma unroll
    for (int o = 32; o; o >>= 1) v = fmaxf(v, __shfl_down(v, o, 64));
    return v;
}
__device__ __forceinline__ float chamber_mask(int i) {
    float slope = 8.0f * 7.0f / 2000.0f;
    return 1.0f / (1.0f + __expf(-slope * (4000.0f - 2000.0f * (i + 0.5f) / 7.0f)));
}

#define GLD16(g, l) __builtin_amdgcn_global_load_lds( \
    (const __attribute__((address_space(1))) void*)(g), \
    (__attribute__((address_space(3))) void*)(l), 16, 0, 0)

// ---------------------------------------------------------------------------
// 128x128-tile NT GEMM: C = alpha * A[M,K] * B[N,K]^T  (bf16 in)
// K=64 per barrier as TWO independent BK=32 panels (stride-32 LDS layout
// preserved -> no new bank conflicts; half the barrier drains).
// mode: 0 f32 store, 1 bf16 store, 3 f16 store
// kss/klen: K slice per bz1 (merge partials). All K extents multiple of 64.
// ---------------------------------------------------------------------------
__global__ __launch_bounds__(256)
void gemm_nt_kernel(const u16* __restrict__ A, const u16* __restrict__ B,
                    void* __restrict__ Cv,
                    int K, int lda, int ldb, int ldc,
                    long long sA1, long long sA2, long long sB1, long long sB2,
                    long long sC1, long long sC2, int zm,
                    float alpha, int mode, int causal_skip, int causal_k,
                    int kss, int klen)
{
    int bn = blockIdx.x, bm = blockIdx.y, bz = blockIdx.z;
    if (causal_skip && bn > bm) return;
    int bz1 = bz % zm, bz2 = bz / zm;

    const u16* Ab = A + bz1 * sA1 + bz2 * sA2 + (long long)(bm * 128) * lda;
    const u16* Bb = B + bz1 * sB1 + bz2 * sB2 + (long long)(bn * 128) * ldb;

    __shared__ u16 sm[4 * 128 * 32];   // 32 KB: A0|B0|A1|B1 panels
    u16* Al0 = sm;
    u16* Bl0 = sm + 128 * 32;
    u16* Al1 = sm + 2 * 128 * 32;
    u16* Bl1 = sm + 3 * 128 * 32;

    int tid  = threadIdx.x;
    int lane = tid & 63;
    int wave = tid >> 6;
    int wm = wave >> 1, wn = wave & 1;

    int k_begin = kss ? bz1 * kss : 0;
    int k_end   = klen ? (k_begin + klen) : K;
    if (causal_k) k_end = min(k_end, (bm + 1) * 128);

    f32x4 acc[4][4];
    #pragma unroll
    for (int i = 0; i < 4; i++)
        #pragma unroll
        for (int j = 0; j < 4; j++)
            acc[i][j] = (f32x4){0.f, 0.f, 0.f, 0.f};

    int srow = lane >> 2;
    int skq  = (lane & 3) * 8;
    int fm   = lane & 15;
    int fk   = (lane >> 4) * 8;

    for (int k0 = k_begin; k0 < k_end; k0 += 64) {
        __syncthreads();
        #pragma unroll
        for (int r = 0; r < 2; r++) {
            int row = r * 64 + wave * 16 + srow;
            long long ra = (long long)row * lda + k0 + skq;
            long long rb2 = (long long)row * ldb + k0 + skq;
            GLD16(Ab + ra,      Al0 + row * 32 + skq);
            GLD16(Bb + rb2,     Bl0 + row * 32 + skq);
            GLD16(Ab + ra + 32, Al1 + row * 32 + skq);
            GLD16(Bb + rb2 + 32, Bl1 + row * 32 + skq);
        }
        __syncthreads();

        #pragma unroll
        for (int p = 0; p < 2; p++) {
            const u16* Al = p ? Al1 : Al0;
            const u16* Bl = p ? Bl1 : Bl0;
            bh8 af[4], bf[4];
            #pragma unroll
            for (int i = 0; i < 4; i++)
                af[i] = *(const bh8*)(Al + (wm * 64 + i * 16 + fm) * 32 + fk);
            #pragma unroll
            for (int j = 0; j < 4; j++)
                bf[j] = *(const bh8*)(Bl + (wn * 64 + j * 16 + fm) * 32 + fk);
            #pragma unroll
            for (int i = 0; i < 4; i++)
                #pragma unroll
                for (int j = 0; j < 4; j++)
                    acc[i][j] = __builtin_amdgcn_mfma_f32_16x16x32_bf16(af[i], bf[j], acc[i][j], 0, 0, 0);
        }
    }

    int rbase = bm * 128 + wm * 64 + (lane >> 4) * 4;
    int cbase = bn * 128 + wn * 64 + (lane & 15);
    long long zoff = bz1 * sC1 + bz2 * sC2;
    if (mode == 1) {
        u16* C = (u16*)Cv + zoff;
        #pragma unroll
        for (int i = 0; i < 4; i++)
            #pragma unroll
            for (int j = 0; j < 4; j++)
                #pragma unroll
                for (int r = 0; r < 4; r++)
                    C[(long long)(rbase + i * 16 + r) * ldc + cbase + j * 16] = f2bf(acc[i][j][r] * alpha);
    } else if (mode == 3) {
        u16* C = (u16*)Cv + zoff;
        #pragma unroll
        for (int i = 0; i < 4; i++)
            #pragma unroll
            for (int j = 0; j < 4; j++)
                #pragma unroll
                for (int r = 0; r < 4; r++) {
                    union { _Float16 h; u16 u; } cv;
                    cv.h = (_Float16)(acc[i][j][r] * alpha);
                    C[(long long)(rbase + i * 16 + r) * ldc + cbase + j * 16] = cv.u;
                }
    } else {
        float* C = (float*)Cv + zoff;
        #pragma unroll
        for (int i = 0; i < 4; i++)
            #pragma unroll
            for (int j = 0; j < 4; j++)
                #pragma unroll
                for (int r = 0; r < 4; r++)
                    C[(long long)(rbase + i * 16 + r) * ldc + cbase + j * 16] = acc[i][j][r] * alpha;
    }
}

// ---------------------------------------------------------------------------
// 64x64-tile NT GEMM — high-block-count launches. Same two-panel K=64 trick.
// z decode: bz1 = bz % zm (stride s?1), bz2 = bz / zm (stride s?2).
// mode: 0 f32, 1 bf16, 3 f16,
//       5 par PV+delta: db[(bz1,t)][bz2*768+d] = bf16(coef*(acc - h))
//       6 seq PV+delta: hh' = hh + coef*(acc - hh) -> hhf, hbs, hts (transposed)
// ---------------------------------------------------------------------------
__global__ __launch_bounds__(256)
void gemm64_nt_kernel(const u16* __restrict__ A, const u16* __restrict__ B,
                      void* __restrict__ Cv,
                      int K, int lda, int ldb, int ldc,
                      long long sA1, long long sA2, long long sB1, long long sB2,
                      long long sC1, long long sC2, int zm,
                      float alpha, int mode, int causal_skip, int causal_k,
                      float* __restrict__ hhfp, const float* __restrict__ coefp,
                      u16* __restrict__ hbsp, u16* __restrict__ htsp,
                      const float* __restrict__ hp, u16* __restrict__ dbp)
{
    int bn = blockIdx.x, bm = blockIdx.y, bz = blockIdx.z;
    if (causal_skip && bn > bm) return;
    int bz1 = bz % zm, bz2 = bz / zm;

    const u16* Ab = A + bz1 * sA1 + bz2 * sA2 + (long long)(bm * 64) * lda;
    const u16* Bb = B + bz1 * sB1 + bz2 * sB2 + (long long)(bn * 64) * ldb;

    __shared__ u16 sm[4 * 64 * 32];    // 16 KB: A0|B0|A1|B1 (mode-6 tile reuses)
    u16* Al0 = sm;
    u16* Bl0 = sm + 64 * 32;
    u16* Al1 = sm + 2 * 64 * 32;
    u16* Bl1 = sm + 3 * 64 * 32;

    int tid  = threadIdx.x;
    int lane = tid & 63;
    int wave = tid >> 6;

    int k_end = causal_k ? min(K, (bm + 1) * 64) : K;

    f32x4 acc[4];
    #pragma unroll
    for (int j = 0; j < 4; j++) acc[j] = (f32x4){0.f, 0.f, 0.f, 0.f};

    int srow   = tid >> 2;             // 0..63
    int schunk = (tid & 3) * 8;
    int fm     = lane & 15;
    int fk     = (lane >> 4) * 8;

    for (int k0 = 0; k0 < k_end; k0 += 64) {
        __syncthreads();
        {
            long long ra  = (long long)srow * lda + k0 + schunk;
            long long rb2 = (long long)srow * ldb + k0 + schunk;
            GLD16(Ab + ra,       Al0 + srow * 32 + schunk);
            GLD16(Bb + rb2,      Bl0 + srow * 32 + schunk);
            GLD16(Ab + ra + 32,  Al1 + srow * 32 + schunk);
            GLD16(Bb + rb2 + 32, Bl1 + srow * 32 + schunk);
        }
        __syncthreads();

        #pragma unroll
        for (int p = 0; p < 2; p++) {
            const u16* Al = p ? Al1 : Al0;
            const u16* Bl = p ? Bl1 : Bl0;
            bh8 af = *(const bh8*)(Al + (wave * 16 + fm) * 32 + fk);
            bh8 bf[4];
            #pragma unroll
            for (int j = 0; j < 4; j++)
                bf[j] = *(const bh8*)(Bl + (j * 16 + fm) * 32 + fk);
            #pragma unroll
            for (int j = 0; j < 4; j++)
                acc[j] = __builtin_amdgcn_mfma_f32_16x16x32_bf16(af, bf[j], acc[j], 0, 0, 0);
        }
    }

    int rbase = bm * 64 + wave * 16 + (lane >> 4) * 4;
    int cbase = bn * 64 + (lane & 15);
    long long zoff = bz1 * sC1 + bz2 * sC2;
    if (mode == 1) {
        u16* C = (u16*)Cv + zoff;
        #pragma unroll
        for (int j = 0; j < 4; j++)
            #pragma unroll
            for (int r = 0; r < 4; r++)
                C[(long long)(rbase + r) * ldc + cbase + j * 16] = f2bf(acc[j][r] * alpha);
    } else if (mode == 3) {
        u16* C = (u16*)Cv + zoff;
        #pragma unroll
        for (int j = 0; j < 4; j++)
            #pragma unroll
            for (int r = 0; r < 4; r++) {
                union { _Float16 h; u16 u; } cv;
                cv.h = (_Float16)(acc[j][r] * alpha);
                C[(long long)(rbase + r) * ldc + cbase + j * 16] = cv.u;
            }
    } else if (mode == 5) {
        // par PV + delta: bz1 = batch b, bz2 = chamber ch
        int b = bz1, ch = bz2;
        #pragma unroll
        for (int r = 0; r < 4; r++) {
            int t = rbase + r;
            long long rowg = (long long)b * T_SEQ + t;
            float cf = coefp[(long long)ch * ROWS + rowg];
            #pragma unroll
            for (int j = 0; j < 4; j++) {
                int d = cbase + j * 16;
                float hv = hp[rowg * D_MODEL + d];
                dbp[rowg * KM + ch * D_MODEL + d] = f2bf(cf * (acc[j][r] - hv));
            }
        }
    } else if (mode == 6) {
        __syncthreads();               // staging LDS dead; reuse as transpose tile
        u16* tile = sm;                // [64][66] = 4224 u16 < 8192 fits
        #pragma unroll
        for (int r = 0; r < 4; r++) {
            int t = rbase + r;
            long long rowg = (long long)bz1 * T_SEQ + t;
            float cf = coefp[rowg];
            int tl = t - bm * 64;
            #pragma unroll
            for (int j = 0; j < 4; j++) {
                int d = cbase + j * 16;
                long long idx = rowg * D_MODEL + d;
                float v = hhfp[idx];
                float nh = v + cf * (acc[j][r] - v);
                hhfp[idx] = nh;
                u16 w = f2bf(nh);
                hbsp[idx] = w;
                tile[((lane & 15) + j * 16) * 66 + tl] = w;
            }
        }
        __syncthreads();
        int dl = tid >> 2, tch = (tid & 3) * 16;
        long long ob = (long long)bz1 * T_SEQ * D_MODEL +
                       (long long)(bn * 64 + dl) * T_SEQ + bm * 64 + tch;
        #pragma unroll
        for (int kk = 0; kk < 16; kk++)
            htsp[ob + kk] = tile[dl * 66 + tch + kk];
    } else {
        float* C = (float*)Cv + zoff;
        #pragma unroll
        for (int j = 0; j < 4; j++)
            #pragma unroll
            for (int r = 0; r < 4; r++)
                C[(long long)(rbase + r) * ldc + cbase + j * 16] = acc[j][r] * alpha;
    }
}

// ---------------------------------------------------------------------------
// LN pre: h = LN(x)*g+b; hhf = h; hbp = hbs = bf16(h)
// ---------------------------------------------------------------------------
__global__ __launch_bounds__(256)
void ln_pre_kernel(const float* __restrict__ x, const float* __restrict__ g,
                   const float* __restrict__ b, float* __restrict__ h,
                   float* __restrict__ hhf, u16* __restrict__ hbp,
                   u16* __restrict__ hbs)
{
    int row = blockIdx.x;
    long long base = (long long)row * D_MODEL;
    int tid = threadIdx.x, lane = tid & 63, wave = tid >> 6;
    __shared__ float red[4];
    float v[3]; float s = 0.f;
    #pragma unroll
    for (int k = 0; k < 3; k++) { v[k] = x[base + tid + k * 256]; s += v[k]; }
    s = wred_sum(s);
    if (lane == 0) red[wave] = s;
    __syncthreads();
    float mean = (red[0] + red[1] + red[2] + red[3]) * (1.f / D_MODEL);
    __syncthreads();
    float sq = 0.f;
    #pragma unroll
    for (int k = 0; k < 3; k++) { float dd = v[k] - mean; sq += dd * dd; }
    sq = wred_sum(sq);
    if (lane == 0) red[wave] = sq;
    __syncthreads();
    float var = (red[0] + red[1] + red[2] + red[3]) * (1.f / D_MODEL);
    float rstd = rsqrtf(var + 1e-5f);
    #pragma unroll
    for (int k = 0; k < 3; k++) {
        int c = tid + k * 256;
        float o = (v[k] - mean) * rstd * g[c] + b[c];
        h[base + c] = o; hhf[base + c] = o;
        u16 w = f2bf(o);
        hbp[base + c] = w; hbs[base + c] = w;
    }
}

// ---------------------------------------------------------------------------
// bf16 transpose, dual output
// ---------------------------------------------------------------------------
__global__ __launch_bounds__(256)
void transpose2_kernel(const u16* __restrict__ hb, u16* __restrict__ htp,
                       u16* __restrict__ hts)
{
    __shared__ u16 tile[32][33];
    int b = blockIdx.z;
    int d0 = blockIdx.x * 32, t0 = blockIdx.y * 32;
    int tx = threadIdx.x & 31, ty = threadIdx.x >> 5;
    long long bb = (long long)b * T_SEQ * D_MODEL;
    #pragma unroll
    for (int i = 0; i < 32; i += 8)
        tile[ty + i][tx] = hb[bb + (long long)(t0 + ty + i) * D_MODEL + d0 + tx];
    __syncthreads();
    #pragma unroll
    for (int i = 0; i < 32; i += 8) {
        long long o = bb + (long long)(d0 + ty + i) * T_SEQ + t0 + tx;
        u16 w = tile[tx][ty + i];
        htp[o] = w; hts[o] = w;
    }
}

// ---------------------------------------------------------------------------
// causal softmax, f16 in -> bf16 out, in place
// ---------------------------------------------------------------------------
__device__ __forceinline__ void softmax_row(u16* row, int len, int tid, int lane, int wave,
                                            float* red)
{
    float ev[4];
    float m = -3.0e38f;
    #pragma unroll
    for (int k = 0; k < 4; k++) {
        int s = tid + k * 256;
        if (s < len) {
            union { u16 u; _Float16 h; } cv; cv.u = row[s];
            ev[k] = (float)cv.h;
        } else ev[k] = -3.0e38f;
        m = fmaxf(m, ev[k]);
    }
    m = wred_max(m);
    if (lane == 0) red[wave] = m;
    __syncthreads();
    m = fmaxf(fmaxf(red[0], red[1]), fmaxf(red[2], red[3]));
    __syncthreads();
    float sum = 0.f;
    #pragma unroll
    for (int k = 0; k < 4; k++) {
        int s = tid + k * 256;
        float e = (s < len) ? __expf(ev[k] - m) : 0.f;
        ev[k] = e; sum += e;
    }
    sum = wred_sum(sum);
    if (lane == 0) red[wave] = sum;
    __syncthreads();
    sum = red[0] + red[1] + red[2] + red[3];
    float inv = 1.f / sum;
    #pragma unroll
    for (int k = 0; k < 4; k++)
        row[tid + k * 256] = f2bf(ev[k] * inv);
}

__global__ __launch_bounds__(256)
void softmax_kernel(u16* __restrict__ SP)
{
    int t = blockIdx.x, z = blockIdx.y;
    __shared__ float red[4];
    int tid = threadIdx.x, lane = tid & 63, wave = tid >> 6;
    softmax_row(SP + (long long)z * T_SEQ * T_SEQ + (long long)t * T_SEQ,
                t + 1, tid, lane, wave, red);
}

// seq softmax + fused coef slice (z == BATCH computes gate coefs for 4 rows)
__global__ __launch_bounds__(256)
void softmax_coef_kernel(u16* __restrict__ SP, const float* __restrict__ hhf,
                         const float* __restrict__ gw, const float* __restrict__ gb,
                         const float* __restrict__ sp, int ci,
                         float* __restrict__ coefS)
{
    int t = blockIdx.x, z = blockIdx.y;
    int tid = threadIdx.x, lane = tid & 63, wave = tid >> 6;
    if (z == BATCH) {
        int row = t * 4 + wave;
        long long base = (long long)row * D_MODEL;
        const float* g = gw + ci * D_MODEL;
        float dot = 0.f;
        #pragma unroll
        for (int k = 0; k < 12; k++) dot += hhf[base + lane + 64 * k] * g[lane + 64 * k];
        dot = wred_sum(dot);
        if (lane == 0) {
            float gate = 1.f / (1.f + __expf(-(dot + gb[ci])));
            coefS[row] = log1pf(expf(sp[ci])) * chamber_mask(ci) * gate;
        }
        return;
    }
    __shared__ float red[4];
    softmax_row(SP + (long long)z * T_SEQ * T_SEQ + (long long)t * T_SEQ,
                t + 1, tid, lane, wave, red);
}

// ---------------------------------------------------------------------------
// par coef: gate coefficient per row for all 7 chambers (frozen h)
// ---------------------------------------------------------------------------
__global__ __launch_bounds__(256)
void coef_par_kernel(const float* __restrict__ h, const float* __restrict__ gw,
                     const float* __restrict__ gb, const float* __restrict__ sp,
                     float* __restrict__ coefP)
{
    int row = blockIdx.x * 4 + (threadIdx.x >> 6);
    int lane = threadIdx.x & 63;
    long long base = (long long)row * D_MODEL;
    float hv[12];
    #pragma unroll
    for (int k = 0; k < 12; k++) hv[k] = h[base + lane + 64 * k];
    for (int ci = 0; ci < NCH; ci++) {
        const float* g = gw + ci * D_MODEL;
        float dot = 0.f;
        #pragma unroll
        for (int k = 0; k < 12; k++) dot += hv[k] * g[lane + 64 * k];
        dot = wred_sum(dot);
        if (lane == 0) {
            float gate = 1.f / (1.f + __expf(-(dot + gb[ci])));
            coefP[ci * ROWS + row] = log1pf(expf(sp[ci])) * chamber_mask(ci) * gate;
        }
    }
}

// ---------------------------------------------------------------------------
__global__ __launch_bounds__(256)
void cast4_kernel(const float4* __restrict__ in, ushort4* __restrict__ outp, int n4)
{
    int i = blockIdx.x * 256 + threadIdx.x;
    if (i < n4) {
        float4 v = in[i];
        ushort4 o;
        o.x = f2bf(v.x); o.y = f2bf(v.y); o.z = f2bf(v.z); o.w = f2bf(v.w);
        outp[i] = o;
    }
}

// ---------------------------------------------------------------------------
// final: par = sum of 7 bf16 partial slabs; e = (1-mg)*(hhf-h) + mg*par;
// out = x + rg*(LN(e)*g+b)
// ---------------------------------------------------------------------------
__global__ __launch_bounds__(256)
void final_kernel(const float* __restrict__ x, const float* __restrict__ h,
                  const float* __restrict__ hhf, const u16* __restrict__ Pp,
                  const float* __restrict__ mode_logit, const float* __restrict__ residual_gate,
                  const float* __restrict__ g, const float* __restrict__ b,
                  float* __restrict__ out)
{
    const long long RDe = (long long)ROWS * D_MODEL;
    int row = blockIdx.x;
    long long base = (long long)row * D_MODEL;
    int tid = threadIdx.x, lane = tid & 63, wave = tid >> 6;
    __shared__ float red[4];
    float mg = 1.f / (1.f + __expf(-mode_logit[0]));
    float rg = residual_gate[0];
    float e[3]; float s = 0.f;
    #pragma unroll
    for (int k = 0; k < 3; k++) {
        int c = tid + k * 256;
        float p = 0.f;
        #pragma unroll
        for (int z = 0; z < NCH; z++) p += bf2f(Pp[z * RDe + base + c]);
        float v = (1.f - mg) * (hhf[base + c] - h[base + c]) + mg * p;
        e[k] = v; s += v;
    }
    s = wred_sum(s);
    if (lane == 0) red[wave] = s;
    __syncthreads();
    float mean = (red[0] + red[1] + red[2] + red[3]) * (1.f / D_MODEL);
    __syncthreads();
    float sq = 0.f;
    #pragma unroll
    for (int k = 0; k < 3; k++) { float dd = e[k] - mean; sq += dd * dd; }
    sq = wred_sum(sq);
    if (lane == 0) red[wave] = sq;
    __syncthreads();
    float var = (red[0] + red[1] + red[2] + red[3]) * (1.f / D_MODEL);
    float rstd = rsqrtf(var + 1e-5f);
    #pragma unroll
    for (int k = 0; k < 3; k++) {
        int c = tid + k * 256;
        out[base + c] = x[base + c] + rg * ((e[k] - mean) * rstd * g[c] + b[c]);
    }
}

// ---------------------------------------------------------------------------
extern "C" void kernel_launch(void* const* d_in, const int* in_sizes, int n_in,
                              void* d_out, int out_size, void* d_ws, size_t ws_size,
                              hipStream_t stream)
{
    (void)in_sizes; (void)n_in; (void)out_size; (void)ws_size;
    const float* x             = (const float*)d_in[0];
    const float* Wq            = (const float*)d_in[1];
    const float* Wk            = (const float*)d_in[2];
    const float* gate_w        = (const float*)d_in[3];
    const float* gate_b        = (const float*)d_in[4];
    const float* scale_p       = (const float*)d_in[5];
    const float* merge_W       = (const float*)d_in[6];
    const float* mode_logit    = (const float*)d_in[7];
    const float* residual_gate = (const float*)d_in[8];
    const float* ln_pre_g      = (const float*)d_in[9];
    const float* ln_pre_b      = (const float*)d_in[10];
    const float* ln_post_g     = (const float*)d_in[11];
    const float* ln_post_b     = (const float*)d_in[12];
    float* out = (float*)d_out;

    const long long DD  = (long long)D_MODEL * D_MODEL;   // 589824
    const long long TD  = (long long)T_SEQ * D_MODEL;     // 786432
    const long long TTs = (long long)T_SEQ * T_SEQ;       // 1048576
    const long long RDe = (long long)ROWS * D_MODEL;      // 3145728

    size_t off = 0;
    char* wsb = (char*)d_ws;
    auto alloc = [&](size_t bytes) -> void* {
        void* p = wsb + off; off += (bytes + 255) & ~(size_t)255; return p;
    };
    u16*   Mtb  = (u16*)alloc((size_t)NCH * DD * 2);
    u16*   mgb  = (u16*)alloc((size_t)D_MODEL * KM * 2);
    float* h    = (float*)alloc(RDe * 4);
    float* hhf  = (float*)alloc(RDe * 4);
    u16*   hbp  = (u16*)alloc(RDe * 2);
    u16*   htp  = (u16*)alloc(RDe * 2);
    u16*   hbs  = (u16*)alloc(RDe * 2);
    u16*   hts0 = (u16*)alloc(RDe * 2);
    u16*   hts1 = (u16*)alloc(RDe * 2);
    u16*   Spar = (u16*)alloc((size_t)(NCH * BATCH) * TTs * 2);
    u16*   Sseq = (u16*)alloc((size_t)BATCH * TTs * 2);
    u16*   Upar = (u16*)alloc((size_t)NCH * RDe * 2);
    u16*   Useq = (u16*)alloc(RDe * 2);
    u16*   db   = (u16*)alloc((size_t)ROWS * KM * 2);
    float* coefP= (float*)alloc((size_t)NCH * ROWS * 4);
    float* coefS= (float*)alloc((size_t)ROWS * 4);
    // transient aliases (stream-ordered lifetimes):
    u16*   Wqb  = Spar;                 // dead before Spar written
    u16*   Wkb  = Spar + (size_t)NCH * DD;
    u16*   Pp   = Upar;                 // merge partials: Upar dead after par scores

    const float sc = 1.0f / sqrtf((float)D_MODEL);
    const int N4W = (int)((size_t)NCH * DD) / 4;
    const int N4M = (int)((size_t)D_MODEL * KM) / 4;

    ln_pre_kernel<<<ROWS, 256, 0, stream>>>(x, ln_pre_g, ln_pre_b, h, hhf, hbp, hbs);
    cast4_kernel<<<(N4W + 255) / 256, 256, 0, stream>>>((const float4*)Wq, (ushort4*)Wqb, N4W);
    cast4_kernel<<<(N4W + 255) / 256, 256, 0, stream>>>((const float4*)Wk, (ushort4*)Wkb, N4W);
    cast4_kernel<<<(N4M + 255) / 256, 256, 0, stream>>>((const float4*)merge_W, (ushort4*)mgb, N4M);
    transpose2_kernel<<<dim3(24, 32, BATCH), 256, 0, stream>>>(hbp, htp, hts0);
    coef_par_kernel<<<ROWS / 4, 256, 0, stream>>>(h, gate_w, gate_b, scale_p, coefP);

    // Mt_i[d'][d] = sum_e Wk_i[d'][e] Wq_i[d][e]   (z=7)
    gemm_nt_kernel<<<dim3(6, 6, NCH), 256, 0, stream>>>(
        Wkb, Wqb, Mtb, D_MODEL, D_MODEL, D_MODEL, D_MODEL,
        DD, 0, DD, 0, DD, 0, NCH, 1.f, 1, 0, 0, 0, 0);

    // ======================= par branch (frozen h, batched over chambers) ====
    // U_i = hbp @ Mt_i^T  (128-tile)
    gemm_nt_kernel<<<dim3(6, 32, NCH), 256, 0, stream>>>(
        hbp, Mtb, Upar, D_MODEL, D_MODEL, D_MODEL, D_MODEL,
        0, 0, DD, 0, RDe, 0, NCH, 1.f, 1, 0, 0, 0, 0);
    // scores (64-tile): Spar[ch*4+b] = U_ch[b] @ hbp[b]^T * sc
    gemm64_nt_kernel<<<dim3(16, 16, BATCH * NCH), 256, 0, stream>>>(
        Upar, hbp, Spar, D_MODEL, D_MODEL, D_MODEL, T_SEQ,
        TD, RDe, TD, 0, TTs, 4 * TTs, BATCH, sc, 3, 1, 0,
        nullptr, nullptr, nullptr, nullptr, nullptr, nullptr);
    softmax_kernel<<<dim3(T_SEQ, BATCH * NCH), 256, 0, stream>>>(Spar);
    // PV + delta (64-tile mode 5): db[(b,t)][ch*768+d] = bf16(coef*(E - h))
    gemm64_nt_kernel<<<dim3(12, 16, BATCH * NCH), 256, 0, stream>>>(
        Spar, htp, nullptr, T_SEQ, T_SEQ, T_SEQ, D_MODEL,
        TTs, 4 * TTs, TD, 0, 0, 0, BATCH, 1.f, 5, 0, 1,
        nullptr, coefP, nullptr, nullptr, h, db);
    // merge partials: Pp[ch] = d_ch @ Wm_ch^T  (K-slice per z; Pp aliases Upar)
    gemm_nt_kernel<<<dim3(6, 32, NCH), 256, 0, stream>>>(
        db, mgb, Pp, KM, KM, KM, D_MODEL,
        0, 0, 0, 0, RDe, 0, NCH, 1.f, 1, 0, 0, D_MODEL, D_MODEL);

    // ======================= seq branch (serial chain, 64-tile) ==============
    u16* htsCur = hts0;
    u16* htsNxt = hts1;
    for (int i = 0; i < NCH; i++) {
        // U = hbs @ Mt_i^T
        gemm64_nt_kernel<<<dim3(12, 64, 1), 256, 0, stream>>>(
            hbs, Mtb + (long long)i * DD, Useq,
            D_MODEL, D_MODEL, D_MODEL, D_MODEL, 0, 0, 0, 0, 0, 0, 1,
            1.f, 1, 0, 0, nullptr, nullptr, nullptr, nullptr, nullptr, nullptr);
        // scores: Sseq[b] = U[b] @ hbs[b]^T * sc, causal
        gemm64_nt_kernel<<<dim3(16, 16, BATCH), 256, 0, stream>>>(
            Useq, hbs, Sseq, D_MODEL, D_MODEL, D_MODEL, T_SEQ,
            TD, 0, TD, 0, TTs, 0, BATCH, sc, 3, 1, 0,
            nullptr, nullptr, nullptr, nullptr, nullptr, nullptr);
        // softmax + fused gate-coef slice (z == BATCH)
        softmax_coef_kernel<<<dim3(T_SEQ, BATCH + 1), 256, 0, stream>>>(
            Sseq, hhf, gate_w, gate_b, scale_p, i, coefS);
        // PV + delta (mode 6): hh' = hh + coef*(E-hh) -> hhf, hbs, htsNxt
        gemm64_nt_kernel<<<dim3(12, 16, BATCH), 256, 0, stream>>>(
            Sseq, htsCur, nullptr, T_SEQ, T_SEQ, T_SEQ, D_MODEL,
            TTs, 0, TD, 0, 0, 0, BATCH, 1.f, 6, 0, 1,
            hhf, coefS, hbs, htsNxt, nullptr, nullptr);
        u16* tmp = htsCur; htsCur = htsNxt; htsNxt = tmp;
    }

    final_kernel<<<ROWS, 256, 0, stream>>>(x, h, hhf, Pp, mode_logit, residual_gate,
                                           ln_post_g, ln_post_b, out);
}

// Round 11
// 790.659 us; speedup vs baseline: 1.7221x; 1.1482x over previous
//
#include <hip/hip_runtime.h>
#include <hip/hip_bf16.h>
#include <math.h>

#define D_MODEL 768
#define T_SEQ   1024
#define BATCH   4
#define NCH     7
#define ROWS    4096            // BATCH*T_SEQ
#define KM      (NCH * D_MODEL) // 5376

typedef unsigned short u16;
typedef __attribute__((ext_vector_type(8))) short bh8;   // 8 x bf16
typedef __attribute__((ext_vector_type(4))) float f32x4;

__device__ __forceinline__ u16 f2bf(float f) {
    union { float f; unsigned u; } v; v.f = f;
    return (u16)((v.u + 0x7fffu + ((v.u >> 16) & 1u)) >> 16);  // RNE
}
__device__ __forceinline__ float bf2f(u16 b) {
    union { unsigned u; float f; } v; v.u = ((unsigned)b) << 16;
    return v.f;
}
__device__ __forceinline__ float wred_sum(float v) {
    #pragma unroll
    for (int o = 32; o; o >>= 1) v += __shfl_down(v, o, 64);
    return v;
}
__device__ __forceinline__ float wred_max(float v) {
    #pragma unroll
    for (int o = 32; o; o >>= 1) v = fmaxf(v, __shfl_down(v, o, 64));
    return v;
}
__device__ __forceinline__ float chamber_mask(int i) {
    float slope = 8.0f * 7.0f / 2000.0f;
    return 1.0f / (1.0f + __expf(-slope * (4000.0f - 2000.0f * (i + 0.5f) / 7.0f)));
}

#define GLD16(g, l) __builtin_amdgcn_global_load_lds( \
    (const __attribute__((address_space(1))) void*)(g), \
    (__attribute__((address_space(3))) void*)(l), 16, 0, 0)

// XCD-aware swizzle: round-robin dispatch puts consecutive flat ids on
// different XCDs; remap so each XCD owns a contiguous tile range (L2 reuse
// of shared A-tiles / z-slabs). Identity when N not divisible by 8.
__device__ __forceinline__ int xcd_swizzle(int gflat, int Ntot) {
    if ((Ntot & 7) == 0) {
        int chunk = Ntot >> 3;
        gflat = (gflat & 7) * chunk + (gflat >> 3);
    }
    return gflat;
}

// ---------------------------------------------------------------------------
// 128x128-tile NT GEMM: C = alpha * A[M,K] * B[N,K]^T  (bf16 in)
// K=64 per barrier as TWO independent BK=32 panels; XCD tile swizzle.
// mode: 0 f32 store, 1 bf16 store, 3 f16 store
// kss/klen: K slice per bz1 (merge partials). All K extents multiple of 64.
// ---------------------------------------------------------------------------
__global__ __launch_bounds__(256)
void gemm_nt_kernel(const u16* __restrict__ A, const u16* __restrict__ B,
                    void* __restrict__ Cv,
                    int K, int lda, int ldb, int ldc,
                    long long sA1, long long sA2, long long sB1, long long sB2,
                    long long sC1, long long sC2, int zm,
                    float alpha, int mode, int causal_skip, int causal_k,
                    int kss, int klen)
{
    int gx = gridDim.x, gy = gridDim.y;
    int Ntot = gx * gy * gridDim.z;
    int gflat = xcd_swizzle(blockIdx.x + gx * (blockIdx.y + gy * blockIdx.z), Ntot);
    int bn = gflat % gx;
    int rest = gflat / gx;
    int bm = rest % gy;
    int bz = rest / gy;
    if (causal_skip && bn > bm) return;
    int bz1 = bz % zm, bz2 = bz / zm;

    const u16* Ab = A + bz1 * sA1 + bz2 * sA2 + (long long)(bm * 128) * lda;
    const u16* Bb = B + bz1 * sB1 + bz2 * sB2 + (long long)(bn * 128) * ldb;

    __shared__ u16 sm[4 * 128 * 32];   // 32 KB: A0|B0|A1|B1 panels
    u16* Al0 = sm;
    u16* Bl0 = sm + 128 * 32;
    u16* Al1 = sm + 2 * 128 * 32;
    u16* Bl1 = sm + 3 * 128 * 32;

    int tid  = threadIdx.x;
    int lane = tid & 63;
    int wave = tid >> 6;
    int wm = wave >> 1, wn = wave & 1;

    int k_begin = kss ? bz1 * kss : 0;
    int k_end   = klen ? (k_begin + klen) : K;
    if (causal_k) k_end = min(k_end, (bm + 1) * 128);

    f32x4 acc[4][4];
    #pragma unroll
    for (int i = 0; i < 4; i++)
        #pragma unroll
        for (int j = 0; j < 4; j++)
            acc[i][j] = (f32x4){0.f, 0.f, 0.f, 0.f};

    int srow = lane >> 2;
    int skq  = (lane & 3) * 8;
    int fm   = lane & 15;
    int fk   = (lane >> 4) * 8;

    for (int k0 = k_begin; k0 < k_end; k0 += 64) {
        __syncthreads();
        #pragma unroll
        for (int r = 0; r < 2; r++) {
            int row = r * 64 + wave * 16 + srow;
            long long ra = (long long)row * lda + k0 + skq;
            long long rb2 = (long long)row * ldb + k0 + skq;
            GLD16(Ab + ra,       Al0 + row * 32 + skq);
            GLD16(Bb + rb2,      Bl0 + row * 32 + skq);
            GLD16(Ab + ra + 32,  Al1 + row * 32 + skq);
            GLD16(Bb + rb2 + 32, Bl1 + row * 32 + skq);
        }
        __syncthreads();

        #pragma unroll
        for (int p = 0; p < 2; p++) {
            const u16* Al = p ? Al1 : Al0;
            const u16* Bl = p ? Bl1 : Bl0;
            bh8 af[4], bf[4];
            #pragma unroll
            for (int i = 0; i < 4; i++)
                af[i] = *(const bh8*)(Al + (wm * 64 + i * 16 + fm) * 32 + fk);
            #pragma unroll
            for (int j = 0; j < 4; j++)
                bf[j] = *(const bh8*)(Bl + (wn * 64 + j * 16 + fm) * 32 + fk);
            #pragma unroll
            for (int i = 0; i < 4; i++)
                #pragma unroll
                for (int j = 0; j < 4; j++)
                    acc[i][j] = __builtin_amdgcn_mfma_f32_16x16x32_bf16(af[i], bf[j], acc[i][j], 0, 0, 0);
        }
    }

    int rbase = bm * 128 + wm * 64 + (lane >> 4) * 4;
    int cbase = bn * 128 + wn * 64 + (lane & 15);
    long long zoff = bz1 * sC1 + bz2 * sC2;
    if (mode == 1) {
        u16* C = (u16*)Cv + zoff;
        #pragma unroll
        for (int i = 0; i < 4; i++)
            #pragma unroll
            for (int j = 0; j < 4; j++)
                #pragma unroll
                for (int r = 0; r < 4; r++)
                    C[(long long)(rbase + i * 16 + r) * ldc + cbase + j * 16] = f2bf(acc[i][j][r] * alpha);
    } else if (mode == 3) {
        u16* C = (u16*)Cv + zoff;
        #pragma unroll
        for (int i = 0; i < 4; i++)
            #pragma unroll
            for (int j = 0; j < 4; j++)
                #pragma unroll
                for (int r = 0; r < 4; r++) {
                    union { _Float16 h; u16 u; } cv;
                    cv.h = (_Float16)(acc[i][j][r] * alpha);
                    C[(long long)(rbase + i * 16 + r) * ldc + cbase + j * 16] = cv.u;
                }
    } else {
        float* C = (float*)Cv + zoff;
        #pragma unroll
        for (int i = 0; i < 4; i++)
            #pragma unroll
            for (int j = 0; j < 4; j++)
                #pragma unroll
                for (int r = 0; r < 4; r++)
                    C[(long long)(rbase + i * 16 + r) * ldc + cbase + j * 16] = acc[i][j][r] * alpha;
    }
}

// ---------------------------------------------------------------------------
// 64x64-tile NT GEMM — K=128 per barrier as FOUR BK=32 panels (2-panel tail
// for 64-remainders, so causal-K PV works). XCD tile swizzle.
// mode: 0 f32, 1 bf16, 3 f16,
//       5 par PV+delta: db[(bz1,t)][bz2*768+d] = bf16(coef*(acc - h))
//       6 seq PV+delta: hh' = hh + coef*(acc - hh) -> hhf, hbs, hts (transposed)
// ---------------------------------------------------------------------------
__global__ __launch_bounds__(256)
void gemm64_nt_kernel(const u16* __restrict__ A, const u16* __restrict__ B,
                      void* __restrict__ Cv,
                      int K, int lda, int ldb, int ldc,
                      long long sA1, long long sA2, long long sB1, long long sB2,
                      long long sC1, long long sC2, int zm,
                      float alpha, int mode, int causal_skip, int causal_k,
                      float* __restrict__ hhfp, const float* __restrict__ coefp,
                      u16* __restrict__ hbsp, u16* __restrict__ htsp,
                      const float* __restrict__ hp, u16* __restrict__ dbp)
{
    int gx = gridDim.x, gy = gridDim.y;
    int Ntot = gx * gy * gridDim.z;
    int gflat = xcd_swizzle(blockIdx.x + gx * (blockIdx.y + gy * blockIdx.z), Ntot);
    int bn = gflat % gx;
    int rest = gflat / gx;
    int bm = rest % gy;
    int bz = rest / gy;
    if (causal_skip && bn > bm) return;
    int bz1 = bz % zm, bz2 = bz / zm;

    const u16* Ab = A + bz1 * sA1 + bz2 * sA2 + (long long)(bm * 64) * lda;
    const u16* Bb = B + bz1 * sB1 + bz2 * sB2 + (long long)(bn * 64) * ldb;

    __shared__ u16 sm[8 * 64 * 32];    // 32 KB: A0 B0 A1 B1 A2 B2 A3 B3
    const int PS = 64 * 32;            // panel stride (2048 u16)

    int tid  = threadIdx.x;
    int lane = tid & 63;
    int wave = tid >> 6;

    int k_end = causal_k ? min(K, (bm + 1) * 64) : K;

    f32x4 acc[4];
    #pragma unroll
    for (int j = 0; j < 4; j++) acc[j] = (f32x4){0.f, 0.f, 0.f, 0.f};

    int srow   = tid >> 2;             // 0..63
    int schunk = (tid & 3) * 8;
    int fm     = lane & 15;
    int fk     = (lane >> 4) * 8;

    int k0 = 0;
    while (k0 < k_end) {
        __syncthreads();
        if (k_end - k0 >= 128) {
            #pragma unroll
            for (int p = 0; p < 4; p++) {
                long long ra  = (long long)srow * lda + k0 + p * 32 + schunk;
                long long rb2 = (long long)srow * ldb + k0 + p * 32 + schunk;
                GLD16(Ab + ra,  sm + (2 * p) * PS + srow * 32 + schunk);
                GLD16(Bb + rb2, sm + (2 * p + 1) * PS + srow * 32 + schunk);
            }
            __syncthreads();
            #pragma unroll
            for (int p = 0; p < 4; p++) {
                const u16* Al = sm + (2 * p) * PS;
                const u16* Bl = sm + (2 * p + 1) * PS;
                bh8 af = *(const bh8*)(Al + (wave * 16 + fm) * 32 + fk);
                bh8 bf[4];
                #pragma unroll
                for (int j = 0; j < 4; j++)
                    bf[j] = *(const bh8*)(Bl + (j * 16 + fm) * 32 + fk);
                #pragma unroll
                for (int j = 0; j < 4; j++)
                    acc[j] = __builtin_amdgcn_mfma_f32_16x16x32_bf16(af, bf[j], acc[j], 0, 0, 0);
            }
            k0 += 128;
        } else {
            #pragma unroll
            for (int p = 0; p < 2; p++) {
                long long ra  = (long long)srow * lda + k0 + p * 32 + schunk;
                long long rb2 = (long long)srow * ldb + k0 + p * 32 + schunk;
                GLD16(Ab + ra,  sm + (2 * p) * PS + srow * 32 + schunk);
                GLD16(Bb + rb2, sm + (2 * p + 1) * PS + srow * 32 + schunk);
            }
            __syncthreads();
            #pragma unroll
            for (int p = 0; p < 2; p++) {
                const u16* Al = sm + (2 * p) * PS;
                const u16* Bl = sm + (2 * p + 1) * PS;
                bh8 af = *(const bh8*)(Al + (wave * 16 + fm) * 32 + fk);
                bh8 bf[4];
                #pragma unroll
                for (int j = 0; j < 4; j++)
                    bf[j] = *(const bh8*)(Bl + (j * 16 + fm) * 32 + fk);
                #pragma unroll
                for (int j = 0; j < 4; j++)
                    acc[j] = __builtin_amdgcn_mfma_f32_16x16x32_bf16(af, bf[j], acc[j], 0, 0, 0);
            }
            k0 += 64;
        }
    }

    int rbase = bm * 64 + wave * 16 + (lane >> 4) * 4;
    int cbase = bn * 64 + (lane & 15);
    long long zoff = bz1 * sC1 + bz2 * sC2;
    if (mode == 1) {
        u16* C = (u16*)Cv + zoff;
        #pragma unroll
        for (int j = 0; j < 4; j++)
            #pragma unroll
            for (int r = 0; r < 4; r++)
                C[(long long)(rbase + r) * ldc + cbase + j * 16] = f2bf(acc[j][r] * alpha);
    } else if (mode == 3) {
        u16* C = (u16*)Cv + zoff;
        #pragma unroll
        for (int j = 0; j < 4; j++)
            #pragma unroll
            for (int r = 0; r < 4; r++) {
                union { _Float16 h; u16 u; } cv;
                cv.h = (_Float16)(acc[j][r] * alpha);
                C[(long long)(rbase + r) * ldc + cbase + j * 16] = cv.u;
            }
    } else if (mode == 5) {
        // par PV + delta: bz1 = batch b, bz2 = chamber ch
        int b = bz1, ch = bz2;
        #pragma unroll
        for (int r = 0; r < 4; r++) {
            int t = rbase + r;
            long long rowg = (long long)b * T_SEQ + t;
            float cf = coefp[(long long)ch * ROWS + rowg];
            #pragma unroll
            for (int j = 0; j < 4; j++) {
                int d = cbase + j * 16;
                float hv = hp[rowg * D_MODEL + d];
                dbp[rowg * KM + ch * D_MODEL + d] = f2bf(cf * (acc[j][r] - hv));
            }
        }
    } else if (mode == 6) {
        __syncthreads();               // staging LDS dead; reuse as transpose tile
        u16* tile = sm;                // [64][66] = 4224 u16, fits
        #pragma unroll
        for (int r = 0; r < 4; r++) {
            int t = rbase + r;
            long long rowg = (long long)bz1 * T_SEQ + t;
            float cf = coefp[rowg];
            int tl = t - bm * 64;
            #pragma unroll
            for (int j = 0; j < 4; j++) {
                int d = cbase + j * 16;
                long long idx = rowg * D_MODEL + d;
                float v = hhfp[idx];
                float nh = v + cf * (acc[j][r] - v);
                hhfp[idx] = nh;
                u16 w = f2bf(nh);
                hbsp[idx] = w;
                tile[((lane & 15) + j * 16) * 66 + tl] = w;
            }
        }
        __syncthreads();
        int dl = tid >> 2, tch = (tid & 3) * 16;
        long long ob = (long long)bz1 * T_SEQ * D_MODEL +
                       (long long)(bn * 64 + dl) * T_SEQ + bm * 64 + tch;
        #pragma unroll
        for (int kk = 0; kk < 16; kk++)
            htsp[ob + kk] = tile[dl * 66 + tch + kk];
    } else {
        float* C = (float*)Cv + zoff;
        #pragma unroll
        for (int j = 0; j < 4; j++)
            #pragma unroll
            for (int r = 0; r < 4; r++)
                C[(long long)(rbase + r) * ldc + cbase + j * 16] = acc[j][r] * alpha;
    }
}

// ---------------------------------------------------------------------------
// LN pre: h = LN(x)*g+b; hhf = h; hbp = hbs = bf16(h)
// ---------------------------------------------------------------------------
__global__ __launch_bounds__(256)
void ln_pre_kernel(const float* __restrict__ x, const float* __restrict__ g,
                   const float* __restrict__ b, float* __restrict__ h,
                   float* __restrict__ hhf, u16* __restrict__ hbp,
                   u16* __restrict__ hbs)
{
    int row = blockIdx.x;
    long long base = (long long)row * D_MODEL;
    int tid = threadIdx.x, lane = tid & 63, wave = tid >> 6;
    __shared__ float red[4];
    float v[3]; float s = 0.f;
    #pragma unroll
    for (int k = 0; k < 3; k++) { v[k] = x[base + tid + k * 256]; s += v[k]; }
    s = wred_sum(s);
    if (lane == 0) red[wave] = s;
    __syncthreads();
    float mean = (red[0] + red[1] + red[2] + red[3]) * (1.f / D_MODEL);
    __syncthreads();
    float sq = 0.f;
    #pragma unroll
    for (int k = 0; k < 3; k++) { float dd = v[k] - mean; sq += dd * dd; }
    sq = wred_sum(sq);
    if (lane == 0) red[wave] = sq;
    __syncthreads();
    float var = (red[0] + red[1] + red[2] + red[3]) * (1.f / D_MODEL);
    float rstd = rsqrtf(var + 1e-5f);
    #pragma unroll
    for (int k = 0; k < 3; k++) {
        int c = tid + k * 256;
        float o = (v[k] - mean) * rstd * g[c] + b[c];
        h[base + c] = o; hhf[base + c] = o;
        u16 w = f2bf(o);
        hbp[base + c] = w; hbs[base + c] = w;
    }
}

// ---------------------------------------------------------------------------
// bf16 transpose, dual output
// ---------------------------------------------------------------------------
__global__ __launch_bounds__(256)
void transpose2_kernel(const u16* __restrict__ hb, u16* __restrict__ htp,
                       u16* __restrict__ hts)
{
    __shared__ u16 tile[32][33];
    int b = blockIdx.z;
    int d0 = blockIdx.x * 32, t0 = blockIdx.y * 32;
    int tx = threadIdx.x & 31, ty = threadIdx.x >> 5;
    long long bb = (long long)b * T_SEQ * D_MODEL;
    #pragma unroll
    for (int i = 0; i < 32; i += 8)
        tile[ty + i][tx] = hb[bb + (long long)(t0 + ty + i) * D_MODEL + d0 + tx];
    __syncthreads();
    #pragma unroll
    for (int i = 0; i < 32; i += 8) {
        long long o = bb + (long long)(d0 + ty + i) * T_SEQ + t0 + tx;
        u16 w = tile[tx][ty + i];
        htp[o] = w; hts[o] = w;
    }
}

// ---------------------------------------------------------------------------
// causal softmax, f16 in -> bf16 out, in place
// ---------------------------------------------------------------------------
__device__ __forceinline__ void softmax_row(u16* row, int len, int tid, int lane, int wave,
                                            float* red)
{
    float ev[4];
    float m = -3.0e38f;
    #pragma unroll
    for (int k = 0; k < 4; k++) {
        int s = tid + k * 256;
        if (s < len) {
            union { u16 u; _Float16 h; } cv; cv.u = row[s];
            ev[k] = (float)cv.h;
        } else ev[k] = -3.0e38f;
        m = fmaxf(m, ev[k]);
    }
    m = wred_max(m);
    if (lane == 0) red[wave] = m;
    __syncthreads();
    m = fmaxf(fmaxf(red[0], red[1]), fmaxf(red[2], red[3]));
    __syncthreads();
    float sum = 0.f;
    #pragma unroll
    for (int k = 0; k < 4; k++) {
        int s = tid + k * 256;
        float e = (s < len) ? __expf(ev[k] - m) : 0.f;
        ev[k] = e; sum += e;
    }
    sum = wred_sum(sum);
    if (lane == 0) red[wave] = sum;
    __syncthreads();
    sum = red[0] + red[1] + red[2] + red[3];
    float inv = 1.f / sum;
    #pragma unroll
    for (int k = 0; k < 4; k++)
        row[tid + k * 256] = f2bf(ev[k] * inv);
}

__global__ __launch_bounds__(256)
void softmax_kernel(u16* __restrict__ SP)
{
    int t = blockIdx.x, z = blockIdx.y;
    __shared__ float red[4];
    int tid = threadIdx.x, lane = tid & 63, wave = tid >> 6;
    softmax_row(SP + (long long)z * T_SEQ * T_SEQ + (long long)t * T_SEQ,
                t + 1, tid, lane, wave, red);
}

// seq softmax + fused coef slice (z == BATCH computes gate coefs for 4 rows)
__global__ __launch_bounds__(256)
void softmax_coef_kernel(u16* __restrict__ SP, const float* __restrict__ hhf,
                         const float* __restrict__ gw, const float* __restrict__ gb,
                         const float* __restrict__ sp, int ci,
                         float* __restrict__ coefS)
{
    int t = blockIdx.x, z = blockIdx.y;
    int tid = threadIdx.x, lane = tid & 63, wave = tid >> 6;
    if (z == BATCH) {
        int row = t * 4 + wave;
        long long base = (long long)row * D_MODEL;
        const float* g = gw + ci * D_MODEL;
        float dot = 0.f;
        #pragma unroll
        for (int k = 0; k < 12; k++) dot += hhf[base + lane + 64 * k] * g[lane + 64 * k];
        dot = wred_sum(dot);
        if (lane == 0) {
            float gate = 1.f / (1.f + __expf(-(dot + gb[ci])));
            coefS[row] = log1pf(expf(sp[ci])) * chamber_mask(ci) * gate;
        }
        return;
    }
    __shared__ float red[4];
    softmax_row(SP + (long long)z * T_SEQ * T_SEQ + (long long)t * T_SEQ,
                t + 1, tid, lane, wave, red);
}

// ---------------------------------------------------------------------------
// par coef: gate coefficient per row for all 7 chambers (frozen h)
// ---------------------------------------------------------------------------
__global__ __launch_bounds__(256)
void coef_par_kernel(const float* __restrict__ h, const float* __restrict__ gw,
                     const float* __restrict__ gb, const float* __restrict__ sp,
                     float* __restrict__ coefP)
{
    int row = blockIdx.x * 4 + (threadIdx.x >> 6);
    int lane = threadIdx.x & 63;
    long long base = (long long)row * D_MODEL;
    float hv[12];
    #pragma unroll
    for (int k = 0; k < 12; k++) hv[k] = h[base + lane + 64 * k];
    for (int ci = 0; ci < NCH; ci++) {
        const float* g = gw + ci * D_MODEL;
        float dot = 0.f;
        #pragma unroll
        for (int k = 0; k < 12; k++) dot += hv[k] * g[lane + 64 * k];
        dot = wred_sum(dot);
        if (lane == 0) {
            float gate = 1.f / (1.f + __expf(-(dot + gb[ci])));
            coefP[ci * ROWS + row] = log1pf(expf(sp[ci])) * chamber_mask(ci) * gate;
        }
    }
}

// ---------------------------------------------------------------------------
__global__ __launch_bounds__(256)
void cast4_kernel(const float4* __restrict__ in, ushort4* __restrict__ outp, int n4)
{
    int i = blockIdx.x * 256 + threadIdx.x;
    if (i < n4) {
        float4 v = in[i];
        ushort4 o;
        o.x = f2bf(v.x); o.y = f2bf(v.y); o.z = f2bf(v.z); o.w = f2bf(v.w);
        outp[i] = o;
    }
}

// ---------------------------------------------------------------------------
// final: par = sum of 7 bf16 partial slabs; e = (1-mg)*(hhf-h) + mg*par;
// out = x + rg*(LN(e)*g+b)
// ---------------------------------------------------------------------------
__global__ __launch_bounds__(256)
void final_kernel(const float* __restrict__ x, const float* __restrict__ h,
                  const float* __restrict__ hhf, const u16* __restrict__ Pp,
                  const float* __restrict__ mode_logit, const float* __restrict__ residual_gate,
                  const float* __restrict__ g, const float* __restrict__ b,
                  float* __restrict__ out)
{
    const long long RDe = (long long)ROWS * D_MODEL;
    int row = blockIdx.x;
    long long base = (long long)row * D_MODEL;
    int tid = threadIdx.x, lane = tid & 63, wave = tid >> 6;
    __shared__ float red[4];
    float mg = 1.f / (1.f + __expf(-mode_logit[0]));
    float rg = residual_gate[0];
    float e[3]; float s = 0.f;
    #pragma unroll
    for (int k = 0; k < 3; k++) {
        int c = tid + k * 256;
        float p = 0.f;
        #pragma unroll
        for (int z = 0; z < NCH; z++) p += bf2f(Pp[z * RDe + base + c]);
        float v = (1.f - mg) * (hhf[base + c] - h[base + c]) + mg * p;
        e[k] = v; s += v;
    }
    s = wred_sum(s);
    if (lane == 0) red[wave] = s;
    __syncthreads();
    float mean = (red[0] + red[1] + red[2] + red[3]) * (1.f / D_MODEL);
    __syncthreads();
    float sq = 0.f;
    #pragma unroll
    for (int k = 0; k < 3; k++) { float dd = e[k] - mean; sq += dd * dd; }
    sq = wred_sum(sq);
    if (lane == 0) red[wave] = sq;
    __syncthreads();
    float var = (red[0] + red[1] + red[2] + red[3]) * (1.f / D_MODEL);
    float rstd = rsqrtf(var + 1e-5f);
    #pragma unroll
    for (int k = 0; k < 3; k++) {
        int c = tid + k * 256;
        out[base + c] = x[base + c] + rg * ((e[k] - mean) * rstd * g[c] + b[c]);
    }
}

// ---------------------------------------------------------------------------
extern "C" void kernel_launch(void* const* d_in, const int* in_sizes, int n_in,
                              void* d_out, int out_size, void* d_ws, size_t ws_size,
                              hipStream_t stream)
{
    (void)in_sizes; (void)n_in; (void)out_size; (void)ws_size;
    const float* x             = (const float*)d_in[0];
    const float* Wq            = (const float*)d_in[1];
    const float* Wk            = (const float*)d_in[2];
    const float* gate_w        = (const float*)d_in[3];
    const float* gate_b        = (const float*)d_in[4];
    const float* scale_p       = (const float*)d_in[5];
    const float* merge_W       = (const float*)d_in[6];
    const float* mode_logit    = (const float*)d_in[7];
    const float* residual_gate = (const float*)d_in[8];
    const float* ln_pre_g      = (const float*)d_in[9];
    const float* ln_pre_b      = (const float*)d_in[10];
    const float* ln_post_g     = (const float*)d_in[11];
    const float* ln_post_b     = (const float*)d_in[12];
    float* out = (float*)d_out;

    const long long DD  = (long long)D_MODEL * D_MODEL;   // 589824
    const long long TD  = (long long)T_SEQ * D_MODEL;     // 786432
    const long long TTs = (long long)T_SEQ * T_SEQ;       // 1048576
    const long long RDe = (long long)ROWS * D_MODEL;      // 3145728

    size_t off = 0;
    char* wsb = (char*)d_ws;
    auto alloc = [&](size_t bytes) -> void* {
        void* p = wsb + off; off += (bytes + 255) & ~(size_t)255; return p;
    };
    u16*   Mtb  = (u16*)alloc((size_t)NCH * DD * 2);
    u16*   mgb  = (u16*)alloc((size_t)D_MODEL * KM * 2);
    float* h    = (float*)alloc(RDe * 4);
    float* hhf  = (float*)alloc(RDe * 4);
    u16*   hbp  = (u16*)alloc(RDe * 2);
    u16*   htp  = (u16*)alloc(RDe * 2);
    u16*   hbs  = (u16*)alloc(RDe * 2);
    u16*   hts0 = (u16*)alloc(RDe * 2);
    u16*   hts1 = (u16*)alloc(RDe * 2);
    u16*   Spar = (u16*)alloc((size_t)(NCH * BATCH) * TTs * 2);
    u16*   Sseq = (u16*)alloc((size_t)BATCH * TTs * 2);
    u16*   Upar = (u16*)alloc((size_t)NCH * RDe * 2);
    u16*   Useq = (u16*)alloc(RDe * 2);
    u16*   db   = (u16*)alloc((size_t)ROWS * KM * 2);
    float* coefP= (float*)alloc((size_t)NCH * ROWS * 4);
    float* coefS= (float*)alloc((size_t)ROWS * 4);
    // transient aliases (stream-ordered lifetimes):
    u16*   Wqb  = Spar;                 // dead before Spar written
    u16*   Wkb  = Spar + (size_t)NCH * DD;
    u16*   Pp   = Upar;                 // merge partials: Upar dead after par scores

    const float sc = 1.0f / sqrtf((float)D_MODEL);
    const int N4W = (int)((size_t)NCH * DD) / 4;
    const int N4M = (int)((size_t)D_MODEL * KM) / 4;

    ln_pre_kernel<<<ROWS, 256, 0, stream>>>(x, ln_pre_g, ln_pre_b, h, hhf, hbp, hbs);
    cast4_kernel<<<(N4W + 255) / 256, 256, 0, stream>>>((const float4*)Wq, (ushort4*)Wqb, N4W);
    cast4_kernel<<<(N4W + 255) / 256, 256, 0, stream>>>((const float4*)Wk, (ushort4*)Wkb, N4W);
    cast4_kernel<<<(N4M + 255) / 256, 256, 0, stream>>>((const float4*)merge_W, (ushort4*)mgb, N4M);
    transpose2_kernel<<<dim3(24, 32, BATCH), 256, 0, stream>>>(hbp, htp, hts0);
    coef_par_kernel<<<ROWS / 4, 256, 0, stream>>>(h, gate_w, gate_b, scale_p, coefP);

    // Mt_i[d'][d] = sum_e Wk_i[d'][e] Wq_i[d][e]   (z=7; 252 blocks -> no swizzle)
    gemm_nt_kernel<<<dim3(6, 6, NCH), 256, 0, stream>>>(
        Wkb, Wqb, Mtb, D_MODEL, D_MODEL, D_MODEL, D_MODEL,
        DD, 0, DD, 0, DD, 0, NCH, 1.f, 1, 0, 0, 0, 0);

    // ======================= par branch (frozen h, batched over chambers) ====
    // U_i = hbp @ Mt_i^T  (128-tile, 1344 blocks, swizzled)
    gemm_nt_kernel<<<dim3(6, 32, NCH), 256, 0, stream>>>(
        hbp, Mtb, Upar, D_MODEL, D_MODEL, D_MODEL, D_MODEL,
        0, 0, DD, 0, RDe, 0, NCH, 1.f, 1, 0, 0, 0, 0);
    // scores (64-tile, 7168 blocks, swizzled): Spar[ch*4+b] = U_ch[b] @ hbp[b]^T
    gemm64_nt_kernel<<<dim3(16, 16, BATCH * NCH), 256, 0, stream>>>(
        Upar, hbp, Spar, D_MODEL, D_MODEL, D_MODEL, T_SEQ,
        TD, RDe, TD, 0, TTs, 4 * TTs, BATCH, sc, 3, 1, 0,
        nullptr, nullptr, nullptr, nullptr, nullptr, nullptr);
    softmax_kernel<<<dim3(T_SEQ, BATCH * NCH), 256, 0, stream>>>(Spar);
    // PV + delta (64-tile mode 5): db[(b,t)][ch*768+d] = bf16(coef*(E - h))
    gemm64_nt_kernel<<<dim3(12, 16, BATCH * NCH), 256, 0, stream>>>(
        Spar, htp, nullptr, T_SEQ, T_SEQ, T_SEQ, D_MODEL,
        TTs, 4 * TTs, TD, 0, 0, 0, BATCH, 1.f, 5, 0, 1,
        nullptr, coefP, nullptr, nullptr, h, db);
    // merge partials: Pp[ch] = d_ch @ Wm_ch^T  (K-slice per z; Pp aliases Upar)
    gemm_nt_kernel<<<dim3(6, 32, NCH), 256, 0, stream>>>(
        db, mgb, Pp, KM, KM, KM, D_MODEL,
        0, 0, 0, 0, RDe, 0, NCH, 1.f, 1, 0, 0, D_MODEL, D_MODEL);

    // ======================= seq branch (serial chain, 64-tile) ==============
    u16* htsCur = hts0;
    u16* htsNxt = hts1;
    for (int i = 0; i < NCH; i++) {
        // U = hbs @ Mt_i^T
        gemm64_nt_kernel<<<dim3(12, 64, 1), 256, 0, stream>>>(
            hbs, Mtb + (long long)i * DD, Useq,
            D_MODEL, D_MODEL, D_MODEL, D_MODEL, 0, 0, 0, 0, 0, 0, 1,
            1.f, 1, 0, 0, nullptr, nullptr, nullptr, nullptr, nullptr, nullptr);
        // scores: Sseq[b] = U[b] @ hbs[b]^T * sc, causal
        gemm64_nt_kernel<<<dim3(16, 16, BATCH), 256, 0, stream>>>(
            Useq, hbs, Sseq, D_MODEL, D_MODEL, D_MODEL, T_SEQ,
            TD, 0, TD, 0, TTs, 0, BATCH, sc, 3, 1, 0,
            nullptr, nullptr, nullptr, nullptr, nullptr, nullptr);
        // softmax + fused gate-coef slice (z == BATCH)
        softmax_coef_kernel<<<dim3(T_SEQ, BATCH + 1), 256, 0, stream>>>(
            Sseq, hhf, gate_w, gate_b, scale_p, i, coefS);
        // PV + delta (mode 6): hh' = hh + coef*(E-hh) -> hhf, hbs, htsNxt
        gemm64_nt_kernel<<<dim3(12, 16, BATCH), 256, 0, stream>>>(
            Sseq, htsCur, nullptr, T_SEQ, T_SEQ, T_SEQ, D_MODEL,
            TTs, 0, TD, 0, 0, 0, BATCH, 1.f, 6, 0, 1,
            hhf, coefS, hbs, htsNxt, nullptr, nullptr);
        u16* tmp = htsCur; htsCur = htsNxt; htsNxt = tmp;
    }

    final_kernel<<<ROWS, 256, 0, stream>>>(x, h, hhf, Pp, mode_logit, residual_gate,
                                           ln_post_g, ln_post_b, out);
}